// Round 20
// baseline (581.283 us; speedup 1.0000x reference)
//
#include <hip/hip_runtime.h>
#include <hip/hip_bf16.h>
#include <math.h>

#define Hh 360
#define Ww 720
#define Cc 64
#define Bb 2
#define BC (Bb*Cc)        // 128
#define Mrows (BC*Hh)     // 46080
#define CHUNKS 2
#define CM (Mrows/CHUNKS) // 23040
#define HPC (Hh/CHUNKS)   // 180 latitudes per chunk
#define KA 768            // A row: [hi(384) | lo(384)]
#define KF3 1152          // GEMM K loop: [hi.Bhi | lo.Bhi | hi.Blo]
#define NF 384            // fwd N (361 bins padded)
#define KI 768            // inv K: [Re(384) | Im(384)]
#define NI 768            // inv C row stride (720 used)
#define NSTORE_INV 720
#define SCALE 0.037267799624996496f   // 1/sqrt(720)
#define TWO_PI 6.2831853071795864769f

typedef __attribute__((ext_vector_type(8))) short s16x8;
typedef __attribute__((ext_vector_type(4))) float f32x4;
typedef __hip_bfloat16 bf16;

__device__ __forceinline__ void gload_lds16(const void* g, void* l) {
    __builtin_amdgcn_global_load_lds(
        (const __attribute__((address_space(1))) unsigned int*)g,
        (__attribute__((address_space(3))) unsigned int*)l, 16, 0, 0);
}
__device__ __forceinline__ short f2bfs(float v) {
    bf16 h = __float2bfloat16(v); short s; __builtin_memcpy(&s, &h, 2); return s;
}
__device__ __forceinline__ float bfs2f(short s) {
    bf16 h; __builtin_memcpy(&h, &s, 2); return __bfloat162float(h);
}

// ---------------------------------------------------------- B-matrix builds
// B stays 1152-wide: [Bhi | Bhi | Blo].
__global__ __launch_bounds__(256) void build_bfwd_kernel(bf16* __restrict__ Bc,
                                                         bf16* __restrict__ Bs) {
    int g = blockIdx.x * 256 + threadIdx.x;
    if (g >= NF * KF3) return;
    int wext = g % KF3;
    int j = g / KF3;
    int blk = wext / 384;
    int w = wext - blk * 384;
    float c = 0.f, s = 0.f;
    if (w <= 360 && j <= 360) {
        int idx = (j * w) % Ww;
        float a = (TWO_PI / Ww) * (float)idx;
        float sv, cv;
        sincosf(a, &sv, &cv);
        c = SCALE * cv;
        s = -SCALE * sv;
    }
    bf16 chi = __float2bfloat16(c);
    bf16 shi = __float2bfloat16(s);
    if (blk == 2) {
        Bc[g] = __float2bfloat16(c - __bfloat162float(chi));
        Bs[g] = __float2bfloat16(s - __bfloat162float(shi));
    } else {
        Bc[g] = chi;
        Bs[g] = shi;
    }
}

__global__ __launch_bounds__(256) void build_binv_kernel(bf16* __restrict__ Bi) {
    int g = blockIdx.x * 256 + threadIdx.x;
    if (g >= NI * KI) return;
    int k = g % KI, n = g / KI;
    float v = 0.f;
    if (n < NSTORE_INV) {
        if (k <= 360) {
            int j = k;
            float f = (j == 0 || j == 360) ? 1.f : 2.f;
            int idx = (j * n) % Ww;
            v = SCALE * f * cosf((TWO_PI / Ww) * (float)idx);
        } else if (k >= 384 && k <= 744) {
            int j = k - 384;
            int idx = (j * n) % Ww;
            v = -2.f * SCALE * sinf((TWO_PI / Ww) * (float)idx);
        }
    }
    Bi[g] = __float2bfloat16(v);
}

// W fragment-packed: s16x8 index = fid*64 + lane, fid = ((n16*4 + kb)*2 + kh).
__global__ __launch_bounds__(256) void build_wf_kernel(
    const float* __restrict__ w1_r, const float* __restrict__ w1_i,
    const float* __restrict__ w2_r, const float* __restrict__ w2_i,
    bf16* __restrict__ W1f, bf16* __restrict__ W2f)
{
    int g = blockIdx.x * 256 + threadIdx.x;
    if (g >= 2 * 32768) return;
    int which = g >> 15;
    int gg = g & 32767;
    int e = gg & 7, lane = (gg >> 3) & 63, kh = (gg >> 9) & 1;
    int kb = (gg >> 10) & 3, n16 = (gg >> 12) & 7;
    int frow = lane & 15, fcol = (lane >> 4) * 8;
    int n = n16 * 16 + frow;
    int kfull = kb * 64 + kh * 32 + fcol + e;
    int kk = kfull & 127, islo = kfull >> 7;
    const float* wr = which ? w2_r : w1_r;
    const float* wi = which ? w2_i : w1_i;
    float v;
    if (n < 64) v = (kk < 64) ? wr[n * 64 + kk] : -wi[n * 64 + kk - 64];
    else { int p = n - 64; v = (kk < 64) ? wi[p * 64 + kk] : wr[p * 64 + kk - 64]; }
    bf16 h = __float2bfloat16(v);
    bf16 out = islo ? __float2bfloat16(v - __bfloat162float(h)) : h;
    (which ? W2f : W1f)[gg] = out;
}

// ---------------------------------------- row starts (compact + 8-padded)
__global__ __launch_bounds__(512) void row_starts_kernel(const int* __restrict__ rows,
                                                         int T, int* __restrict__ rs,
                                                         int* __restrict__ rs8) {
    int h = threadIdx.x;
    if (h <= Hh) {
        if (h == Hh) rs[Hh] = T;
        else {
            int lo = 0, hi = T;
            while (lo < hi) {
                int mid = (lo + hi) >> 1;
                if (rows[mid] < h) lo = mid + 1; else hi = mid;
            }
            rs[h] = lo;
        }
    }
    __syncthreads();
    if (threadIdx.x == 0) {
        int acc = 0;
        for (int i = 0; i < Hh; ++i) {
            rs8[i] = acc;
            int cnt = rs[i + 1] - rs[i];
            acc += (cnt + 7) & ~7;
        }
        rs8[Hh] = acc;
    }
}

// ------------------- pack x chunk -> A [hi|lo] (768-wide), h-major rows
__global__ __launch_bounds__(256) void pack_kernel(const float* __restrict__ x,
                                                   bf16* __restrict__ Ap,
                                                   bf16* __restrict__ Aq,
                                                   int hbase) {
    int g = blockIdx.x * 256 + threadIdx.x;
    if (g >= CM * KA) return;
    int wext = g % KA;
    int r = g / KA;
    int hl = r >> 7;
    int bc = r & 127;
    const float* xrow = x + ((size_t)bc * Hh + hbase + hl) * Ww;
    int islo = (wext >= 384);
    int w = islo ? (wext - 384) : wext;
    float p = 0.f, q = 0.f;
    if (w == 0 || w == 360) {
        p = xrow[w];
    } else if (w < 360) {
        float a = xrow[w];
        float b = xrow[Ww - w];
        p = a + b;
        q = a - b;
    }
    bf16 phi = __float2bfloat16(p);
    bf16 qhi = __float2bfloat16(q);
    if (islo) {
        Ap[g] = __float2bfloat16(p - __bfloat162float(phi));
        Aq[g] = __float2bfloat16(q - __bfloat162float(qhi));
    } else {
        Ap[g] = phi;
        Aq[g] = qhi;
    }
}

// ----------------------------------------------------------------- zero fill
__global__ __launch_bounds__(256) void fill_zero_kernel(uint4* __restrict__ p, long n) {
    long i = (long)blockIdx.x * 256 + threadIdx.x;
    long stride = (long)gridDim.x * 256;
    uint4 z = make_uint4(0u, 0u, 0u, 0u);
    for (; i < n; i += stride) p[i] = z;
}

// -------- fwd MFMA GEMM, h-uniform tiles + early exit + XCD-chunk swizzle
// 1-D grid of 1080 blocks; logical = (bid&7)*135 + (bid>>3) is bijective
// (1080 = 8*135). logical -> (n, z, hl) with same-(hl,z) trios consecutive
// so the 3 n-tiles sharing an A-block land on the same XCD's L2.
__global__ __launch_bounds__(256) void gemm_fwd_compact_kernel(
    const bf16* __restrict__ Ap, const bf16* __restrict__ Aq,
    const bf16* __restrict__ Bc, const bf16* __restrict__ Bsm,
    float* __restrict__ Xcr, float* __restrict__ Xci,
    const int* __restrict__ rs, int T128, int hbase)
{
    __shared__ __align__(128) bf16 As[128][64];
    __shared__ __align__(128) bf16 Bs[128][64];
    const int bid = blockIdx.x;
    const int logical = (bid & 7) * 135 + (bid >> 3);
    const int nsel = logical % 3;
    const int hz = logical / 3;          // 0..359
    const int z = hz & 1;
    const int hl = hz >> 1;              // 0..179
    const int h = hbase + hl;            // one latitude per m-tile
    const int t0 = rs[h];
    const int cnt = rs[h + 1] - t0;
    const int n0 = nsel * 128;
    if (n0 >= cnt) return;               // tile stores nothing: dead work
    const bf16* A  = z ? Aq : Ap;
    const bf16* Bt = z ? Bsm : Bc;
    float* Xc      = z ? Xci : Xcr;
    const int tid = threadIdx.x;
    const int lane = tid & 63;
    const int wave = tid >> 6;
    const int m0 = hl * 128;
    const int wr = (wave >> 1) * 64;
    const int wc = (wave & 1) * 64;
    const int srow = tid >> 3;
    const int scol = (tid & 7) << 3;
    f32x4 acc[4][4] = {};
    for (int k0 = 0; k0 < KF3; k0 += 64) {
        const int ka0 = (k0 >= 768) ? (k0 - 768) : k0;
#pragma unroll
        for (int i = 0; i < 4; ++i) {
            const bf16* ga = A  + (size_t)(m0 + i * 32 + srow) * KA + ka0 + scol;
            const bf16* gb = Bt + (size_t)(n0 + i * 32 + srow) * KF3 + k0 + scol;
            gload_lds16(ga, ((char*)&As[0][0]) + (size_t)(i * 256 + tid) * 16);
            gload_lds16(gb, ((char*)&Bs[0][0]) + (size_t)(i * 256 + tid) * 16);
        }
        __syncthreads();
#pragma unroll
        for (int kk = 0; kk < 64; kk += 32) {
            s16x8 a[4], b[4];
#pragma unroll
            for (int m = 0; m < 4; ++m)
                a[m] = *(const s16x8*)&As[wr + m * 16 + (lane & 15)][kk + (lane >> 4) * 8];
#pragma unroll
            for (int n = 0; n < 4; ++n)
                b[n] = *(const s16x8*)&Bs[wc + n * 16 + (lane & 15)][kk + (lane >> 4) * 8];
#pragma unroll
            for (int m = 0; m < 4; ++m)
#pragma unroll
                for (int n = 0; n < 4; ++n)
                    acc[m][n] = __builtin_amdgcn_mfma_f32_16x16x32_bf16(a[m], b[n], acc[m][n], 0, 0, 0);
        }
        __syncthreads();
    }
    const int rbase = (lane >> 4) * 4;
    const int cidx = lane & 15;
#pragma unroll
    for (int m = 0; m < 4; ++m) {
#pragma unroll
        for (int r = 0; r < 4; ++r) {
            int bc = wr + m * 16 + rbase + r;   // local row within h-tile
#pragma unroll
            for (int n = 0; n < 4; ++n) {
                int j = n0 + wc + n * 16 + cidx;
                if (j < cnt)
                    Xc[(size_t)bc * T128 + t0 + j] = acc[m][n][r];
            }
        }
    }
}

// ---- inverse GEMM, h-uniform tiles + K-tile early-skip + XCD-chunk swizzle
// 1-D grid of 2160 blocks; logical = (bid&7)*270 + (bid>>3) bijective
// (2160 = 8*270). Same-h sextets consecutive -> shared Xg block stays in
// one XCD's L2.
__global__ __launch_bounds__(256) void gemm_inv_kernel(
    const bf16* __restrict__ Xgr, const bf16* __restrict__ Xgi,
    const bf16* __restrict__ Bt, const int* __restrict__ rs8,
    bf16* __restrict__ C, int T8cap)
{
    __shared__ __align__(128) bf16 As[128][64];
    __shared__ __align__(128) bf16 Bs[128][64];
    const int bid = blockIdx.x;
    const int logical = (bid & 7) * 270 + (bid >> 3);
    const int h = logical / 6;           // one latitude per m-tile
    const int n0 = (logical % 6) * 128;
    const int t0v = rs8[h];
    const int cnt8 = rs8[h + 1] - t0v;
    const int tid = threadIdx.x;
    const int lane = tid & 63;
    const int wave = tid >> 6;
    const int wr = (wave >> 1) * 64;
    const int wc = (wave & 1) * 64;
    const int srow = tid >> 3;
    const int scol = (tid & 7) << 3;
    f32x4 acc[4][4] = {};
    for (int k0 = 0; k0 < KI; k0 += 64) {
        const int jb = (k0 < 384) ? k0 : (k0 - 384);
        if (jb >= cnt8) continue;           // A-tile all zero: acc += 0, skip
        const bf16* base = (k0 < 384) ? Xgr : Xgi;
        const int j0 = jb + scol;
#pragma unroll
        for (int i = 0; i < 4; ++i)
            gload_lds16(Bt + (size_t)(n0 + i * 32 + srow) * KI + k0 + scol,
                        ((char*)&Bs[0][0]) + (size_t)(i * 256 + tid) * 16);
#pragma unroll
        for (int i = 0; i < 4; ++i) {
            int bc = i * 32 + srow;
            s16x8 v = (s16x8){0, 0, 0, 0, 0, 0, 0, 0};
            if (j0 < cnt8)
                v = *(const s16x8*)(base + (size_t)bc * T8cap + t0v + j0);
            *(s16x8*)&As[bc][scol] = v;
        }
        __syncthreads();
#pragma unroll
        for (int kk = 0; kk < 64; kk += 32) {
            s16x8 a[4], b[4];
#pragma unroll
            for (int m = 0; m < 4; ++m)
                a[m] = *(const s16x8*)&As[wr + m * 16 + (lane & 15)][kk + (lane >> 4) * 8];
#pragma unroll
            for (int n = 0; n < 4; ++n)
                b[n] = *(const s16x8*)&Bs[wc + n * 16 + (lane & 15)][kk + (lane >> 4) * 8];
#pragma unroll
            for (int m = 0; m < 4; ++m)
#pragma unroll
                for (int n = 0; n < 4; ++n)
                    acc[m][n] = __builtin_amdgcn_mfma_f32_16x16x32_bf16(a[m], b[n], acc[m][n], 0, 0, 0);
        }
        __syncthreads();
    }
    const int rbase = (lane >> 4) * 4;
    const int cidx = lane & 15;
#pragma unroll
    for (int m = 0; m < 4; ++m) {
#pragma unroll
        for (int n = 0; n < 4; ++n) {
            int gcol = n0 + wc + n * 16 + cidx;
            if (gcol < NSTORE_INV) {
#pragma unroll
                for (int r = 0; r < 4; ++r) {
                    int bc = wr + m * 16 + rbase + r;
                    C[(size_t)(h * BC + bc) * NI + gcol] = __float2bfloat16(acc[m][n][r]);
                }
            }
        }
    }
}

// ------------------------------------------------ fused middle stage (v3)
// FROZEN: verbatim green r17 middle. Three independent edits (fastmath,
// register-cache, both) each broke correctness (r12/r18/r19) — do not touch.
__device__ __forceinline__ float gelu_exact(float v) {
    return 0.5f * v * (1.0f + erff(v * 0.7071067811865476f));
}

__global__ __launch_bounds__(256, 4) void middle_fused_kernel(
    const float* __restrict__ Xcr, const float* __restrict__ Xci,
    bf16* __restrict__ Xgr, bf16* __restrict__ Xgi,
    const float* __restrict__ mean_r, const float* __restrict__ mean_i,
    const float* __restrict__ stdv,
    const float* __restrict__ mags_r, const float* __restrict__ mags_i,
    const float* __restrict__ bias_r, const float* __restrict__ bias_i,
    const bf16* __restrict__ W1f, const bf16* __restrict__ W2f,
    const float* __restrict__ brelu_p,
    const float* __restrict__ glu_mags, const float* __restrict__ glu_phases,
    const int* __restrict__ rows, const int* __restrict__ cols,
    const int* __restrict__ rs8,
    int T, int T128, int T8cap)
{
    __shared__ __align__(16) char smemA[32 * 264 * 2];   // 16,896 B
    __shared__ __align__(16) char smemB[32 * 264 * 2];
    bf16*  H1 = (bf16*)smemA;    // [32][264] hi/lo split input
    float* aL = (float*)smemA;   // [32][132] GEMM1 result
    float* cL = (float*)smemA;   // [32][132] GEMM2 result
    bf16*  H2 = (bf16*)smemB;    // [32][264] gelu output

    const int tid = threadIdx.x;
    const int b = blockIdx.y;
    const int t0 = blockIdx.x * 32;
    const int tl = tid & 31;
    const int cg = tid >> 5;          // 0..7
    const int t = t0 + tl;
    const bool valid = (t < T);
    const int lane = tid & 63;
    const int wv = tid >> 6;          // 0..3
    const int frow = lane & 15;
    const int fcol = (lane >> 4) * 8;
    const s16x8* W1v = (const s16x8*)W1f;
    const s16x8* W2v = (const s16x8*)W2f;
    constexpr int ASRC[6] = {0, 1, 2, 3, 0, 1};
    constexpr int BSRC[6] = {0, 1, 0, 1, 2, 3};

    // ---- phase 1: normalize -> H1 (lane=t, coalesced global reads)
    {
        float mr = 0.f, mi_ = 0.f, isd = 0.f;
        if (valid) { mr = mean_r[t]; mi_ = mean_i[t]; isd = 1.0f / (1e-12f + stdv[t]); }
        s16x8 vhr, vhi, vlr, vli;
#pragma unroll
        for (int ci = 0; ci < 8; ++ci) {
            int c = cg * 8 + ci;
            float xr = 0.f, xi = 0.f;
            if (valid) {
                xr = Xcr[(size_t)(b * 64 + c) * T128 + t];
                xi = Xci[(size_t)(b * 64 + c) * T128 + t];
            }
            float hr = (xr - mr) * isd;
            float hi = (xi - mi_) * isd;
            float h1r = fmaf(hr, mags_r[c], fmaf(-hi, mags_i[c], bias_r[c]));
            float h1i = fmaf(hr, mags_i[c], fmaf(hi, mags_r[c], bias_i[c]));
            short rh = f2bfs(h1r), ih = f2bfs(h1i);
            vhr[ci] = rh; vhi[ci] = ih;
            vlr[ci] = f2bfs(h1r - bfs2f(rh));
            vli[ci] = f2bfs(h1i - bfs2f(ih));
        }
        *(s16x8*)&H1[tl * 264 + cg * 8]       = vhr;
        *(s16x8*)&H1[tl * 264 + 64 + cg * 8]  = vhi;
        *(s16x8*)&H1[tl * 264 + 128 + cg * 8] = vlr;
        *(s16x8*)&H1[tl * 264 + 192 + cg * 8] = vli;
    }
    __syncthreads();

    // ---- GEMM1: A = H1 [32][264], B frags direct from W1f (L2)
    f32x4 acc[2][2] = {};
#pragma unroll
    for (int lc = 0; lc < 6; ++lc) {
        const int ka = ASRC[lc] * 64;
        const int kb = BSRC[lc];
#pragma unroll
        for (int kh = 0; kh < 2; ++kh) {
            s16x8 a0 = *(const s16x8*)&H1[frow * 264 + ka + kh * 32 + fcol];
            s16x8 a1 = *(const s16x8*)&H1[(16 + frow) * 264 + ka + kh * 32 + fcol];
#pragma unroll
            for (int n = 0; n < 2; ++n) {
                s16x8 bfv = W1v[(size_t)((((wv * 2 + n) * 4 + kb) * 2 + kh) * 64 + lane)];
                acc[0][n] = __builtin_amdgcn_mfma_f32_16x16x32_bf16(a0, bfv, acc[0][n], 0, 0, 0);
                acc[1][n] = __builtin_amdgcn_mfma_f32_16x16x32_bf16(a1, bfv, acc[1][n], 0, 0, 0);
            }
        }
    }
    __syncthreads();

    // ---- phase 3: acc -> aL (overwrites H1)
    const int rbase = (lane >> 4) * 4;
    const int cidx = lane & 15;
#pragma unroll
    for (int m = 0; m < 2; ++m)
#pragma unroll
        for (int n = 0; n < 2; ++n)
#pragma unroll
            for (int r = 0; r < 4; ++r)
                aL[(m * 16 + rbase + r) * 132 + wv * 32 + n * 16 + cidx] = acc[m][n][r];
    __syncthreads();

    // ---- phase 4: gelu (lane=t) -> H2
    {
        const float brelu = brelu_p[0];
        f32x4 ar0 = *(const f32x4*)&aL[tl * 132 + cg * 8];
        f32x4 ar1 = *(const f32x4*)&aL[tl * 132 + cg * 8 + 4];
        f32x4 ai0 = *(const f32x4*)&aL[tl * 132 + 64 + cg * 8];
        f32x4 ai1 = *(const f32x4*)&aL[tl * 132 + 64 + cg * 8 + 4];
        s16x8 vhr, vhi, vlr, vli;
#pragma unroll
        for (int ci = 0; ci < 8; ++ci) {
            float ar = (ci < 4) ? ar0[ci & 3] : ar1[ci & 3];
            float ai = (ci < 4) ? ai0[ci & 3] : ai1[ci & 3];
            float r = sqrtf(ar * ar + ai * ai);
            float g = gelu_exact(r + brelu);
            float h2r, h2i;
            if (r > 0.f) { float f = g / r; h2r = f * ar; h2i = f * ai; }
            else { h2r = g; h2i = 0.f; }
            short rh = f2bfs(h2r), ih = f2bfs(h2i);
            vhr[ci] = rh; vhi[ci] = ih;
            vlr[ci] = f2bfs(h2r - bfs2f(rh));
            vli[ci] = f2bfs(h2i - bfs2f(ih));
        }
        *(s16x8*)&H2[tl * 264 + cg * 8]       = vhr;
        *(s16x8*)&H2[tl * 264 + 64 + cg * 8]  = vhi;
        *(s16x8*)&H2[tl * 264 + 128 + cg * 8] = vlr;
        *(s16x8*)&H2[tl * 264 + 192 + cg * 8] = vli;
    }
    __syncthreads();

    // ---- GEMM2: A = H2, B frags from W2f
    f32x4 acc2[2][2] = {};
#pragma unroll
    for (int lc = 0; lc < 6; ++lc) {
        const int ka = ASRC[lc] * 64;
        const int kb = BSRC[lc];
#pragma unroll
        for (int kh = 0; kh < 2; ++kh) {
            s16x8 a0 = *(const s16x8*)&H2[frow * 264 + ka + kh * 32 + fcol];
            s16x8 a1 = *(const s16x8*)&H2[(16 + frow) * 264 + ka + kh * 32 + fcol];
#pragma unroll
            for (int n = 0; n < 2; ++n) {
                s16x8 bfv = W2v[(size_t)((((wv * 2 + n) * 4 + kb) * 2 + kh) * 64 + lane)];
                acc2[0][n] = __builtin_amdgcn_mfma_f32_16x16x32_bf16(a0, bfv, acc2[0][n], 0, 0, 0);
                acc2[1][n] = __builtin_amdgcn_mfma_f32_16x16x32_bf16(a1, bfv, acc2[1][n], 0, 0, 0);
            }
        }
    }
    // cL aliases aL (smemA): all aL reads completed before the barrier above
    // GEMM2; no thread reads smemA during GEMM2.
#pragma unroll
    for (int m = 0; m < 2; ++m)
#pragma unroll
        for (int n = 0; n < 2; ++n)
#pragma unroll
            for (int r = 0; r < 4; ++r)
                cL[(m * 16 + rbase + r) * 132 + wv * 32 + n * 16 + cidx] = acc2[m][n][r];
    __syncthreads();

    // ---- phase 8: gate + compact coalesced store (lane=t)
    if (valid) {
        int h = rows[t], j = cols[t];
        size_t wbase = (size_t)rs8[h] + j;
        f32x4 cr0 = *(const f32x4*)&cL[tl * 132 + cg * 8];
        f32x4 cr1 = *(const f32x4*)&cL[tl * 132 + cg * 8 + 4];
        f32x4 ci0 = *(const f32x4*)&cL[tl * 132 + 64 + cg * 8];
        f32x4 ci1 = *(const f32x4*)&cL[tl * 132 + 64 + cg * 8 + 4];
#pragma unroll
        for (int ci = 0; ci < 8; ++ci) {
            int c = cg * 8 + ci;
            float cr  = (ci < 4) ? cr0[ci & 3] : cr1[ci & 3];
            float cii = (ci < 4) ? ci0[ci & 3] : ci1[ci & 3];
            float xr = Xcr[(size_t)(b * 64 + c) * T128 + t];
            float xi = Xci[(size_t)(b * 64 + c) * T128 + t];
            float r3 = sqrtf(cr * cr + cii * cii);
            float gm = glu_mags[(size_t)c * T + t];
            float gp = glu_phases[(size_t)c * T + t];
            float sg = 1.0f / (1.0f + expf(-(r3 + gm)));
            float ux, uy;
            if (r3 > 0.f) { float ir3 = 1.0f / r3; ux = cr * ir3; uy = cii * ir3; }
            else { ux = 1.f; uy = 0.f; }
            float sp, cp;
            sincosf(gp, &sp, &cp);
            float gx = sg * (ux * cp - uy * sp);
            float gy = sg * (ux * sp + uy * cp);
            size_t base = (size_t)(b * 64 + c) * T8cap + wbase;
            Xgr[base] = __float2bfloat16(xr * gx - xi * gy);
            Xgi[base] = __float2bfloat16(xr * gy + xi * gx);
        }
    }
}

// ------- depthwise conv + add (bf16 y, h-major rows, 8-wide, XCD swizzle)
__global__ __launch_bounds__(256) void conv_add_kernel(
    const bf16* __restrict__ y, const float* __restrict__ dw,
    float* __restrict__ out)
{
    const int nb = gridDim.x;
    const int chunk = nb >> 3;
    const int orig = blockIdx.x;
    const int swz = (orig & 7) * chunk + (orig >> 3);   // bijective: nb % 8 == 0
    int g = swz * 256 + threadIdx.x;
    int w8 = g % 90;
    int rem = g / 90;
    int h = rem % Hh;
    int bc = rem / Hh;
    int c = bc & (Cc - 1);
    int w = w8 * 8;
    int walt = (w >= Ww / 2) ? (w - Ww / 2) : (w + Ww / 2);
    float acc[8];
    {
        s16x8 v0 = *(const s16x8*)&y[((size_t)h * BC + bc) * NI + w];
#pragma unroll
        for (int e = 0; e < 8; ++e) acc[e] = bfs2f(v0[e]);
    }
#pragma unroll
    for (int k = 0; k < 11; ++k) {
        int hp = h + k - 5;
        int hh, ww;
        if (hp < 0)        { hh = -1 - hp;         ww = walt; }
        else if (hp >= Hh) { hh = 2 * Hh - 1 - hp; ww = walt; }
        else               { hh = hp;              ww = w; }
        s16x8 v = *(const s16x8*)&y[((size_t)hh * BC + bc) * NI + ww];
        float dwk = dw[c * 11 + k];
#pragma unroll
        for (int e = 0; e < 8; ++e)
            acc[e] = fmaf(dwk, bfs2f(v[e]), acc[e]);
    }
    float* ob = &out[((size_t)bc * Hh + h) * Ww + w];
    *(float4*)&ob[0] = make_float4(acc[0], acc[1], acc[2], acc[3]);
    *(float4*)&ob[4] = make_float4(acc[4], acc[5], acc[6], acc[7]);
}

// ------------------------------------------------------------------ launch
extern "C" void kernel_launch(void* const* d_in, const int* in_sizes, int n_in,
                              void* d_out, int out_size, void* d_ws, size_t ws_size,
                              hipStream_t stream)
{
    const float* x      = (const float*)d_in[0];
    const float* mean_r = (const float*)d_in[1];
    const float* mean_i = (const float*)d_in[2];
    const float* stdv   = (const float*)d_in[3];
    const float* mags_r = (const float*)d_in[4];
    const float* mags_i = (const float*)d_in[5];
    const float* bias_r = (const float*)d_in[6];
    const float* bias_i = (const float*)d_in[7];
    const float* w1_r   = (const float*)d_in[8];
    const float* w1_i   = (const float*)d_in[9];
    const float* brelu  = (const float*)d_in[10];
    const float* w2_r   = (const float*)d_in[11];
    const float* w2_i   = (const float*)d_in[12];
    const float* glu_m  = (const float*)d_in[13];
    const float* glu_p  = (const float*)d_in[14];
    const float* dw     = (const float*)d_in[15];
    const int*   rows   = (const int*)d_in[16];
    const int*   cols   = (const int*)d_in[17];
    const int T = in_sizes[16];
    const int T128 = ((T + 127) / 128) * 128;
    const int T8cap = ((T + 7 * Hh) + 127) & ~127;

    char* ws = (char*)d_ws;
    const size_t SApc  = (size_t)CM * KA * 2;             // 35,389,440
    const size_t XC_SZ = (size_t)BC * T128 * 4;           // ~42.7 MB
    const size_t XG_SZ = (size_t)BC * T8cap * 2;          // ~22.0 MB
    bf16*  Ap  = (bf16*)ws;
    bf16*  Aq  = (bf16*)(ws + SApc);
    float* Xcr = (float*)(ws + 2 * SApc);
    float* Xci = (float*)(ws + 2 * SApc + XC_SZ);
    bf16*  Xgr = (bf16*)ws;
    bf16*  Xgi = (bf16*)(ws + XG_SZ);
    bf16*  y   = (bf16*)(ws + 2 * XG_SZ);
    size_t boff = 2 * SApc + 2 * XC_SZ;                   // ~156.1 MB
    bf16*  Bce = (bf16*)(ws + boff);
    bf16*  Bse = (bf16*)(ws + boff + (size_t)NF * KF3 * 2);
    bf16*  Bti = (bf16*)(ws + boff + 2 * (size_t)NF * KF3 * 2);
    bf16*  W1f = (bf16*)(ws + boff + 2 * (size_t)NF * KF3 * 2 + (size_t)NI * KI * 2);
    bf16*  W2f = W1f + 32768;
    int*   rs  = (int*)(W2f + 32768);
    int*   rs8 = rs + (Hh + 2);

    build_bfwd_kernel<<<(NF * KF3 + 255) / 256, 256, 0, stream>>>(Bce, Bse);
    build_binv_kernel<<<(NI * KI + 255) / 256, 256, 0, stream>>>(Bti);
    build_wf_kernel<<<(2 * 32768 + 255) / 256, 256, 0, stream>>>(
        w1_r, w1_i, w2_r, w2_i, W1f, W2f);
    row_starts_kernel<<<1, 512, 0, stream>>>(rows, T, rs, rs8);

    for (int ch = 0; ch < CHUNKS; ++ch) {
        pack_kernel<<<(CM * KA + 255) / 256, 256, 0, stream>>>(
            x, Ap, Aq, ch * HPC);
        gemm_fwd_compact_kernel<<<1080, 256, 0, stream>>>(
            Ap, Aq, Bce, Bse, Xcr, Xci, rs, T128, ch * HPC);
    }

    fill_zero_kernel<<<2048, 256, 0, stream>>>((uint4*)Xgr, (long)(2 * XG_SZ / 16));

    const int nT32 = (T + 31) / 32;
    middle_fused_kernel<<<dim3(nT32, Bb), 256, 0, stream>>>(
        Xcr, Xci, Xgr, Xgi, mean_r, mean_i, stdv, mags_r, mags_i,
        bias_r, bias_i, W1f, W2f, brelu, glu_m, glu_p, rows, cols, rs8,
        T, T128, T8cap);

    gemm_inv_kernel<<<2160, 256, 0, stream>>>(
        Xgr, Xgi, Bti, rs8, y, T8cap);

    conv_add_kernel<<<(Bb * Cc * Hh * 90) / 256, 256, 0, stream>>>(y, dw, (float*)d_out);
}

// Round 21
// 515.279 us; speedup vs baseline: 1.1281x; 1.1281x over previous
//
#include <hip/hip_runtime.h>
#include <hip/hip_bf16.h>
#include <math.h>

#define Hh 360
#define Ww 720
#define Cc 64
#define Bb 2
#define BC (Bb*Cc)        // 128
#define Mrows (BC*Hh)     // 46080
#define CHUNKS 2
#define CM (Mrows/CHUNKS) // 23040
#define HPC (Hh/CHUNKS)   // 180 latitudes per chunk
#define KA 768            // A row: [hi(384) | lo(384)]
#define KF3 1152          // GEMM K loop: [hi.Bhi | lo.Bhi | hi.Blo]
#define NF 384            // fwd N (361 bins padded)
#define KI 768            // inv K: [Re(384) | Im(384)]
#define NI 768            // inv C row stride (720 used)
#define NSTORE_INV 720
#define SCALE 0.037267799624996496f   // 1/sqrt(720)
#define TWO_PI 6.2831853071795864769f

typedef __attribute__((ext_vector_type(8))) short s16x8;
typedef __attribute__((ext_vector_type(4))) float f32x4;
typedef __hip_bfloat16 bf16;

__device__ __forceinline__ void gload_lds16(const void* g, void* l) {
    __builtin_amdgcn_global_load_lds(
        (const __attribute__((address_space(1))) unsigned int*)g,
        (__attribute__((address_space(3))) unsigned int*)l, 16, 0, 0);
}
__device__ __forceinline__ short f2bfs(float v) {
    bf16 h = __float2bfloat16(v); short s; __builtin_memcpy(&s, &h, 2); return s;
}
__device__ __forceinline__ float bfs2f(short s) {
    bf16 h; __builtin_memcpy(&h, &s, 2); return __bfloat162float(h);
}

// ---------------------------------------------------------- B-matrix builds
// B stays 1152-wide: [Bhi | Bhi | Blo].
__global__ __launch_bounds__(256) void build_bfwd_kernel(bf16* __restrict__ Bc,
                                                         bf16* __restrict__ Bs) {
    int g = blockIdx.x * 256 + threadIdx.x;
    if (g >= NF * KF3) return;
    int wext = g % KF3;
    int j = g / KF3;
    int blk = wext / 384;
    int w = wext - blk * 384;
    float c = 0.f, s = 0.f;
    if (w <= 360 && j <= 360) {
        int idx = (j * w) % Ww;
        float a = (TWO_PI / Ww) * (float)idx;
        float sv, cv;
        sincosf(a, &sv, &cv);
        c = SCALE * cv;
        s = -SCALE * sv;
    }
    bf16 chi = __float2bfloat16(c);
    bf16 shi = __float2bfloat16(s);
    if (blk == 2) {
        Bc[g] = __float2bfloat16(c - __bfloat162float(chi));
        Bs[g] = __float2bfloat16(s - __bfloat162float(shi));
    } else {
        Bc[g] = chi;
        Bs[g] = shi;
    }
}

__global__ __launch_bounds__(256) void build_binv_kernel(bf16* __restrict__ Bi) {
    int g = blockIdx.x * 256 + threadIdx.x;
    if (g >= NI * KI) return;
    int k = g % KI, n = g / KI;
    float v = 0.f;
    if (n < NSTORE_INV) {
        if (k <= 360) {
            int j = k;
            float f = (j == 0 || j == 360) ? 1.f : 2.f;
            int idx = (j * n) % Ww;
            v = SCALE * f * cosf((TWO_PI / Ww) * (float)idx);
        } else if (k >= 384 && k <= 744) {
            int j = k - 384;
            int idx = (j * n) % Ww;
            v = -2.f * SCALE * sinf((TWO_PI / Ww) * (float)idx);
        }
    }
    Bi[g] = __float2bfloat16(v);
}

// W fragment-packed: s16x8 index = fid*64 + lane, fid = ((n16*4 + kb)*2 + kh).
__global__ __launch_bounds__(256) void build_wf_kernel(
    const float* __restrict__ w1_r, const float* __restrict__ w1_i,
    const float* __restrict__ w2_r, const float* __restrict__ w2_i,
    bf16* __restrict__ W1f, bf16* __restrict__ W2f)
{
    int g = blockIdx.x * 256 + threadIdx.x;
    if (g >= 2 * 32768) return;
    int which = g >> 15;
    int gg = g & 32767;
    int e = gg & 7, lane = (gg >> 3) & 63, kh = (gg >> 9) & 1;
    int kb = (gg >> 10) & 3, n16 = (gg >> 12) & 7;
    int frow = lane & 15, fcol = (lane >> 4) * 8;
    int n = n16 * 16 + frow;
    int kfull = kb * 64 + kh * 32 + fcol + e;
    int kk = kfull & 127, islo = kfull >> 7;
    const float* wr = which ? w2_r : w1_r;
    const float* wi = which ? w2_i : w1_i;
    float v;
    if (n < 64) v = (kk < 64) ? wr[n * 64 + kk] : -wi[n * 64 + kk - 64];
    else { int p = n - 64; v = (kk < 64) ? wi[p * 64 + kk] : wr[p * 64 + kk - 64]; }
    bf16 h = __float2bfloat16(v);
    bf16 out = islo ? __float2bfloat16(v - __bfloat162float(h)) : h;
    (which ? W2f : W1f)[gg] = out;
}

// ---------------------------------------- row starts (compact + 8-padded)
__global__ __launch_bounds__(512) void row_starts_kernel(const int* __restrict__ rows,
                                                         int T, int* __restrict__ rs,
                                                         int* __restrict__ rs8) {
    int h = threadIdx.x;
    if (h <= Hh) {
        if (h == Hh) rs[Hh] = T;
        else {
            int lo = 0, hi = T;
            while (lo < hi) {
                int mid = (lo + hi) >> 1;
                if (rows[mid] < h) lo = mid + 1; else hi = mid;
            }
            rs[h] = lo;
        }
    }
    __syncthreads();
    if (threadIdx.x == 0) {
        int acc = 0;
        for (int i = 0; i < Hh; ++i) {
            rs8[i] = acc;
            int cnt = rs[i + 1] - rs[i];
            acc += (cnt + 7) & ~7;
        }
        rs8[Hh] = acc;
    }
}

// ------------------- pack x chunk -> A [hi|lo] (768-wide), h-major rows
__global__ __launch_bounds__(256) void pack_kernel(const float* __restrict__ x,
                                                   bf16* __restrict__ Ap,
                                                   bf16* __restrict__ Aq,
                                                   int hbase) {
    int g = blockIdx.x * 256 + threadIdx.x;
    if (g >= CM * KA) return;
    int wext = g % KA;
    int r = g / KA;
    int hl = r >> 7;
    int bc = r & 127;
    const float* xrow = x + ((size_t)bc * Hh + hbase + hl) * Ww;
    int islo = (wext >= 384);
    int w = islo ? (wext - 384) : wext;
    float p = 0.f, q = 0.f;
    if (w == 0 || w == 360) {
        p = xrow[w];
    } else if (w < 360) {
        float a = xrow[w];
        float b = xrow[Ww - w];
        p = a + b;
        q = a - b;
    }
    bf16 phi = __float2bfloat16(p);
    bf16 qhi = __float2bfloat16(q);
    if (islo) {
        Ap[g] = __float2bfloat16(p - __bfloat162float(phi));
        Aq[g] = __float2bfloat16(q - __bfloat162float(qhi));
    } else {
        Ap[g] = phi;
        Aq[g] = qhi;
    }
}

// ----------------------------------------------------------------- zero fill
__global__ __launch_bounds__(256) void fill_zero_kernel(uint4* __restrict__ p, long n) {
    long i = (long)blockIdx.x * 256 + threadIdx.x;
    long stride = (long)gridDim.x * 256;
    uint4 z = make_uint4(0u, 0u, 0u, 0u);
    for (; i < n; i += stride) p[i] = z;
}

// ------------------- fwd MFMA GEMM, h-uniform tiles + early exit + compact C
__global__ __launch_bounds__(256) void gemm_fwd_compact_kernel(
    const bf16* __restrict__ Ap, const bf16* __restrict__ Aq,
    const bf16* __restrict__ Bc, const bf16* __restrict__ Bsm,
    float* __restrict__ Xcr, float* __restrict__ Xci,
    const int* __restrict__ rs, int T128, int hbase)
{
    __shared__ __align__(128) bf16 As[128][64];
    __shared__ __align__(128) bf16 Bs[128][64];
    const int h = hbase + blockIdx.x;       // one latitude per m-tile
    const int t0 = rs[h];
    const int cnt = rs[h + 1] - t0;
    const int n0 = blockIdx.y * 128;
    if (n0 >= cnt) return;                   // tile stores nothing: dead work
    const bf16* A  = blockIdx.z ? Aq : Ap;
    const bf16* Bt = blockIdx.z ? Bsm : Bc;
    float* Xc      = blockIdx.z ? Xci : Xcr;
    const int tid = threadIdx.x;
    const int lane = tid & 63;
    const int wave = tid >> 6;
    const int m0 = blockIdx.x * 128;
    const int wr = (wave >> 1) * 64;
    const int wc = (wave & 1) * 64;
    const int srow = tid >> 3;
    const int scol = (tid & 7) << 3;
    f32x4 acc[4][4] = {};
    for (int k0 = 0; k0 < KF3; k0 += 64) {
        const int ka0 = (k0 >= 768) ? (k0 - 768) : k0;
#pragma unroll
        for (int i = 0; i < 4; ++i) {
            const bf16* ga = A  + (size_t)(m0 + i * 32 + srow) * KA + ka0 + scol;
            const bf16* gb = Bt + (size_t)(n0 + i * 32 + srow) * KF3 + k0 + scol;
            gload_lds16(ga, ((char*)&As[0][0]) + (size_t)(i * 256 + tid) * 16);
            gload_lds16(gb, ((char*)&Bs[0][0]) + (size_t)(i * 256 + tid) * 16);
        }
        __syncthreads();
#pragma unroll
        for (int kk = 0; kk < 64; kk += 32) {
            s16x8 a[4], b[4];
#pragma unroll
            for (int m = 0; m < 4; ++m)
                a[m] = *(const s16x8*)&As[wr + m * 16 + (lane & 15)][kk + (lane >> 4) * 8];
#pragma unroll
            for (int n = 0; n < 4; ++n)
                b[n] = *(const s16x8*)&Bs[wc + n * 16 + (lane & 15)][kk + (lane >> 4) * 8];
#pragma unroll
            for (int m = 0; m < 4; ++m)
#pragma unroll
                for (int n = 0; n < 4; ++n)
                    acc[m][n] = __builtin_amdgcn_mfma_f32_16x16x32_bf16(a[m], b[n], acc[m][n], 0, 0, 0);
        }
        __syncthreads();
    }
    const int rbase = (lane >> 4) * 4;
    const int cidx = lane & 15;
#pragma unroll
    for (int m = 0; m < 4; ++m) {
#pragma unroll
        for (int r = 0; r < 4; ++r) {
            int bc = wr + m * 16 + rbase + r;   // local row within h-tile
#pragma unroll
            for (int n = 0; n < 4; ++n) {
                int j = n0 + wc + n * 16 + cidx;
                if (j < cnt)
                    Xc[(size_t)bc * T128 + t0 + j] = acc[m][n][r];
            }
        }
    }
}

// -------------- inverse GEMM, h-uniform tiles + K-tile early-skip; y h-major
__global__ __launch_bounds__(256) void gemm_inv_kernel(
    const bf16* __restrict__ Xgr, const bf16* __restrict__ Xgi,
    const bf16* __restrict__ Bt, const int* __restrict__ rs8,
    bf16* __restrict__ C, int T8cap)
{
    __shared__ __align__(128) bf16 As[128][64];
    __shared__ __align__(128) bf16 Bs[128][64];
    const int h = blockIdx.x;               // one latitude per m-tile
    const int t0v = rs8[h];
    const int cnt8 = rs8[h + 1] - t0v;
    const int n0 = blockIdx.y * 128;
    const int tid = threadIdx.x;
    const int lane = tid & 63;
    const int wave = tid >> 6;
    const int wr = (wave >> 1) * 64;
    const int wc = (wave & 1) * 64;
    const int srow = tid >> 3;
    const int scol = (tid & 7) << 3;
    f32x4 acc[4][4] = {};
    for (int k0 = 0; k0 < KI; k0 += 64) {
        const int jb = (k0 < 384) ? k0 : (k0 - 384);
        if (jb >= cnt8) continue;           // A-tile all zero: acc += 0, skip
        const bf16* base = (k0 < 384) ? Xgr : Xgi;
        const int j0 = jb + scol;
#pragma unroll
        for (int i = 0; i < 4; ++i)
            gload_lds16(Bt + (size_t)(n0 + i * 32 + srow) * KI + k0 + scol,
                        ((char*)&Bs[0][0]) + (size_t)(i * 256 + tid) * 16);
#pragma unroll
        for (int i = 0; i < 4; ++i) {
            int bc = i * 32 + srow;
            s16x8 v = (s16x8){0, 0, 0, 0, 0, 0, 0, 0};
            if (j0 < cnt8)
                v = *(const s16x8*)(base + (size_t)bc * T8cap + t0v + j0);
            *(s16x8*)&As[bc][scol] = v;
        }
        __syncthreads();
#pragma unroll
        for (int kk = 0; kk < 64; kk += 32) {
            s16x8 a[4], b[4];
#pragma unroll
            for (int m = 0; m < 4; ++m)
                a[m] = *(const s16x8*)&As[wr + m * 16 + (lane & 15)][kk + (lane >> 4) * 8];
#pragma unroll
            for (int n = 0; n < 4; ++n)
                b[n] = *(const s16x8*)&Bs[wc + n * 16 + (lane & 15)][kk + (lane >> 4) * 8];
#pragma unroll
            for (int m = 0; m < 4; ++m)
#pragma unroll
                for (int n = 0; n < 4; ++n)
                    acc[m][n] = __builtin_amdgcn_mfma_f32_16x16x32_bf16(a[m], b[n], acc[m][n], 0, 0, 0);
        }
        __syncthreads();
    }
    const int rbase = (lane >> 4) * 4;
    const int cidx = lane & 15;
#pragma unroll
    for (int m = 0; m < 4; ++m) {
#pragma unroll
        for (int n = 0; n < 4; ++n) {
            int gcol = n0 + wc + n * 16 + cidx;
            if (gcol < NSTORE_INV) {
#pragma unroll
                for (int r = 0; r < 4; ++r) {
                    int bc = wr + m * 16 + rbase + r;
                    C[(size_t)(h * BC + bc) * NI + gcol] = __float2bfloat16(acc[m][n][r]);
                }
            }
        }
    }
}

// ------------------------------------------------ fused middle stage (v3)
// FROZEN: verbatim green r17 middle. Three independent edits (fastmath,
// register-cache, both) each broke correctness (r12/r18/r19) — do not touch.
__device__ __forceinline__ float gelu_exact(float v) {
    return 0.5f * v * (1.0f + erff(v * 0.7071067811865476f));
}

__global__ __launch_bounds__(256, 4) void middle_fused_kernel(
    const float* __restrict__ Xcr, const float* __restrict__ Xci,
    bf16* __restrict__ Xgr, bf16* __restrict__ Xgi,
    const float* __restrict__ mean_r, const float* __restrict__ mean_i,
    const float* __restrict__ stdv,
    const float* __restrict__ mags_r, const float* __restrict__ mags_i,
    const float* __restrict__ bias_r, const float* __restrict__ bias_i,
    const bf16* __restrict__ W1f, const bf16* __restrict__ W2f,
    const float* __restrict__ brelu_p,
    const float* __restrict__ glu_mags, const float* __restrict__ glu_phases,
    const int* __restrict__ rows, const int* __restrict__ cols,
    const int* __restrict__ rs8,
    int T, int T128, int T8cap)
{
    __shared__ __align__(16) char smemA[32 * 264 * 2];   // 16,896 B
    __shared__ __align__(16) char smemB[32 * 264 * 2];
    bf16*  H1 = (bf16*)smemA;    // [32][264] hi/lo split input
    float* aL = (float*)smemA;   // [32][132] GEMM1 result
    float* cL = (float*)smemA;   // [32][132] GEMM2 result
    bf16*  H2 = (bf16*)smemB;    // [32][264] gelu output

    const int tid = threadIdx.x;
    const int b = blockIdx.y;
    const int t0 = blockIdx.x * 32;
    const int tl = tid & 31;
    const int cg = tid >> 5;          // 0..7
    const int t = t0 + tl;
    const bool valid = (t < T);
    const int lane = tid & 63;
    const int wv = tid >> 6;          // 0..3
    const int frow = lane & 15;
    const int fcol = (lane >> 4) * 8;
    const s16x8* W1v = (const s16x8*)W1f;
    const s16x8* W2v = (const s16x8*)W2f;
    constexpr int ASRC[6] = {0, 1, 2, 3, 0, 1};
    constexpr int BSRC[6] = {0, 1, 0, 1, 2, 3};

    // ---- phase 1: normalize -> H1 (lane=t, coalesced global reads)
    {
        float mr = 0.f, mi_ = 0.f, isd = 0.f;
        if (valid) { mr = mean_r[t]; mi_ = mean_i[t]; isd = 1.0f / (1e-12f + stdv[t]); }
        s16x8 vhr, vhi, vlr, vli;
#pragma unroll
        for (int ci = 0; ci < 8; ++ci) {
            int c = cg * 8 + ci;
            float xr = 0.f, xi = 0.f;
            if (valid) {
                xr = Xcr[(size_t)(b * 64 + c) * T128 + t];
                xi = Xci[(size_t)(b * 64 + c) * T128 + t];
            }
            float hr = (xr - mr) * isd;
            float hi = (xi - mi_) * isd;
            float h1r = fmaf(hr, mags_r[c], fmaf(-hi, mags_i[c], bias_r[c]));
            float h1i = fmaf(hr, mags_i[c], fmaf(hi, mags_r[c], bias_i[c]));
            short rh = f2bfs(h1r), ih = f2bfs(h1i);
            vhr[ci] = rh; vhi[ci] = ih;
            vlr[ci] = f2bfs(h1r - bfs2f(rh));
            vli[ci] = f2bfs(h1i - bfs2f(ih));
        }
        *(s16x8*)&H1[tl * 264 + cg * 8]       = vhr;
        *(s16x8*)&H1[tl * 264 + 64 + cg * 8]  = vhi;
        *(s16x8*)&H1[tl * 264 + 128 + cg * 8] = vlr;
        *(s16x8*)&H1[tl * 264 + 192 + cg * 8] = vli;
    }
    __syncthreads();

    // ---- GEMM1: A = H1 [32][264], B frags direct from W1f (L2)
    f32x4 acc[2][2] = {};
#pragma unroll
    for (int lc = 0; lc < 6; ++lc) {
        const int ka = ASRC[lc] * 64;
        const int kb = BSRC[lc];
#pragma unroll
        for (int kh = 0; kh < 2; ++kh) {
            s16x8 a0 = *(const s16x8*)&H1[frow * 264 + ka + kh * 32 + fcol];
            s16x8 a1 = *(const s16x8*)&H1[(16 + frow) * 264 + ka + kh * 32 + fcol];
#pragma unroll
            for (int n = 0; n < 2; ++n) {
                s16x8 bfv = W1v[(size_t)((((wv * 2 + n) * 4 + kb) * 2 + kh) * 64 + lane)];
                acc[0][n] = __builtin_amdgcn_mfma_f32_16x16x32_bf16(a0, bfv, acc[0][n], 0, 0, 0);
                acc[1][n] = __builtin_amdgcn_mfma_f32_16x16x32_bf16(a1, bfv, acc[1][n], 0, 0, 0);
            }
        }
    }
    __syncthreads();

    // ---- phase 3: acc -> aL (overwrites H1)
    const int rbase = (lane >> 4) * 4;
    const int cidx = lane & 15;
#pragma unroll
    for (int m = 0; m < 2; ++m)
#pragma unroll
        for (int n = 0; n < 2; ++n)
#pragma unroll
            for (int r = 0; r < 4; ++r)
                aL[(m * 16 + rbase + r) * 132 + wv * 32 + n * 16 + cidx] = acc[m][n][r];
    __syncthreads();

    // ---- phase 4: gelu (lane=t) -> H2
    {
        const float brelu = brelu_p[0];
        f32x4 ar0 = *(const f32x4*)&aL[tl * 132 + cg * 8];
        f32x4 ar1 = *(const f32x4*)&aL[tl * 132 + cg * 8 + 4];
        f32x4 ai0 = *(const f32x4*)&aL[tl * 132 + 64 + cg * 8];
        f32x4 ai1 = *(const f32x4*)&aL[tl * 132 + 64 + cg * 8 + 4];
        s16x8 vhr, vhi, vlr, vli;
#pragma unroll
        for (int ci = 0; ci < 8; ++ci) {
            float ar = (ci < 4) ? ar0[ci & 3] : ar1[ci & 3];
            float ai = (ci < 4) ? ai0[ci & 3] : ai1[ci & 3];
            float r = sqrtf(ar * ar + ai * ai);
            float g = gelu_exact(r + brelu);
            float h2r, h2i;
            if (r > 0.f) { float f = g / r; h2r = f * ar; h2i = f * ai; }
            else { h2r = g; h2i = 0.f; }
            short rh = f2bfs(h2r), ih = f2bfs(h2i);
            vhr[ci] = rh; vhi[ci] = ih;
            vlr[ci] = f2bfs(h2r - bfs2f(rh));
            vli[ci] = f2bfs(h2i - bfs2f(ih));
        }
        *(s16x8*)&H2[tl * 264 + cg * 8]       = vhr;
        *(s16x8*)&H2[tl * 264 + 64 + cg * 8]  = vhi;
        *(s16x8*)&H2[tl * 264 + 128 + cg * 8] = vlr;
        *(s16x8*)&H2[tl * 264 + 192 + cg * 8] = vli;
    }
    __syncthreads();

    // ---- GEMM2: A = H2, B frags from W2f
    f32x4 acc2[2][2] = {};
#pragma unroll
    for (int lc = 0; lc < 6; ++lc) {
        const int ka = ASRC[lc] * 64;
        const int kb = BSRC[lc];
#pragma unroll
        for (int kh = 0; kh < 2; ++kh) {
            s16x8 a0 = *(const s16x8*)&H2[frow * 264 + ka + kh * 32 + fcol];
            s16x8 a1 = *(const s16x8*)&H2[(16 + frow) * 264 + ka + kh * 32 + fcol];
#pragma unroll
            for (int n = 0; n < 2; ++n) {
                s16x8 bfv = W2v[(size_t)((((wv * 2 + n) * 4 + kb) * 2 + kh) * 64 + lane)];
                acc2[0][n] = __builtin_amdgcn_mfma_f32_16x16x32_bf16(a0, bfv, acc2[0][n], 0, 0, 0);
                acc2[1][n] = __builtin_amdgcn_mfma_f32_16x16x32_bf16(a1, bfv, acc2[1][n], 0, 0, 0);
            }
        }
    }
    // cL aliases aL (smemA): all aL reads completed before the barrier above
    // GEMM2; no thread reads smemA during GEMM2.
#pragma unroll
    for (int m = 0; m < 2; ++m)
#pragma unroll
        for (int n = 0; n < 2; ++n)
#pragma unroll
            for (int r = 0; r < 4; ++r)
                cL[(m * 16 + rbase + r) * 132 + wv * 32 + n * 16 + cidx] = acc2[m][n][r];
    __syncthreads();

    // ---- phase 8: gate + compact coalesced store (lane=t)
    if (valid) {
        int h = rows[t], j = cols[t];
        size_t wbase = (size_t)rs8[h] + j;
        f32x4 cr0 = *(const f32x4*)&cL[tl * 132 + cg * 8];
        f32x4 cr1 = *(const f32x4*)&cL[tl * 132 + cg * 8 + 4];
        f32x4 ci0 = *(const f32x4*)&cL[tl * 132 + 64 + cg * 8];
        f32x4 ci1 = *(const f32x4*)&cL[tl * 132 + 64 + cg * 8 + 4];
#pragma unroll
        for (int ci = 0; ci < 8; ++ci) {
            int c = cg * 8 + ci;
            float cr  = (ci < 4) ? cr0[ci & 3] : cr1[ci & 3];
            float cii = (ci < 4) ? ci0[ci & 3] : ci1[ci & 3];
            float xr = Xcr[(size_t)(b * 64 + c) * T128 + t];
            float xi = Xci[(size_t)(b * 64 + c) * T128 + t];
            float r3 = sqrtf(cr * cr + cii * cii);
            float gm = glu_mags[(size_t)c * T + t];
            float gp = glu_phases[(size_t)c * T + t];
            float sg = 1.0f / (1.0f + expf(-(r3 + gm)));
            float ux, uy;
            if (r3 > 0.f) { float ir3 = 1.0f / r3; ux = cr * ir3; uy = cii * ir3; }
            else { ux = 1.f; uy = 0.f; }
            float sp, cp;
            sincosf(gp, &sp, &cp);
            float gx = sg * (ux * cp - uy * sp);
            float gy = sg * (ux * sp + uy * cp);
            size_t base = (size_t)(b * 64 + c) * T8cap + wbase;
            Xgr[base] = __float2bfloat16(xr * gx - xi * gy);
            Xgi[base] = __float2bfloat16(xr * gy + xi * gx);
        }
    }
}

// ------- depthwise conv + add (bf16 y, h-major rows, 8-wide, XCD swizzle)
__global__ __launch_bounds__(256) void conv_add_kernel(
    const bf16* __restrict__ y, const float* __restrict__ dw,
    float* __restrict__ out)
{
    const int nb = gridDim.x;
    const int chunk = nb >> 3;
    const int orig = blockIdx.x;
    const int swz = (orig & 7) * chunk + (orig >> 3);   // bijective: nb % 8 == 0
    int g = swz * 256 + threadIdx.x;
    int w8 = g % 90;
    int rem = g / 90;
    int h = rem % Hh;
    int bc = rem / Hh;
    int c = bc & (Cc - 1);
    int w = w8 * 8;
    int walt = (w >= Ww / 2) ? (w - Ww / 2) : (w + Ww / 2);
    float acc[8];
    {
        s16x8 v0 = *(const s16x8*)&y[((size_t)h * BC + bc) * NI + w];
#pragma unroll
        for (int e = 0; e < 8; ++e) acc[e] = bfs2f(v0[e]);
    }
#pragma unroll
    for (int k = 0; k < 11; ++k) {
        int hp = h + k - 5;
        int hh, ww;
        if (hp < 0)        { hh = -1 - hp;         ww = walt; }
        else if (hp >= Hh) { hh = 2 * Hh - 1 - hp; ww = walt; }
        else               { hh = hp;              ww = w; }
        s16x8 v = *(const s16x8*)&y[((size_t)hh * BC + bc) * NI + ww];
        float dwk = dw[c * 11 + k];
#pragma unroll
        for (int e = 0; e < 8; ++e)
            acc[e] = fmaf(dwk, bfs2f(v[e]), acc[e]);
    }
    float* ob = &out[((size_t)bc * Hh + h) * Ww + w];
    *(float4*)&ob[0] = make_float4(acc[0], acc[1], acc[2], acc[3]);
    *(float4*)&ob[4] = make_float4(acc[4], acc[5], acc[6], acc[7]);
}

// ------------------------------------------------------------------ launch
extern "C" void kernel_launch(void* const* d_in, const int* in_sizes, int n_in,
                              void* d_out, int out_size, void* d_ws, size_t ws_size,
                              hipStream_t stream)
{
    const float* x      = (const float*)d_in[0];
    const float* mean_r = (const float*)d_in[1];
    const float* mean_i = (const float*)d_in[2];
    const float* stdv   = (const float*)d_in[3];
    const float* mags_r = (const float*)d_in[4];
    const float* mags_i = (const float*)d_in[5];
    const float* bias_r = (const float*)d_in[6];
    const float* bias_i = (const float*)d_in[7];
    const float* w1_r   = (const float*)d_in[8];
    const float* w1_i   = (const float*)d_in[9];
    const float* brelu  = (const float*)d_in[10];
    const float* w2_r   = (const float*)d_in[11];
    const float* w2_i   = (const float*)d_in[12];
    const float* glu_m  = (const float*)d_in[13];
    const float* glu_p  = (const float*)d_in[14];
    const float* dw     = (const float*)d_in[15];
    const int*   rows   = (const int*)d_in[16];
    const int*   cols   = (const int*)d_in[17];
    const int T = in_sizes[16];
    const int T128 = ((T + 127) / 128) * 128;
    const int T8cap = ((T + 7 * Hh) + 127) & ~127;

    char* ws = (char*)d_ws;
    const size_t SApc  = (size_t)CM * KA * 2;             // 35,389,440
    const size_t XC_SZ = (size_t)BC * T128 * 4;           // ~42.7 MB
    const size_t XG_SZ = (size_t)BC * T8cap * 2;          // ~22.0 MB
    bf16*  Ap  = (bf16*)ws;
    bf16*  Aq  = (bf16*)(ws + SApc);
    float* Xcr = (float*)(ws + 2 * SApc);
    float* Xci = (float*)(ws + 2 * SApc + XC_SZ);
    bf16*  Xgr = (bf16*)ws;
    bf16*  Xgi = (bf16*)(ws + XG_SZ);
    bf16*  y   = (bf16*)(ws + 2 * XG_SZ);
    size_t boff = 2 * SApc + 2 * XC_SZ;                   // ~156.1 MB
    bf16*  Bce = (bf16*)(ws + boff);
    bf16*  Bse = (bf16*)(ws + boff + (size_t)NF * KF3 * 2);
    bf16*  Bti = (bf16*)(ws + boff + 2 * (size_t)NF * KF3 * 2);
    bf16*  W1f = (bf16*)(ws + boff + 2 * (size_t)NF * KF3 * 2 + (size_t)NI * KI * 2);
    bf16*  W2f = W1f + 32768;
    int*   rs  = (int*)(W2f + 32768);
    int*   rs8 = rs + (Hh + 2);

    build_bfwd_kernel<<<(NF * KF3 + 255) / 256, 256, 0, stream>>>(Bce, Bse);
    build_binv_kernel<<<(NI * KI + 255) / 256, 256, 0, stream>>>(Bti);
    build_wf_kernel<<<(2 * 32768 + 255) / 256, 256, 0, stream>>>(
        w1_r, w1_i, w2_r, w2_i, W1f, W2f);
    row_starts_kernel<<<1, 512, 0, stream>>>(rows, T, rs, rs8);

    for (int ch = 0; ch < CHUNKS; ++ch) {
        pack_kernel<<<(CM * KA + 255) / 256, 256, 0, stream>>>(
            x, Ap, Aq, ch * HPC);
        gemm_fwd_compact_kernel<<<dim3(CM / 128, NF / 128, 2), 256, 0, stream>>>(
            Ap, Aq, Bce, Bse, Xcr, Xci, rs, T128, ch * HPC);
    }

    fill_zero_kernel<<<2048, 256, 0, stream>>>((uint4*)Xgr, (long)(2 * XG_SZ / 16));

    const int nT32 = (T + 31) / 32;
    middle_fused_kernel<<<dim3(nT32, Bb), 256, 0, stream>>>(
        Xcr, Xci, Xgr, Xgi, mean_r, mean_i, stdv, mags_r, mags_i,
        bias_r, bias_i, W1f, W2f, brelu, glu_m, glu_p, rows, cols, rs8,
        T, T128, T8cap);

    gemm_inv_kernel<<<dim3(Hh, NI / 128), 256, 0, stream>>>(
        Xgr, Xgi, Bti, rs8, y, T8cap);

    conv_add_kernel<<<(Bb * Cc * Hh * 90) / 256, 256, 0, stream>>>(y, dw, (float*)d_out);
}

// Round 22
// 470.822 us; speedup vs baseline: 1.2346x; 1.0944x over previous
//
#include <hip/hip_runtime.h>
#include <hip/hip_bf16.h>
#include <math.h>

#define Hh 360
#define Ww 720
#define Cc 64
#define Bb 2
#define BC (Bb*Cc)        // 128
#define Mrows (BC*Hh)     // 46080
#define CHUNKS 2
#define CM (Mrows/CHUNKS) // 23040
#define HPC (Hh/CHUNKS)   // 180 latitudes per chunk
#define KA 768            // A row: [hi(384) | lo(384)]
#define KF3 1152          // GEMM K loop: [hi.Bhi | lo.Bhi | hi.Blo]
#define NF 384            // fwd N (361 bins padded)
#define KI 768            // inv K: [Re(384) | Im(384)]
#define NI 768            // inv C row stride (720 used)
#define NSTORE_INV 720
#define SCALE 0.037267799624996496f   // 1/sqrt(720)
#define TWO_PI 6.2831853071795864769f

typedef __attribute__((ext_vector_type(8))) short s16x8;
typedef __attribute__((ext_vector_type(4))) float f32x4;
typedef __hip_bfloat16 bf16;

__device__ __forceinline__ void gload_lds16(const void* g, void* l) {
    __builtin_amdgcn_global_load_lds(
        (const __attribute__((address_space(1))) unsigned int*)g,
        (__attribute__((address_space(3))) unsigned int*)l, 16, 0, 0);
}
__device__ __forceinline__ short f2bfs(float v) {
    bf16 h = __float2bfloat16(v); short s; __builtin_memcpy(&s, &h, 2); return s;
}
__device__ __forceinline__ float bfs2f(short s) {
    bf16 h; __builtin_memcpy(&h, &s, 2); return __bfloat162float(h);
}

// ---------------------------------------------------------- B-matrix builds
// B stays 1152-wide: [Bhi | Bhi | Blo].
__global__ __launch_bounds__(256) void build_bfwd_kernel(bf16* __restrict__ Bc,
                                                         bf16* __restrict__ Bs) {
    int g = blockIdx.x * 256 + threadIdx.x;
    if (g >= NF * KF3) return;
    int wext = g % KF3;
    int j = g / KF3;
    int blk = wext / 384;
    int w = wext - blk * 384;
    float c = 0.f, s = 0.f;
    if (w <= 360 && j <= 360) {
        int idx = (j * w) % Ww;
        float a = (TWO_PI / Ww) * (float)idx;
        float sv, cv;
        sincosf(a, &sv, &cv);
        c = SCALE * cv;
        s = -SCALE * sv;
    }
    bf16 chi = __float2bfloat16(c);
    bf16 shi = __float2bfloat16(s);
    if (blk == 2) {
        Bc[g] = __float2bfloat16(c - __bfloat162float(chi));
        Bs[g] = __float2bfloat16(s - __bfloat162float(shi));
    } else {
        Bc[g] = chi;
        Bs[g] = shi;
    }
}

__global__ __launch_bounds__(256) void build_binv_kernel(bf16* __restrict__ Bi) {
    int g = blockIdx.x * 256 + threadIdx.x;
    if (g >= NI * KI) return;
    int k = g % KI, n = g / KI;
    float v = 0.f;
    if (n < NSTORE_INV) {
        if (k <= 360) {
            int j = k;
            float f = (j == 0 || j == 360) ? 1.f : 2.f;
            int idx = (j * n) % Ww;
            v = SCALE * f * cosf((TWO_PI / Ww) * (float)idx);
        } else if (k >= 384 && k <= 744) {
            int j = k - 384;
            int idx = (j * n) % Ww;
            v = -2.f * SCALE * sinf((TWO_PI / Ww) * (float)idx);
        }
    }
    Bi[g] = __float2bfloat16(v);
}

// W fragment-packed: s16x8 index = fid*64 + lane, fid = ((n16*4 + kb)*2 + kh).
__global__ __launch_bounds__(256) void build_wf_kernel(
    const float* __restrict__ w1_r, const float* __restrict__ w1_i,
    const float* __restrict__ w2_r, const float* __restrict__ w2_i,
    bf16* __restrict__ W1f, bf16* __restrict__ W2f)
{
    int g = blockIdx.x * 256 + threadIdx.x;
    if (g >= 2 * 32768) return;
    int which = g >> 15;
    int gg = g & 32767;
    int e = gg & 7, lane = (gg >> 3) & 63, kh = (gg >> 9) & 1;
    int kb = (gg >> 10) & 3, n16 = (gg >> 12) & 7;
    int frow = lane & 15, fcol = (lane >> 4) * 8;
    int n = n16 * 16 + frow;
    int kfull = kb * 64 + kh * 32 + fcol + e;
    int kk = kfull & 127, islo = kfull >> 7;
    const float* wr = which ? w2_r : w1_r;
    const float* wi = which ? w2_i : w1_i;
    float v;
    if (n < 64) v = (kk < 64) ? wr[n * 64 + kk] : -wi[n * 64 + kk - 64];
    else { int p = n - 64; v = (kk < 64) ? wi[p * 64 + kk] : wr[p * 64 + kk - 64]; }
    bf16 h = __float2bfloat16(v);
    bf16 out = islo ? __float2bfloat16(v - __bfloat162float(h)) : h;
    (which ? W2f : W1f)[gg] = out;
}

// ---------------------------------------- row starts (compact + 8-padded)
__global__ __launch_bounds__(512) void row_starts_kernel(const int* __restrict__ rows,
                                                         int T, int* __restrict__ rs,
                                                         int* __restrict__ rs8) {
    int h = threadIdx.x;
    if (h <= Hh) {
        if (h == Hh) rs[Hh] = T;
        else {
            int lo = 0, hi = T;
            while (lo < hi) {
                int mid = (lo + hi) >> 1;
                if (rows[mid] < h) lo = mid + 1; else hi = mid;
            }
            rs[h] = lo;
        }
    }
    __syncthreads();
    if (threadIdx.x == 0) {
        int acc = 0;
        for (int i = 0; i < Hh; ++i) {
            rs8[i] = acc;
            int cnt = rs[i + 1] - rs[i];
            acc += (cnt + 7) & ~7;
        }
        rs8[Hh] = acc;
    }
}

// ---------- pack x chunk -> A [hi|lo], h-major rows; one thread per (row,w)
// computes p,q once and writes all 4 outputs (x read once, not twice).
// Values bit-identical to the per-element version.
__global__ __launch_bounds__(256) void pack_kernel(const float* __restrict__ x,
                                                   bf16* __restrict__ Ap,
                                                   bf16* __restrict__ Aq,
                                                   int hbase) {
    int g = blockIdx.x * 256 + threadIdx.x;
    if (g >= CM * 384) return;
    int w = g % 384;
    int r = g / 384;
    int hl = r >> 7;
    int bc = r & 127;
    const float* xrow = x + ((size_t)bc * Hh + hbase + hl) * Ww;
    float p = 0.f, q = 0.f;
    if (w == 0 || w == 360) {
        p = xrow[w];
    } else if (w < 360) {
        float a = xrow[w];
        float b = xrow[Ww - w];
        p = a + b;
        q = a - b;
    }
    bf16 phi = __float2bfloat16(p);
    bf16 qhi = __float2bfloat16(q);
    size_t base = (size_t)r * KA + w;
    Ap[base]       = phi;
    Aq[base]       = qhi;
    Ap[base + 384] = __float2bfloat16(p - __bfloat162float(phi));
    Aq[base + 384] = __float2bfloat16(q - __bfloat162float(qhi));
}

// ----------------------------------------------------------------- zero fill
__global__ __launch_bounds__(256) void fill_zero_kernel(uint4* __restrict__ p, long n) {
    long i = (long)blockIdx.x * 256 + threadIdx.x;
    long stride = (long)gridDim.x * 256;
    uint4 z = make_uint4(0u, 0u, 0u, 0u);
    for (; i < n; i += stride) p[i] = z;
}

// ------------------- fwd MFMA GEMM, h-uniform tiles + early exit + compact C
__global__ __launch_bounds__(256) void gemm_fwd_compact_kernel(
    const bf16* __restrict__ Ap, const bf16* __restrict__ Aq,
    const bf16* __restrict__ Bc, const bf16* __restrict__ Bsm,
    float* __restrict__ Xcr, float* __restrict__ Xci,
    const int* __restrict__ rs, int T128, int hbase)
{
    __shared__ __align__(128) bf16 As[128][64];
    __shared__ __align__(128) bf16 Bs[128][64];
    const int h = hbase + blockIdx.x;       // one latitude per m-tile
    const int t0 = rs[h];
    const int cnt = rs[h + 1] - t0;
    const int n0 = blockIdx.y * 128;
    if (n0 >= cnt) return;                   // tile stores nothing: dead work
    const bf16* A  = blockIdx.z ? Aq : Ap;
    const bf16* Bt = blockIdx.z ? Bsm : Bc;
    float* Xc      = blockIdx.z ? Xci : Xcr;
    const int tid = threadIdx.x;
    const int lane = tid & 63;
    const int wave = tid >> 6;
    const int m0 = blockIdx.x * 128;
    const int wr = (wave >> 1) * 64;
    const int wc = (wave & 1) * 64;
    const int srow = tid >> 3;
    const int scol = (tid & 7) << 3;
    f32x4 acc[4][4] = {};
    for (int k0 = 0; k0 < KF3; k0 += 64) {
        const int ka0 = (k0 >= 768) ? (k0 - 768) : k0;
#pragma unroll
        for (int i = 0; i < 4; ++i) {
            const bf16* ga = A  + (size_t)(m0 + i * 32 + srow) * KA + ka0 + scol;
            const bf16* gb = Bt + (size_t)(n0 + i * 32 + srow) * KF3 + k0 + scol;
            gload_lds16(ga, ((char*)&As[0][0]) + (size_t)(i * 256 + tid) * 16);
            gload_lds16(gb, ((char*)&Bs[0][0]) + (size_t)(i * 256 + tid) * 16);
        }
        __syncthreads();
#pragma unroll
        for (int kk = 0; kk < 64; kk += 32) {
            s16x8 a[4], b[4];
#pragma unroll
            for (int m = 0; m < 4; ++m)
                a[m] = *(const s16x8*)&As[wr + m * 16 + (lane & 15)][kk + (lane >> 4) * 8];
#pragma unroll
            for (int n = 0; n < 4; ++n)
                b[n] = *(const s16x8*)&Bs[wc + n * 16 + (lane & 15)][kk + (lane >> 4) * 8];
#pragma unroll
            for (int m = 0; m < 4; ++m)
#pragma unroll
                for (int n = 0; n < 4; ++n)
                    acc[m][n] = __builtin_amdgcn_mfma_f32_16x16x32_bf16(a[m], b[n], acc[m][n], 0, 0, 0);
        }
        __syncthreads();
    }
    const int rbase = (lane >> 4) * 4;
    const int cidx = lane & 15;
#pragma unroll
    for (int m = 0; m < 4; ++m) {
#pragma unroll
        for (int r = 0; r < 4; ++r) {
            int bc = wr + m * 16 + rbase + r;   // local row within h-tile
#pragma unroll
            for (int n = 0; n < 4; ++n) {
                int j = n0 + wc + n * 16 + cidx;
                if (j < cnt)
                    Xc[(size_t)bc * T128 + t0 + j] = acc[m][n][r];
            }
        }
    }
}

// -------------- inverse GEMM, h-uniform tiles + K-tile early-skip; y h-major
__global__ __launch_bounds__(256) void gemm_inv_kernel(
    const bf16* __restrict__ Xgr, const bf16* __restrict__ Xgi,
    const bf16* __restrict__ Bt, const int* __restrict__ rs8,
    bf16* __restrict__ C, int T8cap)
{
    __shared__ __align__(128) bf16 As[128][64];
    __shared__ __align__(128) bf16 Bs[128][64];
    const int h = blockIdx.x;               // one latitude per m-tile
    const int t0v = rs8[h];
    const int cnt8 = rs8[h + 1] - t0v;
    const int n0 = blockIdx.y * 128;
    const int tid = threadIdx.x;
    const int lane = tid & 63;
    const int wave = tid >> 6;
    const int wr = (wave >> 1) * 64;
    const int wc = (wave & 1) * 64;
    const int srow = tid >> 3;
    const int scol = (tid & 7) << 3;
    f32x4 acc[4][4] = {};
    for (int k0 = 0; k0 < KI; k0 += 64) {
        const int jb = (k0 < 384) ? k0 : (k0 - 384);
        if (jb >= cnt8) continue;           // A-tile all zero: acc += 0, skip
        const bf16* base = (k0 < 384) ? Xgr : Xgi;
        const int j0 = jb + scol;
#pragma unroll
        for (int i = 0; i < 4; ++i)
            gload_lds16(Bt + (size_t)(n0 + i * 32 + srow) * KI + k0 + scol,
                        ((char*)&Bs[0][0]) + (size_t)(i * 256 + tid) * 16);
#pragma unroll
        for (int i = 0; i < 4; ++i) {
            int bc = i * 32 + srow;
            s16x8 v = (s16x8){0, 0, 0, 0, 0, 0, 0, 0};
            if (j0 < cnt8)
                v = *(const s16x8*)(base + (size_t)bc * T8cap + t0v + j0);
            *(s16x8*)&As[bc][scol] = v;
        }
        __syncthreads();
#pragma unroll
        for (int kk = 0; kk < 64; kk += 32) {
            s16x8 a[4], b[4];
#pragma unroll
            for (int m = 0; m < 4; ++m)
                a[m] = *(const s16x8*)&As[wr + m * 16 + (lane & 15)][kk + (lane >> 4) * 8];
#pragma unroll
            for (int n = 0; n < 4; ++n)
                b[n] = *(const s16x8*)&Bs[wc + n * 16 + (lane & 15)][kk + (lane >> 4) * 8];
#pragma unroll
            for (int m = 0; m < 4; ++m)
#pragma unroll
                for (int n = 0; n < 4; ++n)
                    acc[m][n] = __builtin_amdgcn_mfma_f32_16x16x32_bf16(a[m], b[n], acc[m][n], 0, 0, 0);
        }
        __syncthreads();
    }
    const int rbase = (lane >> 4) * 4;
    const int cidx = lane & 15;
#pragma unroll
    for (int m = 0; m < 4; ++m) {
#pragma unroll
        for (int n = 0; n < 4; ++n) {
            int gcol = n0 + wc + n * 16 + cidx;
            if (gcol < NSTORE_INV) {
#pragma unroll
                for (int r = 0; r < 4; ++r) {
                    int bc = wr + m * 16 + rbase + r;
                    C[(size_t)(h * BC + bc) * NI + gcol] = __float2bfloat16(acc[m][n][r]);
                }
            }
        }
    }
}

// ------------------------------------------------ fused middle stage (v3)
// FROZEN: verbatim green r17 middle. Three independent edits (fastmath,
// register-cache, both) each broke correctness (r12/r18/r19) — do not touch.
__device__ __forceinline__ float gelu_exact(float v) {
    return 0.5f * v * (1.0f + erff(v * 0.7071067811865476f));
}

__global__ __launch_bounds__(256, 4) void middle_fused_kernel(
    const float* __restrict__ Xcr, const float* __restrict__ Xci,
    bf16* __restrict__ Xgr, bf16* __restrict__ Xgi,
    const float* __restrict__ mean_r, const float* __restrict__ mean_i,
    const float* __restrict__ stdv,
    const float* __restrict__ mags_r, const float* __restrict__ mags_i,
    const float* __restrict__ bias_r, const float* __restrict__ bias_i,
    const bf16* __restrict__ W1f, const bf16* __restrict__ W2f,
    const float* __restrict__ brelu_p,
    const float* __restrict__ glu_mags, const float* __restrict__ glu_phases,
    const int* __restrict__ rows, const int* __restrict__ cols,
    const int* __restrict__ rs8,
    int T, int T128, int T8cap)
{
    __shared__ __align__(16) char smemA[32 * 264 * 2];   // 16,896 B
    __shared__ __align__(16) char smemB[32 * 264 * 2];
    bf16*  H1 = (bf16*)smemA;    // [32][264] hi/lo split input
    float* aL = (float*)smemA;   // [32][132] GEMM1 result
    float* cL = (float*)smemA;   // [32][132] GEMM2 result
    bf16*  H2 = (bf16*)smemB;    // [32][264] gelu output

    const int tid = threadIdx.x;
    const int b = blockIdx.y;
    const int t0 = blockIdx.x * 32;
    const int tl = tid & 31;
    const int cg = tid >> 5;          // 0..7
    const int t = t0 + tl;
    const bool valid = (t < T);
    const int lane = tid & 63;
    const int wv = tid >> 6;          // 0..3
    const int frow = lane & 15;
    const int fcol = (lane >> 4) * 8;
    const s16x8* W1v = (const s16x8*)W1f;
    const s16x8* W2v = (const s16x8*)W2f;
    constexpr int ASRC[6] = {0, 1, 2, 3, 0, 1};
    constexpr int BSRC[6] = {0, 1, 0, 1, 2, 3};

    // ---- phase 1: normalize -> H1 (lane=t, coalesced global reads)
    {
        float mr = 0.f, mi_ = 0.f, isd = 0.f;
        if (valid) { mr = mean_r[t]; mi_ = mean_i[t]; isd = 1.0f / (1e-12f + stdv[t]); }
        s16x8 vhr, vhi, vlr, vli;
#pragma unroll
        for (int ci = 0; ci < 8; ++ci) {
            int c = cg * 8 + ci;
            float xr = 0.f, xi = 0.f;
            if (valid) {
                xr = Xcr[(size_t)(b * 64 + c) * T128 + t];
                xi = Xci[(size_t)(b * 64 + c) * T128 + t];
            }
            float hr = (xr - mr) * isd;
            float hi = (xi - mi_) * isd;
            float h1r = fmaf(hr, mags_r[c], fmaf(-hi, mags_i[c], bias_r[c]));
            float h1i = fmaf(hr, mags_i[c], fmaf(hi, mags_r[c], bias_i[c]));
            short rh = f2bfs(h1r), ih = f2bfs(h1i);
            vhr[ci] = rh; vhi[ci] = ih;
            vlr[ci] = f2bfs(h1r - bfs2f(rh));
            vli[ci] = f2bfs(h1i - bfs2f(ih));
        }
        *(s16x8*)&H1[tl * 264 + cg * 8]       = vhr;
        *(s16x8*)&H1[tl * 264 + 64 + cg * 8]  = vhi;
        *(s16x8*)&H1[tl * 264 + 128 + cg * 8] = vlr;
        *(s16x8*)&H1[tl * 264 + 192 + cg * 8] = vli;
    }
    __syncthreads();

    // ---- GEMM1: A = H1 [32][264], B frags direct from W1f (L2)
    f32x4 acc[2][2] = {};
#pragma unroll
    for (int lc = 0; lc < 6; ++lc) {
        const int ka = ASRC[lc] * 64;
        const int kb = BSRC[lc];
#pragma unroll
        for (int kh = 0; kh < 2; ++kh) {
            s16x8 a0 = *(const s16x8*)&H1[frow * 264 + ka + kh * 32 + fcol];
            s16x8 a1 = *(const s16x8*)&H1[(16 + frow) * 264 + ka + kh * 32 + fcol];
#pragma unroll
            for (int n = 0; n < 2; ++n) {
                s16x8 bfv = W1v[(size_t)((((wv * 2 + n) * 4 + kb) * 2 + kh) * 64 + lane)];
                acc[0][n] = __builtin_amdgcn_mfma_f32_16x16x32_bf16(a0, bfv, acc[0][n], 0, 0, 0);
                acc[1][n] = __builtin_amdgcn_mfma_f32_16x16x32_bf16(a1, bfv, acc[1][n], 0, 0, 0);
            }
        }
    }
    __syncthreads();

    // ---- phase 3: acc -> aL (overwrites H1)
    const int rbase = (lane >> 4) * 4;
    const int cidx = lane & 15;
#pragma unroll
    for (int m = 0; m < 2; ++m)
#pragma unroll
        for (int n = 0; n < 2; ++n)
#pragma unroll
            for (int r = 0; r < 4; ++r)
                aL[(m * 16 + rbase + r) * 132 + wv * 32 + n * 16 + cidx] = acc[m][n][r];
    __syncthreads();

    // ---- phase 4: gelu (lane=t) -> H2
    {
        const float brelu = brelu_p[0];
        f32x4 ar0 = *(const f32x4*)&aL[tl * 132 + cg * 8];
        f32x4 ar1 = *(const f32x4*)&aL[tl * 132 + cg * 8 + 4];
        f32x4 ai0 = *(const f32x4*)&aL[tl * 132 + 64 + cg * 8];
        f32x4 ai1 = *(const f32x4*)&aL[tl * 132 + 64 + cg * 8 + 4];
        s16x8 vhr, vhi, vlr, vli;
#pragma unroll
        for (int ci = 0; ci < 8; ++ci) {
            float ar = (ci < 4) ? ar0[ci & 3] : ar1[ci & 3];
            float ai = (ci < 4) ? ai0[ci & 3] : ai1[ci & 3];
            float r = sqrtf(ar * ar + ai * ai);
            float g = gelu_exact(r + brelu);
            float h2r, h2i;
            if (r > 0.f) { float f = g / r; h2r = f * ar; h2i = f * ai; }
            else { h2r = g; h2i = 0.f; }
            short rh = f2bfs(h2r), ih = f2bfs(h2i);
            vhr[ci] = rh; vhi[ci] = ih;
            vlr[ci] = f2bfs(h2r - bfs2f(rh));
            vli[ci] = f2bfs(h2i - bfs2f(ih));
        }
        *(s16x8*)&H2[tl * 264 + cg * 8]       = vhr;
        *(s16x8*)&H2[tl * 264 + 64 + cg * 8]  = vhi;
        *(s16x8*)&H2[tl * 264 + 128 + cg * 8] = vlr;
        *(s16x8*)&H2[tl * 264 + 192 + cg * 8] = vli;
    }
    __syncthreads();

    // ---- GEMM2: A = H2, B frags from W2f
    f32x4 acc2[2][2] = {};
#pragma unroll
    for (int lc = 0; lc < 6; ++lc) {
        const int ka = ASRC[lc] * 64;
        const int kb = BSRC[lc];
#pragma unroll
        for (int kh = 0; kh < 2; ++kh) {
            s16x8 a0 = *(const s16x8*)&H2[frow * 264 + ka + kh * 32 + fcol];
            s16x8 a1 = *(const s16x8*)&H2[(16 + frow) * 264 + ka + kh * 32 + fcol];
#pragma unroll
            for (int n = 0; n < 2; ++n) {
                s16x8 bfv = W2v[(size_t)((((wv * 2 + n) * 4 + kb) * 2 + kh) * 64 + lane)];
                acc2[0][n] = __builtin_amdgcn_mfma_f32_16x16x32_bf16(a0, bfv, acc2[0][n], 0, 0, 0);
                acc2[1][n] = __builtin_amdgcn_mfma_f32_16x16x32_bf16(a1, bfv, acc2[1][n], 0, 0, 0);
            }
        }
    }
    // cL aliases aL (smemA): all aL reads completed before the barrier above
    // GEMM2; no thread reads smemA during GEMM2.
#pragma unroll
    for (int m = 0; m < 2; ++m)
#pragma unroll
        for (int n = 0; n < 2; ++n)
#pragma unroll
            for (int r = 0; r < 4; ++r)
                cL[(m * 16 + rbase + r) * 132 + wv * 32 + n * 16 + cidx] = acc2[m][n][r];
    __syncthreads();

    // ---- phase 8: gate + compact coalesced store (lane=t)
    if (valid) {
        int h = rows[t], j = cols[t];
        size_t wbase = (size_t)rs8[h] + j;
        f32x4 cr0 = *(const f32x4*)&cL[tl * 132 + cg * 8];
        f32x4 cr1 = *(const f32x4*)&cL[tl * 132 + cg * 8 + 4];
        f32x4 ci0 = *(const f32x4*)&cL[tl * 132 + 64 + cg * 8];
        f32x4 ci1 = *(const f32x4*)&cL[tl * 132 + 64 + cg * 8 + 4];
#pragma unroll
        for (int ci = 0; ci < 8; ++ci) {
            int c = cg * 8 + ci;
            float cr  = (ci < 4) ? cr0[ci & 3] : cr1[ci & 3];
            float cii = (ci < 4) ? ci0[ci & 3] : ci1[ci & 3];
            float xr = Xcr[(size_t)(b * 64 + c) * T128 + t];
            float xi = Xci[(size_t)(b * 64 + c) * T128 + t];
            float r3 = sqrtf(cr * cr + cii * cii);
            float gm = glu_mags[(size_t)c * T + t];
            float gp = glu_phases[(size_t)c * T + t];
            float sg = 1.0f / (1.0f + expf(-(r3 + gm)));
            float ux, uy;
            if (r3 > 0.f) { float ir3 = 1.0f / r3; ux = cr * ir3; uy = cii * ir3; }
            else { ux = 1.f; uy = 0.f; }
            float sp, cp;
            sincosf(gp, &sp, &cp);
            float gx = sg * (ux * cp - uy * sp);
            float gy = sg * (ux * sp + uy * cp);
            size_t base = (size_t)(b * 64 + c) * T8cap + wbase;
            Xgr[base] = __float2bfloat16(xr * gx - xi * gy);
            Xgi[base] = __float2bfloat16(xr * gy + xi * gx);
        }
    }
}

// ------- depthwise conv + add (bf16 y, h-major rows, 8-wide, XCD swizzle)
__global__ __launch_bounds__(256) void conv_add_kernel(
    const bf16* __restrict__ y, const float* __restrict__ dw,
    float* __restrict__ out)
{
    const int nb = gridDim.x;
    const int chunk = nb >> 3;
    const int orig = blockIdx.x;
    const int swz = (orig & 7) * chunk + (orig >> 3);   // bijective: nb % 8 == 0
    int g = swz * 256 + threadIdx.x;
    int w8 = g % 90;
    int rem = g / 90;
    int h = rem % Hh;
    int bc = rem / Hh;
    int c = bc & (Cc - 1);
    int w = w8 * 8;
    int walt = (w >= Ww / 2) ? (w - Ww / 2) : (w + Ww / 2);
    float acc[8];
    {
        s16x8 v0 = *(const s16x8*)&y[((size_t)h * BC + bc) * NI + w];
#pragma unroll
        for (int e = 0; e < 8; ++e) acc[e] = bfs2f(v0[e]);
    }
#pragma unroll
    for (int k = 0; k < 11; ++k) {
        int hp = h + k - 5;
        int hh, ww;
        if (hp < 0)        { hh = -1 - hp;         ww = walt; }
        else if (hp >= Hh) { hh = 2 * Hh - 1 - hp; ww = walt; }
        else               { hh = hp;              ww = w; }
        s16x8 v = *(const s16x8*)&y[((size_t)hh * BC + bc) * NI + ww];
        float dwk = dw[c * 11 + k];
#pragma unroll
        for (int e = 0; e < 8; ++e)
            acc[e] = fmaf(dwk, bfs2f(v[e]), acc[e]);
    }
    float* ob = &out[((size_t)bc * Hh + h) * Ww + w];
    *(float4*)&ob[0] = make_float4(acc[0], acc[1], acc[2], acc[3]);
    *(float4*)&ob[4] = make_float4(acc[4], acc[5], acc[6], acc[7]);
}

// ------------------------------------------------------------------ launch
extern "C" void kernel_launch(void* const* d_in, const int* in_sizes, int n_in,
                              void* d_out, int out_size, void* d_ws, size_t ws_size,
                              hipStream_t stream)
{
    const float* x      = (const float*)d_in[0];
    const float* mean_r = (const float*)d_in[1];
    const float* mean_i = (const float*)d_in[2];
    const float* stdv   = (const float*)d_in[3];
    const float* mags_r = (const float*)d_in[4];
    const float* mags_i = (const float*)d_in[5];
    const float* bias_r = (const float*)d_in[6];
    const float* bias_i = (const float*)d_in[7];
    const float* w1_r   = (const float*)d_in[8];
    const float* w1_i   = (const float*)d_in[9];
    const float* brelu  = (const float*)d_in[10];
    const float* w2_r   = (const float*)d_in[11];
    const float* w2_i   = (const float*)d_in[12];
    const float* glu_m  = (const float*)d_in[13];
    const float* glu_p  = (const float*)d_in[14];
    const float* dw     = (const float*)d_in[15];
    const int*   rows   = (const int*)d_in[16];
    const int*   cols   = (const int*)d_in[17];
    const int T = in_sizes[16];
    const int T128 = ((T + 127) / 128) * 128;
    const int T8cap = ((T + 7 * Hh) + 127) & ~127;

    char* ws = (char*)d_ws;
    const size_t SApc  = (size_t)CM * KA * 2;             // 35,389,440
    const size_t XC_SZ = (size_t)BC * T128 * 4;           // ~42.7 MB
    const size_t XG_SZ = (size_t)BC * T8cap * 2;          // ~22.0 MB
    bf16*  Ap  = (bf16*)ws;
    bf16*  Aq  = (bf16*)(ws + SApc);
    float* Xcr = (float*)(ws + 2 * SApc);
    float* Xci = (float*)(ws + 2 * SApc + XC_SZ);
    bf16*  Xgr = (bf16*)ws;
    bf16*  Xgi = (bf16*)(ws + XG_SZ);
    bf16*  y   = (bf16*)(ws + 2 * XG_SZ);
    size_t boff = 2 * SApc + 2 * XC_SZ;                   // ~156.1 MB
    bf16*  Bce = (bf16*)(ws + boff);
    bf16*  Bse = (bf16*)(ws + boff + (size_t)NF * KF3 * 2);
    bf16*  Bti = (bf16*)(ws + boff + 2 * (size_t)NF * KF3 * 2);
    bf16*  W1f = (bf16*)(ws + boff + 2 * (size_t)NF * KF3 * 2 + (size_t)NI * KI * 2);
    bf16*  W2f = W1f + 32768;
    int*   rs  = (int*)(W2f + 32768);
    int*   rs8 = rs + (Hh + 2);

    build_bfwd_kernel<<<(NF * KF3 + 255) / 256, 256, 0, stream>>>(Bce, Bse);
    build_binv_kernel<<<(NI * KI + 255) / 256, 256, 0, stream>>>(Bti);
    build_wf_kernel<<<(2 * 32768 + 255) / 256, 256, 0, stream>>>(
        w1_r, w1_i, w2_r, w2_i, W1f, W2f);
    row_starts_kernel<<<1, 512, 0, stream>>>(rows, T, rs, rs8);

    for (int ch = 0; ch < CHUNKS; ++ch) {
        pack_kernel<<<(CM * 384 + 255) / 256, 256, 0, stream>>>(
            x, Ap, Aq, ch * HPC);
        gemm_fwd_compact_kernel<<<dim3(CM / 128, NF / 128, 2), 256, 0, stream>>>(
            Ap, Aq, Bce, Bse, Xcr, Xci, rs, T128, ch * HPC);
    }

    fill_zero_kernel<<<2048, 256, 0, stream>>>((uint4*)Xgr, (long)(2 * XG_SZ / 16));

    const int nT32 = (T + 31) / 32;
    middle_fused_kernel<<<dim3(nT32, Bb), 256, 0, stream>>>(
        Xcr, Xci, Xgr, Xgi, mean_r, mean_i, stdv, mags_r, mags_i,
        bias_r, bias_i, W1f, W2f, brelu, glu_m, glu_p, rows, cols, rs8,
        T, T128, T8cap);

    gemm_inv_kernel<<<dim3(Hh, NI / 128), 256, 0, stream>>>(
        Xgr, Xgi, Bti, rs8, y, T8cap);

    conv_add_kernel<<<(Bb * Cc * Hh * 90) / 256, 256, 0, stream>>>(y, dw, (float*)d_out);
}

// Round 23
// 462.213 us; speedup vs baseline: 1.2576x; 1.0186x over previous
//
#include <hip/hip_runtime.h>
#include <hip/hip_bf16.h>
#include <math.h>

#define Hh 360
#define Ww 720
#define Cc 64
#define Bb 2
#define BC (Bb*Cc)        // 128
#define Mrows (BC*Hh)     // 46080
#define CHUNKS 2
#define CM (Mrows/CHUNKS) // 23040
#define HPC (Hh/CHUNKS)   // 180 latitudes per chunk
#define KA 768            // A row: [hi(384) | lo(384)]
#define KF3 1152          // GEMM K loop: [hi.Bhi | lo.Bhi | hi.Blo]
#define NF 384            // fwd N (361 bins padded)
#define KI 768            // inv K: [Re(384) | Im(384)]
#define NI 768            // inv C row stride (720 used)
#define NSTORE_INV 720
#define SCALE 0.037267799624996496f   // 1/sqrt(720)
#define TWO_PI 6.2831853071795864769f

typedef __attribute__((ext_vector_type(8))) short s16x8;
typedef __attribute__((ext_vector_type(4))) float f32x4;
typedef __hip_bfloat16 bf16;

__device__ __forceinline__ void gload_lds16(const void* g, void* l) {
    __builtin_amdgcn_global_load_lds(
        (const __attribute__((address_space(1))) unsigned int*)g,
        (__attribute__((address_space(3))) unsigned int*)l, 16, 0, 0);
}
__device__ __forceinline__ short f2bfs(float v) {
    bf16 h = __float2bfloat16(v); short s; __builtin_memcpy(&s, &h, 2); return s;
}
__device__ __forceinline__ float bfs2f(short s) {
    bf16 h; __builtin_memcpy(&h, &s, 2); return __bfloat162float(h);
}

// ---------------------------------------------------------- B-matrix builds
// B stays 1152-wide: [Bhi | Bhi | Blo].
__global__ __launch_bounds__(256) void build_bfwd_kernel(bf16* __restrict__ Bc,
                                                         bf16* __restrict__ Bs) {
    int g = blockIdx.x * 256 + threadIdx.x;
    if (g >= NF * KF3) return;
    int wext = g % KF3;
    int j = g / KF3;
    int blk = wext / 384;
    int w = wext - blk * 384;
    float c = 0.f, s = 0.f;
    if (w <= 360 && j <= 360) {
        int idx = (j * w) % Ww;
        float a = (TWO_PI / Ww) * (float)idx;
        float sv, cv;
        sincosf(a, &sv, &cv);
        c = SCALE * cv;
        s = -SCALE * sv;
    }
    bf16 chi = __float2bfloat16(c);
    bf16 shi = __float2bfloat16(s);
    if (blk == 2) {
        Bc[g] = __float2bfloat16(c - __bfloat162float(chi));
        Bs[g] = __float2bfloat16(s - __bfloat162float(shi));
    } else {
        Bc[g] = chi;
        Bs[g] = shi;
    }
}

__global__ __launch_bounds__(256) void build_binv_kernel(bf16* __restrict__ Bi) {
    int g = blockIdx.x * 256 + threadIdx.x;
    if (g >= NI * KI) return;
    int k = g % KI, n = g / KI;
    float v = 0.f;
    if (n < NSTORE_INV) {
        if (k <= 360) {
            int j = k;
            float f = (j == 0 || j == 360) ? 1.f : 2.f;
            int idx = (j * n) % Ww;
            v = SCALE * f * cosf((TWO_PI / Ww) * (float)idx);
        } else if (k >= 384 && k <= 744) {
            int j = k - 384;
            int idx = (j * n) % Ww;
            v = -2.f * SCALE * sinf((TWO_PI / Ww) * (float)idx);
        }
    }
    Bi[g] = __float2bfloat16(v);
}

// W fragment-packed: s16x8 index = fid*64 + lane, fid = ((n16*4 + kb)*2 + kh).
__global__ __launch_bounds__(256) void build_wf_kernel(
    const float* __restrict__ w1_r, const float* __restrict__ w1_i,
    const float* __restrict__ w2_r, const float* __restrict__ w2_i,
    bf16* __restrict__ W1f, bf16* __restrict__ W2f)
{
    int g = blockIdx.x * 256 + threadIdx.x;
    if (g >= 2 * 32768) return;
    int which = g >> 15;
    int gg = g & 32767;
    int e = gg & 7, lane = (gg >> 3) & 63, kh = (gg >> 9) & 1;
    int kb = (gg >> 10) & 3, n16 = (gg >> 12) & 7;
    int frow = lane & 15, fcol = (lane >> 4) * 8;
    int n = n16 * 16 + frow;
    int kfull = kb * 64 + kh * 32 + fcol + e;
    int kk = kfull & 127, islo = kfull >> 7;
    const float* wr = which ? w2_r : w1_r;
    const float* wi = which ? w2_i : w1_i;
    float v;
    if (n < 64) v = (kk < 64) ? wr[n * 64 + kk] : -wi[n * 64 + kk - 64];
    else { int p = n - 64; v = (kk < 64) ? wi[p * 64 + kk] : wr[p * 64 + kk - 64]; }
    bf16 h = __float2bfloat16(v);
    bf16 out = islo ? __float2bfloat16(v - __bfloat162float(h)) : h;
    (which ? W2f : W1f)[gg] = out;
}

// ------------- row starts (compact + 8-padded), parallel prefix scan
__global__ __launch_bounds__(512) void row_starts_kernel(const int* __restrict__ rows,
                                                         int T, int* __restrict__ rs,
                                                         int* __restrict__ rs8) {
    __shared__ int scan[512];
    const int h = threadIdx.x;
    if (h <= Hh) {
        if (h == Hh) rs[Hh] = T;
        else {
            int lo = 0, hi = T;
            while (lo < hi) {
                int mid = (lo + hi) >> 1;
                if (rows[mid] < h) lo = mid + 1; else hi = mid;
            }
            rs[h] = lo;
        }
    }
    __syncthreads();
    // cnt8(h) = (cnt(h)+7)&~7 ; rs8 = exclusive prefix sum (Hillis-Steele).
    int c8 = 0;
    if (h < Hh) c8 = ((rs[h + 1] - rs[h]) + 7) & ~7;
    scan[h] = c8;
    __syncthreads();
    for (int off = 1; off < 512; off <<= 1) {
        int add = (h >= off) ? scan[h - off] : 0;
        __syncthreads();
        scan[h] += add;
        __syncthreads();
    }
    if (h < Hh) rs8[h] = scan[h] - c8;       // exclusive
    if (h == Hh) rs8[Hh] = scan[Hh - 1];     // total
}

// ---------- pack x chunk -> A [hi|lo], h-major rows; one thread per (row,w)
__global__ __launch_bounds__(256) void pack_kernel(const float* __restrict__ x,
                                                   bf16* __restrict__ Ap,
                                                   bf16* __restrict__ Aq,
                                                   int hbase) {
    int g = blockIdx.x * 256 + threadIdx.x;
    if (g >= CM * 384) return;
    int w = g % 384;
    int r = g / 384;
    int hl = r >> 7;
    int bc = r & 127;
    const float* xrow = x + ((size_t)bc * Hh + hbase + hl) * Ww;
    float p = 0.f, q = 0.f;
    if (w == 0 || w == 360) {
        p = xrow[w];
    } else if (w < 360) {
        float a = xrow[w];
        float b = xrow[Ww - w];
        p = a + b;
        q = a - b;
    }
    bf16 phi = __float2bfloat16(p);
    bf16 qhi = __float2bfloat16(q);
    size_t base = (size_t)r * KA + w;
    Ap[base]       = phi;
    Aq[base]       = qhi;
    Ap[base + 384] = __float2bfloat16(p - __bfloat162float(phi));
    Aq[base + 384] = __float2bfloat16(q - __bfloat162float(qhi));
}

// --------- pad-only zero of Xg: rows [cnt, cnt8) per (bc,h) (<= 7 elems)
// Middle writes all j<cnt each call; inv reads [0,cnt8) -> pads must be 0.
__global__ __launch_bounds__(256) void pad_zero_kernel(
    bf16* __restrict__ Xgr, bf16* __restrict__ Xgi,
    const int* __restrict__ rs, const int* __restrict__ rs8, int T8cap)
{
    const int h = blockIdx.x;
    const int cnt = rs[h + 1] - rs[h];
    const int t0 = rs8[h];
    const int cnt8 = rs8[h + 1] - t0;
    const int pad = cnt8 - cnt;
    if (pad <= 0) return;
    for (int idx = threadIdx.x; idx < BC * 8; idx += 256) {
        int bc = idx >> 3;
        int e = idx & 7;
        if (e < pad) {
            size_t off = (size_t)bc * T8cap + t0 + cnt + e;
            Xgr[off] = __float2bfloat16(0.f);
            Xgi[off] = __float2bfloat16(0.f);
        }
    }
}

// ------------------- fwd MFMA GEMM, h-uniform tiles + early exit + compact C
__global__ __launch_bounds__(256) void gemm_fwd_compact_kernel(
    const bf16* __restrict__ Ap, const bf16* __restrict__ Aq,
    const bf16* __restrict__ Bc, const bf16* __restrict__ Bsm,
    float* __restrict__ Xcr, float* __restrict__ Xci,
    const int* __restrict__ rs, int T128, int hbase)
{
    __shared__ __align__(128) bf16 As[128][64];
    __shared__ __align__(128) bf16 Bs[128][64];
    const int h = hbase + blockIdx.x;       // one latitude per m-tile
    const int t0 = rs[h];
    const int cnt = rs[h + 1] - t0;
    const int n0 = blockIdx.y * 128;
    if (n0 >= cnt) return;                   // tile stores nothing: dead work
    const bf16* A  = blockIdx.z ? Aq : Ap;
    const bf16* Bt = blockIdx.z ? Bsm : Bc;
    float* Xc      = blockIdx.z ? Xci : Xcr;
    const int tid = threadIdx.x;
    const int lane = tid & 63;
    const int wave = tid >> 6;
    const int m0 = blockIdx.x * 128;
    const int wr = (wave >> 1) * 64;
    const int wc = (wave & 1) * 64;
    const int srow = tid >> 3;
    const int scol = (tid & 7) << 3;
    f32x4 acc[4][4] = {};
    for (int k0 = 0; k0 < KF3; k0 += 64) {
        const int ka0 = (k0 >= 768) ? (k0 - 768) : k0;
#pragma unroll
        for (int i = 0; i < 4; ++i) {
            const bf16* ga = A  + (size_t)(m0 + i * 32 + srow) * KA + ka0 + scol;
            const bf16* gb = Bt + (size_t)(n0 + i * 32 + srow) * KF3 + k0 + scol;
            gload_lds16(ga, ((char*)&As[0][0]) + (size_t)(i * 256 + tid) * 16);
            gload_lds16(gb, ((char*)&Bs[0][0]) + (size_t)(i * 256 + tid) * 16);
        }
        __syncthreads();
#pragma unroll
        for (int kk = 0; kk < 64; kk += 32) {
            s16x8 a[4], b[4];
#pragma unroll
            for (int m = 0; m < 4; ++m)
                a[m] = *(const s16x8*)&As[wr + m * 16 + (lane & 15)][kk + (lane >> 4) * 8];
#pragma unroll
            for (int n = 0; n < 4; ++n)
                b[n] = *(const s16x8*)&Bs[wc + n * 16 + (lane & 15)][kk + (lane >> 4) * 8];
#pragma unroll
            for (int m = 0; m < 4; ++m)
#pragma unroll
                for (int n = 0; n < 4; ++n)
                    acc[m][n] = __builtin_amdgcn_mfma_f32_16x16x32_bf16(a[m], b[n], acc[m][n], 0, 0, 0);
        }
        __syncthreads();
    }
    const int rbase = (lane >> 4) * 4;
    const int cidx = lane & 15;
#pragma unroll
    for (int m = 0; m < 4; ++m) {
#pragma unroll
        for (int r = 0; r < 4; ++r) {
            int bc = wr + m * 16 + rbase + r;   // local row within h-tile
#pragma unroll
            for (int n = 0; n < 4; ++n) {
                int j = n0 + wc + n * 16 + cidx;
                if (j < cnt)
                    Xc[(size_t)bc * T128 + t0 + j] = acc[m][n][r];
            }
        }
    }
}

// -------------- inverse GEMM, h-uniform tiles + K-tile early-skip; y h-major
__global__ __launch_bounds__(256) void gemm_inv_kernel(
    const bf16* __restrict__ Xgr, const bf16* __restrict__ Xgi,
    const bf16* __restrict__ Bt, const int* __restrict__ rs8,
    bf16* __restrict__ C, int T8cap)
{
    __shared__ __align__(128) bf16 As[128][64];
    __shared__ __align__(128) bf16 Bs[128][64];
    const int h = blockIdx.x;               // one latitude per m-tile
    const int t0v = rs8[h];
    const int cnt8 = rs8[h + 1] - t0v;
    const int n0 = blockIdx.y * 128;
    const int tid = threadIdx.x;
    const int lane = tid & 63;
    const int wave = tid >> 6;
    const int wr = (wave >> 1) * 64;
    const int wc = (wave & 1) * 64;
    const int srow = tid >> 3;
    const int scol = (tid & 7) << 3;
    f32x4 acc[4][4] = {};
    for (int k0 = 0; k0 < KI; k0 += 64) {
        const int jb = (k0 < 384) ? k0 : (k0 - 384);
        if (jb >= cnt8) continue;           // A-tile all zero: acc += 0, skip
        const bf16* base = (k0 < 384) ? Xgr : Xgi;
        const int j0 = jb + scol;
#pragma unroll
        for (int i = 0; i < 4; ++i)
            gload_lds16(Bt + (size_t)(n0 + i * 32 + srow) * KI + k0 + scol,
                        ((char*)&Bs[0][0]) + (size_t)(i * 256 + tid) * 16);
#pragma unroll
        for (int i = 0; i < 4; ++i) {
            int bc = i * 32 + srow;
            s16x8 v = (s16x8){0, 0, 0, 0, 0, 0, 0, 0};
            if (j0 < cnt8)
                v = *(const s16x8*)(base + (size_t)bc * T8cap + t0v + j0);
            *(s16x8*)&As[bc][scol] = v;
        }
        __syncthreads();
#pragma unroll
        for (int kk = 0; kk < 64; kk += 32) {
            s16x8 a[4], b[4];
#pragma unroll
            for (int m = 0; m < 4; ++m)
                a[m] = *(const s16x8*)&As[wr + m * 16 + (lane & 15)][kk + (lane >> 4) * 8];
#pragma unroll
            for (int n = 0; n < 4; ++n)
                b[n] = *(const s16x8*)&Bs[wc + n * 16 + (lane & 15)][kk + (lane >> 4) * 8];
#pragma unroll
            for (int m = 0; m < 4; ++m)
#pragma unroll
                for (int n = 0; n < 4; ++n)
                    acc[m][n] = __builtin_amdgcn_mfma_f32_16x16x32_bf16(a[m], b[n], acc[m][n], 0, 0, 0);
        }
        __syncthreads();
    }
    const int rbase = (lane >> 4) * 4;
    const int cidx = lane & 15;
#pragma unroll
    for (int m = 0; m < 4; ++m) {
#pragma unroll
        for (int n = 0; n < 4; ++n) {
            int gcol = n0 + wc + n * 16 + cidx;
            if (gcol < NSTORE_INV) {
#pragma unroll
                for (int r = 0; r < 4; ++r) {
                    int bc = wr + m * 16 + rbase + r;
                    C[(size_t)(h * BC + bc) * NI + gcol] = __float2bfloat16(acc[m][n][r]);
                }
            }
        }
    }
}

// ------------------------------------------------ fused middle stage (v3)
// FROZEN: verbatim green r17 middle. Three independent edits (fastmath,
// register-cache, both) each broke correctness (r12/r18/r19) — do not touch.
__device__ __forceinline__ float gelu_exact(float v) {
    return 0.5f * v * (1.0f + erff(v * 0.7071067811865476f));
}

__global__ __launch_bounds__(256, 4) void middle_fused_kernel(
    const float* __restrict__ Xcr, const float* __restrict__ Xci,
    bf16* __restrict__ Xgr, bf16* __restrict__ Xgi,
    const float* __restrict__ mean_r, const float* __restrict__ mean_i,
    const float* __restrict__ stdv,
    const float* __restrict__ mags_r, const float* __restrict__ mags_i,
    const float* __restrict__ bias_r, const float* __restrict__ bias_i,
    const bf16* __restrict__ W1f, const bf16* __restrict__ W2f,
    const float* __restrict__ brelu_p,
    const float* __restrict__ glu_mags, const float* __restrict__ glu_phases,
    const int* __restrict__ rows, const int* __restrict__ cols,
    const int* __restrict__ rs8,
    int T, int T128, int T8cap)
{
    __shared__ __align__(16) char smemA[32 * 264 * 2];   // 16,896 B
    __shared__ __align__(16) char smemB[32 * 264 * 2];
    bf16*  H1 = (bf16*)smemA;    // [32][264] hi/lo split input
    float* aL = (float*)smemA;   // [32][132] GEMM1 result
    float* cL = (float*)smemA;   // [32][132] GEMM2 result
    bf16*  H2 = (bf16*)smemB;    // [32][264] gelu output

    const int tid = threadIdx.x;
    const int b = blockIdx.y;
    const int t0 = blockIdx.x * 32;
    const int tl = tid & 31;
    const int cg = tid >> 5;          // 0..7
    const int t = t0 + tl;
    const bool valid = (t < T);
    const int lane = tid & 63;
    const int wv = tid >> 6;          // 0..3
    const int frow = lane & 15;
    const int fcol = (lane >> 4) * 8;
    const s16x8* W1v = (const s16x8*)W1f;
    const s16x8* W2v = (const s16x8*)W2f;
    constexpr int ASRC[6] = {0, 1, 2, 3, 0, 1};
    constexpr int BSRC[6] = {0, 1, 0, 1, 2, 3};

    // ---- phase 1: normalize -> H1 (lane=t, coalesced global reads)
    {
        float mr = 0.f, mi_ = 0.f, isd = 0.f;
        if (valid) { mr = mean_r[t]; mi_ = mean_i[t]; isd = 1.0f / (1e-12f + stdv[t]); }
        s16x8 vhr, vhi, vlr, vli;
#pragma unroll
        for (int ci = 0; ci < 8; ++ci) {
            int c = cg * 8 + ci;
            float xr = 0.f, xi = 0.f;
            if (valid) {
                xr = Xcr[(size_t)(b * 64 + c) * T128 + t];
                xi = Xci[(size_t)(b * 64 + c) * T128 + t];
            }
            float hr = (xr - mr) * isd;
            float hi = (xi - mi_) * isd;
            float h1r = fmaf(hr, mags_r[c], fmaf(-hi, mags_i[c], bias_r[c]));
            float h1i = fmaf(hr, mags_i[c], fmaf(hi, mags_r[c], bias_i[c]));
            short rh = f2bfs(h1r), ih = f2bfs(h1i);
            vhr[ci] = rh; vhi[ci] = ih;
            vlr[ci] = f2bfs(h1r - bfs2f(rh));
            vli[ci] = f2bfs(h1i - bfs2f(ih));
        }
        *(s16x8*)&H1[tl * 264 + cg * 8]       = vhr;
        *(s16x8*)&H1[tl * 264 + 64 + cg * 8]  = vhi;
        *(s16x8*)&H1[tl * 264 + 128 + cg * 8] = vlr;
        *(s16x8*)&H1[tl * 264 + 192 + cg * 8] = vli;
    }
    __syncthreads();

    // ---- GEMM1: A = H1 [32][264], B frags direct from W1f (L2)
    f32x4 acc[2][2] = {};
#pragma unroll
    for (int lc = 0; lc < 6; ++lc) {
        const int ka = ASRC[lc] * 64;
        const int kb = BSRC[lc];
#pragma unroll
        for (int kh = 0; kh < 2; ++kh) {
            s16x8 a0 = *(const s16x8*)&H1[frow * 264 + ka + kh * 32 + fcol];
            s16x8 a1 = *(const s16x8*)&H1[(16 + frow) * 264 + ka + kh * 32 + fcol];
#pragma unroll
            for (int n = 0; n < 2; ++n) {
                s16x8 bfv = W1v[(size_t)((((wv * 2 + n) * 4 + kb) * 2 + kh) * 64 + lane)];
                acc[0][n] = __builtin_amdgcn_mfma_f32_16x16x32_bf16(a0, bfv, acc[0][n], 0, 0, 0);
                acc[1][n] = __builtin_amdgcn_mfma_f32_16x16x32_bf16(a1, bfv, acc[1][n], 0, 0, 0);
            }
        }
    }
    __syncthreads();

    // ---- phase 3: acc -> aL (overwrites H1)
    const int rbase = (lane >> 4) * 4;
    const int cidx = lane & 15;
#pragma unroll
    for (int m = 0; m < 2; ++m)
#pragma unroll
        for (int n = 0; n < 2; ++n)
#pragma unroll
            for (int r = 0; r < 4; ++r)
                aL[(m * 16 + rbase + r) * 132 + wv * 32 + n * 16 + cidx] = acc[m][n][r];
    __syncthreads();

    // ---- phase 4: gelu (lane=t) -> H2
    {
        const float brelu = brelu_p[0];
        f32x4 ar0 = *(const f32x4*)&aL[tl * 132 + cg * 8];
        f32x4 ar1 = *(const f32x4*)&aL[tl * 132 + cg * 8 + 4];
        f32x4 ai0 = *(const f32x4*)&aL[tl * 132 + 64 + cg * 8];
        f32x4 ai1 = *(const f32x4*)&aL[tl * 132 + 64 + cg * 8 + 4];
        s16x8 vhr, vhi, vlr, vli;
#pragma unroll
        for (int ci = 0; ci < 8; ++ci) {
            float ar = (ci < 4) ? ar0[ci & 3] : ar1[ci & 3];
            float ai = (ci < 4) ? ai0[ci & 3] : ai1[ci & 3];
            float r = sqrtf(ar * ar + ai * ai);
            float g = gelu_exact(r + brelu);
            float h2r, h2i;
            if (r > 0.f) { float f = g / r; h2r = f * ar; h2i = f * ai; }
            else { h2r = g; h2i = 0.f; }
            short rh = f2bfs(h2r), ih = f2bfs(h2i);
            vhr[ci] = rh; vhi[ci] = ih;
            vlr[ci] = f2bfs(h2r - bfs2f(rh));
            vli[ci] = f2bfs(h2i - bfs2f(ih));
        }
        *(s16x8*)&H2[tl * 264 + cg * 8]       = vhr;
        *(s16x8*)&H2[tl * 264 + 64 + cg * 8]  = vhi;
        *(s16x8*)&H2[tl * 264 + 128 + cg * 8] = vlr;
        *(s16x8*)&H2[tl * 264 + 192 + cg * 8] = vli;
    }
    __syncthreads();

    // ---- GEMM2: A = H2, B frags from W2f
    f32x4 acc2[2][2] = {};
#pragma unroll
    for (int lc = 0; lc < 6; ++lc) {
        const int ka = ASRC[lc] * 64;
        const int kb = BSRC[lc];
#pragma unroll
        for (int kh = 0; kh < 2; ++kh) {
            s16x8 a0 = *(const s16x8*)&H2[frow * 264 + ka + kh * 32 + fcol];
            s16x8 a1 = *(const s16x8*)&H2[(16 + frow) * 264 + ka + kh * 32 + fcol];
#pragma unroll
            for (int n = 0; n < 2; ++n) {
                s16x8 bfv = W2v[(size_t)((((wv * 2 + n) * 4 + kb) * 2 + kh) * 64 + lane)];
                acc2[0][n] = __builtin_amdgcn_mfma_f32_16x16x32_bf16(a0, bfv, acc2[0][n], 0, 0, 0);
                acc2[1][n] = __builtin_amdgcn_mfma_f32_16x16x32_bf16(a1, bfv, acc2[1][n], 0, 0, 0);
            }
        }
    }
    // cL aliases aL (smemA): all aL reads completed before the barrier above
    // GEMM2; no thread reads smemA during GEMM2.
#pragma unroll
    for (int m = 0; m < 2; ++m)
#pragma unroll
        for (int n = 0; n < 2; ++n)
#pragma unroll
            for (int r = 0; r < 4; ++r)
                cL[(m * 16 + rbase + r) * 132 + wv * 32 + n * 16 + cidx] = acc2[m][n][r];
    __syncthreads();

    // ---- phase 8: gate + compact coalesced store (lane=t)
    if (valid) {
        int h = rows[t], j = cols[t];
        size_t wbase = (size_t)rs8[h] + j;
        f32x4 cr0 = *(const f32x4*)&cL[tl * 132 + cg * 8];
        f32x4 cr1 = *(const f32x4*)&cL[tl * 132 + cg * 8 + 4];
        f32x4 ci0 = *(const f32x4*)&cL[tl * 132 + 64 + cg * 8];
        f32x4 ci1 = *(const f32x4*)&cL[tl * 132 + 64 + cg * 8 + 4];
#pragma unroll
        for (int ci = 0; ci < 8; ++ci) {
            int c = cg * 8 + ci;
            float cr  = (ci < 4) ? cr0[ci & 3] : cr1[ci & 3];
            float cii = (ci < 4) ? ci0[ci & 3] : ci1[ci & 3];
            float xr = Xcr[(size_t)(b * 64 + c) * T128 + t];
            float xi = Xci[(size_t)(b * 64 + c) * T128 + t];
            float r3 = sqrtf(cr * cr + cii * cii);
            float gm = glu_mags[(size_t)c * T + t];
            float gp = glu_phases[(size_t)c * T + t];
            float sg = 1.0f / (1.0f + expf(-(r3 + gm)));
            float ux, uy;
            if (r3 > 0.f) { float ir3 = 1.0f / r3; ux = cr * ir3; uy = cii * ir3; }
            else { ux = 1.f; uy = 0.f; }
            float sp, cp;
            sincosf(gp, &sp, &cp);
            float gx = sg * (ux * cp - uy * sp);
            float gy = sg * (ux * sp + uy * cp);
            size_t base = (size_t)(b * 64 + c) * T8cap + wbase;
            Xgr[base] = __float2bfloat16(xr * gx - xi * gy);
            Xgi[base] = __float2bfloat16(xr * gy + xi * gx);
        }
    }
}

// ------- depthwise conv + add (bf16 y, h-major rows, 8-wide, XCD swizzle)
__global__ __launch_bounds__(256) void conv_add_kernel(
    const bf16* __restrict__ y, const float* __restrict__ dw,
    float* __restrict__ out)
{
    const int nb = gridDim.x;
    const int chunk = nb >> 3;
    const int orig = blockIdx.x;
    const int swz = (orig & 7) * chunk + (orig >> 3);   // bijective: nb % 8 == 0
    int g = swz * 256 + threadIdx.x;
    int w8 = g % 90;
    int rem = g / 90;
    int h = rem % Hh;
    int bc = rem / Hh;
    int c = bc & (Cc - 1);
    int w = w8 * 8;
    int walt = (w >= Ww / 2) ? (w - Ww / 2) : (w + Ww / 2);
    float acc[8];
    {
        s16x8 v0 = *(const s16x8*)&y[((size_t)h * BC + bc) * NI + w];
#pragma unroll
        for (int e = 0; e < 8; ++e) acc[e] = bfs2f(v0[e]);
    }
#pragma unroll
    for (int k = 0; k < 11; ++k) {
        int hp = h + k - 5;
        int hh, ww;
        if (hp < 0)        { hh = -1 - hp;         ww = walt; }
        else if (hp >= Hh) { hh = 2 * Hh - 1 - hp; ww = walt; }
        else               { hh = hp;              ww = w; }
        s16x8 v = *(const s16x8*)&y[((size_t)hh * BC + bc) * NI + ww];
        float dwk = dw[c * 11 + k];
#pragma unroll
        for (int e = 0; e < 8; ++e)
            acc[e] = fmaf(dwk, bfs2f(v[e]), acc[e]);
    }
    float* ob = &out[((size_t)bc * Hh + h) * Ww + w];
    *(float4*)&ob[0] = make_float4(acc[0], acc[1], acc[2], acc[3]);
    *(float4*)&ob[4] = make_float4(acc[4], acc[5], acc[6], acc[7]);
}

// ------------------------------------------------------------------ launch
extern "C" void kernel_launch(void* const* d_in, const int* in_sizes, int n_in,
                              void* d_out, int out_size, void* d_ws, size_t ws_size,
                              hipStream_t stream)
{
    const float* x      = (const float*)d_in[0];
    const float* mean_r = (const float*)d_in[1];
    const float* mean_i = (const float*)d_in[2];
    const float* stdv   = (const float*)d_in[3];
    const float* mags_r = (const float*)d_in[4];
    const float* mags_i = (const float*)d_in[5];
    const float* bias_r = (const float*)d_in[6];
    const float* bias_i = (const float*)d_in[7];
    const float* w1_r   = (const float*)d_in[8];
    const float* w1_i   = (const float*)d_in[9];
    const float* brelu  = (const float*)d_in[10];
    const float* w2_r   = (const float*)d_in[11];
    const float* w2_i   = (const float*)d_in[12];
    const float* glu_m  = (const float*)d_in[13];
    const float* glu_p  = (const float*)d_in[14];
    const float* dw     = (const float*)d_in[15];
    const int*   rows   = (const int*)d_in[16];
    const int*   cols   = (const int*)d_in[17];
    const int T = in_sizes[16];
    const int T128 = ((T + 127) / 128) * 128;
    const int T8cap = ((T + 7 * Hh) + 127) & ~127;

    char* ws = (char*)d_ws;
    const size_t SApc  = (size_t)CM * KA * 2;             // 35,389,440
    const size_t XC_SZ = (size_t)BC * T128 * 4;           // ~42.7 MB
    const size_t XG_SZ = (size_t)BC * T8cap * 2;          // ~22.0 MB
    bf16*  Ap  = (bf16*)ws;
    bf16*  Aq  = (bf16*)(ws + SApc);
    float* Xcr = (float*)(ws + 2 * SApc);
    float* Xci = (float*)(ws + 2 * SApc + XC_SZ);
    bf16*  Xgr = (bf16*)ws;
    bf16*  Xgi = (bf16*)(ws + XG_SZ);
    bf16*  y   = (bf16*)(ws + 2 * XG_SZ);
    size_t boff = 2 * SApc + 2 * XC_SZ;                   // ~156.1 MB
    bf16*  Bce = (bf16*)(ws + boff);
    bf16*  Bse = (bf16*)(ws + boff + (size_t)NF * KF3 * 2);
    bf16*  Bti = (bf16*)(ws + boff + 2 * (size_t)NF * KF3 * 2);
    bf16*  W1f = (bf16*)(ws + boff + 2 * (size_t)NF * KF3 * 2 + (size_t)NI * KI * 2);
    bf16*  W2f = W1f + 32768;
    int*   rs  = (int*)(W2f + 32768);
    int*   rs8 = rs + (Hh + 2);

    build_bfwd_kernel<<<(NF * KF3 + 255) / 256, 256, 0, stream>>>(Bce, Bse);
    build_binv_kernel<<<(NI * KI + 255) / 256, 256, 0, stream>>>(Bti);
    build_wf_kernel<<<(2 * 32768 + 255) / 256, 256, 0, stream>>>(
        w1_r, w1_i, w2_r, w2_i, W1f, W2f);
    row_starts_kernel<<<1, 512, 0, stream>>>(rows, T, rs, rs8);

    for (int ch = 0; ch < CHUNKS; ++ch) {
        pack_kernel<<<(CM * 384 + 255) / 256, 256, 0, stream>>>(
            x, Ap, Aq, ch * HPC);
        gemm_fwd_compact_kernel<<<dim3(CM / 128, NF / 128, 2), 256, 0, stream>>>(
            Ap, Aq, Bce, Bse, Xcr, Xci, rs, T128, ch * HPC);
    }

    pad_zero_kernel<<<Hh, 256, 0, stream>>>(Xgr, Xgi, rs, rs8, T8cap);

    const int nT32 = (T + 31) / 32;
    middle_fused_kernel<<<dim3(nT32, Bb), 256, 0, stream>>>(
        Xcr, Xci, Xgr, Xgi, mean_r, mean_i, stdv, mags_r, mags_i,
        bias_r, bias_i, W1f, W2f, brelu, glu_m, glu_p, rows, cols, rs8,
        T, T128, T8cap);

    gemm_inv_kernel<<<dim3(Hh, NI / 128), 256, 0, stream>>>(
        Xgr, Xgi, Bti, rs8, y, T8cap);

    conv_add_kernel<<<(Bb * Cc * Hh * 90) / 256, 256, 0, stream>>>(y, dw, (float*)d_out);
}

// Round 24
// 455.067 us; speedup vs baseline: 1.2774x; 1.0157x over previous
//
#include <hip/hip_runtime.h>
#include <hip/hip_bf16.h>
#include <math.h>

#define Hh 360
#define Ww 720
#define Cc 64
#define Bb 2
#define BC (Bb*Cc)        // 128
#define Mrows (BC*Hh)     // 46080
#define CHUNKS 2
#define CM (Mrows/CHUNKS) // 23040
#define HPC (Hh/CHUNKS)   // 180 latitudes per chunk
#define KA 768            // A row: [hi(384) | lo(384)]
#define KF3 1152          // GEMM K loop: [hi.Bhi | lo.Bhi | hi.Blo]
#define NF 384            // fwd N (361 bins padded)
#define KI 768            // inv K: [Re(384) | Im(384)]
#define NI 768            // inv C row stride (720 used)
#define NSTORE_INV 720
#define SCALE 0.037267799624996496f   // 1/sqrt(720)
#define TWO_PI 6.2831853071795864769f

typedef __attribute__((ext_vector_type(8))) short s16x8;
typedef __attribute__((ext_vector_type(4))) float f32x4;
typedef __hip_bfloat16 bf16;

__device__ __forceinline__ void gload_lds16(const void* g, void* l) {
    __builtin_amdgcn_global_load_lds(
        (const __attribute__((address_space(1))) unsigned int*)g,
        (__attribute__((address_space(3))) unsigned int*)l, 16, 0, 0);
}
__device__ __forceinline__ short f2bfs(float v) {
    bf16 h = __float2bfloat16(v); short s; __builtin_memcpy(&s, &h, 2); return s;
}
__device__ __forceinline__ float bfs2f(short s) {
    bf16 h; __builtin_memcpy(&h, &s, 2); return __bfloat162float(h);
}

// ---------------------------------------------------------- B-matrix builds
// B stays 1152-wide: [Bhi | Bhi | Blo].
__global__ __launch_bounds__(256) void build_bfwd_kernel(bf16* __restrict__ Bc,
                                                         bf16* __restrict__ Bs) {
    int g = blockIdx.x * 256 + threadIdx.x;
    if (g >= NF * KF3) return;
    int wext = g % KF3;
    int j = g / KF3;
    int blk = wext / 384;
    int w = wext - blk * 384;
    float c = 0.f, s = 0.f;
    if (w <= 360 && j <= 360) {
        int idx = (j * w) % Ww;
        float a = (TWO_PI / Ww) * (float)idx;
        float sv, cv;
        sincosf(a, &sv, &cv);
        c = SCALE * cv;
        s = -SCALE * sv;
    }
    bf16 chi = __float2bfloat16(c);
    bf16 shi = __float2bfloat16(s);
    if (blk == 2) {
        Bc[g] = __float2bfloat16(c - __bfloat162float(chi));
        Bs[g] = __float2bfloat16(s - __bfloat162float(shi));
    } else {
        Bc[g] = chi;
        Bs[g] = shi;
    }
}

__global__ __launch_bounds__(256) void build_binv_kernel(bf16* __restrict__ Bi) {
    int g = blockIdx.x * 256 + threadIdx.x;
    if (g >= NI * KI) return;
    int k = g % KI, n = g / KI;
    float v = 0.f;
    if (n < NSTORE_INV) {
        if (k <= 360) {
            int j = k;
            float f = (j == 0 || j == 360) ? 1.f : 2.f;
            int idx = (j * n) % Ww;
            v = SCALE * f * cosf((TWO_PI / Ww) * (float)idx);
        } else if (k >= 384 && k <= 744) {
            int j = k - 384;
            int idx = (j * n) % Ww;
            v = -2.f * SCALE * sinf((TWO_PI / Ww) * (float)idx);
        }
    }
    Bi[g] = __float2bfloat16(v);
}

// W fragment-packed: s16x8 index = fid*64 + lane, fid = ((n16*4 + kb)*2 + kh).
__global__ __launch_bounds__(256) void build_wf_kernel(
    const float* __restrict__ w1_r, const float* __restrict__ w1_i,
    const float* __restrict__ w2_r, const float* __restrict__ w2_i,
    bf16* __restrict__ W1f, bf16* __restrict__ W2f)
{
    int g = blockIdx.x * 256 + threadIdx.x;
    if (g >= 2 * 32768) return;
    int which = g >> 15;
    int gg = g & 32767;
    int e = gg & 7, lane = (gg >> 3) & 63, kh = (gg >> 9) & 1;
    int kb = (gg >> 10) & 3, n16 = (gg >> 12) & 7;
    int frow = lane & 15, fcol = (lane >> 4) * 8;
    int n = n16 * 16 + frow;
    int kfull = kb * 64 + kh * 32 + fcol + e;
    int kk = kfull & 127, islo = kfull >> 7;
    const float* wr = which ? w2_r : w1_r;
    const float* wi = which ? w2_i : w1_i;
    float v;
    if (n < 64) v = (kk < 64) ? wr[n * 64 + kk] : -wi[n * 64 + kk - 64];
    else { int p = n - 64; v = (kk < 64) ? wi[p * 64 + kk] : wr[p * 64 + kk - 64]; }
    bf16 h = __float2bfloat16(v);
    bf16 out = islo ? __float2bfloat16(v - __bfloat162float(h)) : h;
    (which ? W2f : W1f)[gg] = out;
}

// ------------- row starts (compact + 8-padded), parallel prefix scan
__global__ __launch_bounds__(512) void row_starts_kernel(const int* __restrict__ rows,
                                                         int T, int* __restrict__ rs,
                                                         int* __restrict__ rs8) {
    __shared__ int scan[512];
    const int h = threadIdx.x;
    if (h <= Hh) {
        if (h == Hh) rs[Hh] = T;
        else {
            int lo = 0, hi = T;
            while (lo < hi) {
                int mid = (lo + hi) >> 1;
                if (rows[mid] < h) lo = mid + 1; else hi = mid;
            }
            rs[h] = lo;
        }
    }
    __syncthreads();
    int c8 = 0;
    if (h < Hh) c8 = ((rs[h + 1] - rs[h]) + 7) & ~7;
    scan[h] = c8;
    __syncthreads();
    for (int off = 1; off < 512; off <<= 1) {
        int add = (h >= off) ? scan[h - off] : 0;
        __syncthreads();
        scan[h] += add;
        __syncthreads();
    }
    if (h < Hh) rs8[h] = scan[h] - c8;       // exclusive
    if (h == Hh) rs8[Hh] = scan[Hh - 1];     // total
}

// ---------- pack x chunk -> A [hi|lo], h-major rows; one thread per (row,w4)
// float4 main read + short4 stores; per-element math identical to r23.
__global__ __launch_bounds__(256) void pack_kernel(const float* __restrict__ x,
                                                   bf16* __restrict__ Ap,
                                                   bf16* __restrict__ Aq,
                                                   int hbase) {
    int g = blockIdx.x * 256 + threadIdx.x;
    if (g >= CM * 96) return;
    int w4 = g % 96;
    int r = g / 96;
    int hl = r >> 7;
    int bc = r & 127;
    const float* xrow = x + ((size_t)bc * Hh + hbase + hl) * Ww;
    const int wb = w4 * 4;
    float4 fw = *(const float4*)&xrow[wb];
    float fwv[4] = {fw.x, fw.y, fw.z, fw.w};
    short ph[4], qh[4], pl[4], ql[4];
#pragma unroll
    for (int e = 0; e < 4; ++e) {
        int w = wb + e;
        float p = 0.f, q = 0.f;
        if (w == 0 || w == 360) {
            p = fwv[e];
        } else if (w < 360) {
            float a = fwv[e];
            float b = xrow[Ww - w];
            p = a + b;
            q = a - b;
        }
        short phe = f2bfs(p);
        short qhe = f2bfs(q);
        ph[e] = phe; qh[e] = qhe;
        pl[e] = f2bfs(p - bfs2f(phe));
        ql[e] = f2bfs(q - bfs2f(qhe));
    }
    size_t base = (size_t)r * KA + wb;
    *(short4*)&Ap[base]       = make_short4(ph[0], ph[1], ph[2], ph[3]);
    *(short4*)&Aq[base]       = make_short4(qh[0], qh[1], qh[2], qh[3]);
    *(short4*)&Ap[base + 384] = make_short4(pl[0], pl[1], pl[2], pl[3]);
    *(short4*)&Aq[base + 384] = make_short4(ql[0], ql[1], ql[2], ql[3]);
}

// --------- pad-only zero of Xg: rows [cnt, cnt8) per (bc,h) (<= 7 elems)
__global__ __launch_bounds__(256) void pad_zero_kernel(
    bf16* __restrict__ Xgr, bf16* __restrict__ Xgi,
    const int* __restrict__ rs, const int* __restrict__ rs8, int T8cap)
{
    const int h = blockIdx.x;
    const int cnt = rs[h + 1] - rs[h];
    const int t0 = rs8[h];
    const int cnt8 = rs8[h + 1] - t0;
    const int pad = cnt8 - cnt;
    if (pad <= 0) return;
    for (int idx = threadIdx.x; idx < BC * 8; idx += 256) {
        int bc = idx >> 3;
        int e = idx & 7;
        if (e < pad) {
            size_t off = (size_t)bc * T8cap + t0 + cnt + e;
            Xgr[off] = __float2bfloat16(0.f);
            Xgi[off] = __float2bfloat16(0.f);
        }
    }
}

// ------------------- fwd MFMA GEMM, h-uniform tiles + early exit + compact C
__global__ __launch_bounds__(256) void gemm_fwd_compact_kernel(
    const bf16* __restrict__ Ap, const bf16* __restrict__ Aq,
    const bf16* __restrict__ Bc, const bf16* __restrict__ Bsm,
    float* __restrict__ Xcr, float* __restrict__ Xci,
    const int* __restrict__ rs, int T128, int hbase)
{
    __shared__ __align__(128) bf16 As[128][64];
    __shared__ __align__(128) bf16 Bs[128][64];
    const int h = hbase + blockIdx.x;       // one latitude per m-tile
    const int t0 = rs[h];
    const int cnt = rs[h + 1] - t0;
    const int n0 = blockIdx.y * 128;
    if (n0 >= cnt) return;                   // tile stores nothing: dead work
    const bf16* A  = blockIdx.z ? Aq : Ap;
    const bf16* Bt = blockIdx.z ? Bsm : Bc;
    float* Xc      = blockIdx.z ? Xci : Xcr;
    const int tid = threadIdx.x;
    const int lane = tid & 63;
    const int wave = tid >> 6;
    const int m0 = blockIdx.x * 128;
    const int wr = (wave >> 1) * 64;
    const int wc = (wave & 1) * 64;
    const int srow = tid >> 3;
    const int scol = (tid & 7) << 3;
    f32x4 acc[4][4] = {};
    for (int k0 = 0; k0 < KF3; k0 += 64) {
        const int ka0 = (k0 >= 768) ? (k0 - 768) : k0;
#pragma unroll
        for (int i = 0; i < 4; ++i) {
            const bf16* ga = A  + (size_t)(m0 + i * 32 + srow) * KA + ka0 + scol;
            const bf16* gb = Bt + (size_t)(n0 + i * 32 + srow) * KF3 + k0 + scol;
            gload_lds16(ga, ((char*)&As[0][0]) + (size_t)(i * 256 + tid) * 16);
            gload_lds16(gb, ((char*)&Bs[0][0]) + (size_t)(i * 256 + tid) * 16);
        }
        __syncthreads();
#pragma unroll
        for (int kk = 0; kk < 64; kk += 32) {
            s16x8 a[4], b[4];
#pragma unroll
            for (int m = 0; m < 4; ++m)
                a[m] = *(const s16x8*)&As[wr + m * 16 + (lane & 15)][kk + (lane >> 4) * 8];
#pragma unroll
            for (int n = 0; n < 4; ++n)
                b[n] = *(const s16x8*)&Bs[wc + n * 16 + (lane & 15)][kk + (lane >> 4) * 8];
#pragma unroll
            for (int m = 0; m < 4; ++m)
#pragma unroll
                for (int n = 0; n < 4; ++n)
                    acc[m][n] = __builtin_amdgcn_mfma_f32_16x16x32_bf16(a[m], b[n], acc[m][n], 0, 0, 0);
        }
        __syncthreads();
    }
    const int rbase = (lane >> 4) * 4;
    const int cidx = lane & 15;
#pragma unroll
    for (int m = 0; m < 4; ++m) {
#pragma unroll
        for (int r = 0; r < 4; ++r) {
            int bc = wr + m * 16 + rbase + r;   // local row within h-tile
#pragma unroll
            for (int n = 0; n < 4; ++n) {
                int j = n0 + wc + n * 16 + cidx;
                if (j < cnt)
                    Xc[(size_t)bc * T128 + t0 + j] = acc[m][n][r];
            }
        }
    }
}

// -------------- inverse GEMM, h-uniform tiles + K-tile early-skip; y h-major
__global__ __launch_bounds__(256) void gemm_inv_kernel(
    const bf16* __restrict__ Xgr, const bf16* __restrict__ Xgi,
    const bf16* __restrict__ Bt, const int* __restrict__ rs8,
    bf16* __restrict__ C, int T8cap)
{
    __shared__ __align__(128) bf16 As[128][64];
    __shared__ __align__(128) bf16 Bs[128][64];
    const int h = blockIdx.x;               // one latitude per m-tile
    const int t0v = rs8[h];
    const int cnt8 = rs8[h + 1] - t0v;
    const int n0 = blockIdx.y * 128;
    const int tid = threadIdx.x;
    const int lane = tid & 63;
    const int wave = tid >> 6;
    const int wr = (wave >> 1) * 64;
    const int wc = (wave & 1) * 64;
    const int srow = tid >> 3;
    const int scol = (tid & 7) << 3;
    f32x4 acc[4][4] = {};
    for (int k0 = 0; k0 < KI; k0 += 64) {
        const int jb = (k0 < 384) ? k0 : (k0 - 384);
        if (jb >= cnt8) continue;           // A-tile all zero: acc += 0, skip
        const bf16* base = (k0 < 384) ? Xgr : Xgi;
        const int j0 = jb + scol;
#pragma unroll
        for (int i = 0; i < 4; ++i)
            gload_lds16(Bt + (size_t)(n0 + i * 32 + srow) * KI + k0 + scol,
                        ((char*)&Bs[0][0]) + (size_t)(i * 256 + tid) * 16);
#pragma unroll
        for (int i = 0; i < 4; ++i) {
            int bc = i * 32 + srow;
            s16x8 v = (s16x8){0, 0, 0, 0, 0, 0, 0, 0};
            if (j0 < cnt8)
                v = *(const s16x8*)(base + (size_t)bc * T8cap + t0v + j0);
            *(s16x8*)&As[bc][scol] = v;
        }
        __syncthreads();
#pragma unroll
        for (int kk = 0; kk < 64; kk += 32) {
            s16x8 a[4], b[4];
#pragma unroll
            for (int m = 0; m < 4; ++m)
                a[m] = *(const s16x8*)&As[wr + m * 16 + (lane & 15)][kk + (lane >> 4) * 8];
#pragma unroll
            for (int n = 0; n < 4; ++n)
                b[n] = *(const s16x8*)&Bs[wc + n * 16 + (lane & 15)][kk + (lane >> 4) * 8];
#pragma unroll
            for (int m = 0; m < 4; ++m)
#pragma unroll
                for (int n = 0; n < 4; ++n)
                    acc[m][n] = __builtin_amdgcn_mfma_f32_16x16x32_bf16(a[m], b[n], acc[m][n], 0, 0, 0);
        }
        __syncthreads();
    }
    const int rbase = (lane >> 4) * 4;
    const int cidx = lane & 15;
#pragma unroll
    for (int m = 0; m < 4; ++m) {
#pragma unroll
        for (int n = 0; n < 4; ++n) {
            int gcol = n0 + wc + n * 16 + cidx;
            if (gcol < NSTORE_INV) {
#pragma unroll
                for (int r = 0; r < 4; ++r) {
                    int bc = wr + m * 16 + rbase + r;
                    C[(size_t)(h * BC + bc) * NI + gcol] = __float2bfloat16(acc[m][n][r]);
                }
            }
        }
    }
}

// ------------------------------------------------ fused middle stage (v3)
// FROZEN: verbatim green r17 middle. Three independent edits (fastmath,
// register-cache, both) each broke correctness (r12/r18/r19) — do not touch.
__device__ __forceinline__ float gelu_exact(float v) {
    return 0.5f * v * (1.0f + erff(v * 0.7071067811865476f));
}

__global__ __launch_bounds__(256, 4) void middle_fused_kernel(
    const float* __restrict__ Xcr, const float* __restrict__ Xci,
    bf16* __restrict__ Xgr, bf16* __restrict__ Xgi,
    const float* __restrict__ mean_r, const float* __restrict__ mean_i,
    const float* __restrict__ stdv,
    const float* __restrict__ mags_r, const float* __restrict__ mags_i,
    const float* __restrict__ bias_r, const float* __restrict__ bias_i,
    const bf16* __restrict__ W1f, const bf16* __restrict__ W2f,
    const float* __restrict__ brelu_p,
    const float* __restrict__ glu_mags, const float* __restrict__ glu_phases,
    const int* __restrict__ rows, const int* __restrict__ cols,
    const int* __restrict__ rs8,
    int T, int T128, int T8cap)
{
    __shared__ __align__(16) char smemA[32 * 264 * 2];   // 16,896 B
    __shared__ __align__(16) char smemB[32 * 264 * 2];
    bf16*  H1 = (bf16*)smemA;    // [32][264] hi/lo split input
    float* aL = (float*)smemA;   // [32][132] GEMM1 result
    float* cL = (float*)smemA;   // [32][132] GEMM2 result
    bf16*  H2 = (bf16*)smemB;    // [32][264] gelu output

    const int tid = threadIdx.x;
    const int b = blockIdx.y;
    const int t0 = blockIdx.x * 32;
    const int tl = tid & 31;
    const int cg = tid >> 5;          // 0..7
    const int t = t0 + tl;
    const bool valid = (t < T);
    const int lane = tid & 63;
    const int wv = tid >> 6;          // 0..3
    const int frow = lane & 15;
    const int fcol = (lane >> 4) * 8;
    const s16x8* W1v = (const s16x8*)W1f;
    const s16x8* W2v = (const s16x8*)W2f;
    constexpr int ASRC[6] = {0, 1, 2, 3, 0, 1};
    constexpr int BSRC[6] = {0, 1, 0, 1, 2, 3};

    // ---- phase 1: normalize -> H1 (lane=t, coalesced global reads)
    {
        float mr = 0.f, mi_ = 0.f, isd = 0.f;
        if (valid) { mr = mean_r[t]; mi_ = mean_i[t]; isd = 1.0f / (1e-12f + stdv[t]); }
        s16x8 vhr, vhi, vlr, vli;
#pragma unroll
        for (int ci = 0; ci < 8; ++ci) {
            int c = cg * 8 + ci;
            float xr = 0.f, xi = 0.f;
            if (valid) {
                xr = Xcr[(size_t)(b * 64 + c) * T128 + t];
                xi = Xci[(size_t)(b * 64 + c) * T128 + t];
            }
            float hr = (xr - mr) * isd;
            float hi = (xi - mi_) * isd;
            float h1r = fmaf(hr, mags_r[c], fmaf(-hi, mags_i[c], bias_r[c]));
            float h1i = fmaf(hr, mags_i[c], fmaf(hi, mags_r[c], bias_i[c]));
            short rh = f2bfs(h1r), ih = f2bfs(h1i);
            vhr[ci] = rh; vhi[ci] = ih;
            vlr[ci] = f2bfs(h1r - bfs2f(rh));
            vli[ci] = f2bfs(h1i - bfs2f(ih));
        }
        *(s16x8*)&H1[tl * 264 + cg * 8]       = vhr;
        *(s16x8*)&H1[tl * 264 + 64 + cg * 8]  = vhi;
        *(s16x8*)&H1[tl * 264 + 128 + cg * 8] = vlr;
        *(s16x8*)&H1[tl * 264 + 192 + cg * 8] = vli;
    }
    __syncthreads();

    // ---- GEMM1: A = H1 [32][264], B frags direct from W1f (L2)
    f32x4 acc[2][2] = {};
#pragma unroll
    for (int lc = 0; lc < 6; ++lc) {
        const int ka = ASRC[lc] * 64;
        const int kb = BSRC[lc];
#pragma unroll
        for (int kh = 0; kh < 2; ++kh) {
            s16x8 a0 = *(const s16x8*)&H1[frow * 264 + ka + kh * 32 + fcol];
            s16x8 a1 = *(const s16x8*)&H1[(16 + frow) * 264 + ka + kh * 32 + fcol];
#pragma unroll
            for (int n = 0; n < 2; ++n) {
                s16x8 bfv = W1v[(size_t)((((wv * 2 + n) * 4 + kb) * 2 + kh) * 64 + lane)];
                acc[0][n] = __builtin_amdgcn_mfma_f32_16x16x32_bf16(a0, bfv, acc[0][n], 0, 0, 0);
                acc[1][n] = __builtin_amdgcn_mfma_f32_16x16x32_bf16(a1, bfv, acc[1][n], 0, 0, 0);
            }
        }
    }
    __syncthreads();

    // ---- phase 3: acc -> aL (overwrites H1)
    const int rbase = (lane >> 4) * 4;
    const int cidx = lane & 15;
#pragma unroll
    for (int m = 0; m < 2; ++m)
#pragma unroll
        for (int n = 0; n < 2; ++n)
#pragma unroll
            for (int r = 0; r < 4; ++r)
                aL[(m * 16 + rbase + r) * 132 + wv * 32 + n * 16 + cidx] = acc[m][n][r];
    __syncthreads();

    // ---- phase 4: gelu (lane=t) -> H2
    {
        const float brelu = brelu_p[0];
        f32x4 ar0 = *(const f32x4*)&aL[tl * 132 + cg * 8];
        f32x4 ar1 = *(const f32x4*)&aL[tl * 132 + cg * 8 + 4];
        f32x4 ai0 = *(const f32x4*)&aL[tl * 132 + 64 + cg * 8];
        f32x4 ai1 = *(const f32x4*)&aL[tl * 132 + 64 + cg * 8 + 4];
        s16x8 vhr, vhi, vlr, vli;
#pragma unroll
        for (int ci = 0; ci < 8; ++ci) {
            float ar = (ci < 4) ? ar0[ci & 3] : ar1[ci & 3];
            float ai = (ci < 4) ? ai0[ci & 3] : ai1[ci & 3];
            float r = sqrtf(ar * ar + ai * ai);
            float g = gelu_exact(r + brelu);
            float h2r, h2i;
            if (r > 0.f) { float f = g / r; h2r = f * ar; h2i = f * ai; }
            else { h2r = g; h2i = 0.f; }
            short rh = f2bfs(h2r), ih = f2bfs(h2i);
            vhr[ci] = rh; vhi[ci] = ih;
            vlr[ci] = f2bfs(h2r - bfs2f(rh));
            vli[ci] = f2bfs(h2i - bfs2f(ih));
        }
        *(s16x8*)&H2[tl * 264 + cg * 8]       = vhr;
        *(s16x8*)&H2[tl * 264 + 64 + cg * 8]  = vhi;
        *(s16x8*)&H2[tl * 264 + 128 + cg * 8] = vlr;
        *(s16x8*)&H2[tl * 264 + 192 + cg * 8] = vli;
    }
    __syncthreads();

    // ---- GEMM2: A = H2, B frags from W2f
    f32x4 acc2[2][2] = {};
#pragma unroll
    for (int lc = 0; lc < 6; ++lc) {
        const int ka = ASRC[lc] * 64;
        const int kb = BSRC[lc];
#pragma unroll
        for (int kh = 0; kh < 2; ++kh) {
            s16x8 a0 = *(const s16x8*)&H2[frow * 264 + ka + kh * 32 + fcol];
            s16x8 a1 = *(const s16x8*)&H2[(16 + frow) * 264 + ka + kh * 32 + fcol];
#pragma unroll
            for (int n = 0; n < 2; ++n) {
                s16x8 bfv = W2v[(size_t)((((wv * 2 + n) * 4 + kb) * 2 + kh) * 64 + lane)];
                acc2[0][n] = __builtin_amdgcn_mfma_f32_16x16x32_bf16(a0, bfv, acc2[0][n], 0, 0, 0);
                acc2[1][n] = __builtin_amdgcn_mfma_f32_16x16x32_bf16(a1, bfv, acc2[1][n], 0, 0, 0);
            }
        }
    }
    // cL aliases aL (smemA): all aL reads completed before the barrier above
    // GEMM2; no thread reads smemA during GEMM2.
#pragma unroll
    for (int m = 0; m < 2; ++m)
#pragma unroll
        for (int n = 0; n < 2; ++n)
#pragma unroll
            for (int r = 0; r < 4; ++r)
                cL[(m * 16 + rbase + r) * 132 + wv * 32 + n * 16 + cidx] = acc2[m][n][r];
    __syncthreads();

    // ---- phase 8: gate + compact coalesced store (lane=t)
    if (valid) {
        int h = rows[t], j = cols[t];
        size_t wbase = (size_t)rs8[h] + j;
        f32x4 cr0 = *(const f32x4*)&cL[tl * 132 + cg * 8];
        f32x4 cr1 = *(const f32x4*)&cL[tl * 132 + cg * 8 + 4];
        f32x4 ci0 = *(const f32x4*)&cL[tl * 132 + 64 + cg * 8];
        f32x4 ci1 = *(const f32x4*)&cL[tl * 132 + 64 + cg * 8 + 4];
#pragma unroll
        for (int ci = 0; ci < 8; ++ci) {
            int c = cg * 8 + ci;
            float cr  = (ci < 4) ? cr0[ci & 3] : cr1[ci & 3];
            float cii = (ci < 4) ? ci0[ci & 3] : ci1[ci & 3];
            float xr = Xcr[(size_t)(b * 64 + c) * T128 + t];
            float xi = Xci[(size_t)(b * 64 + c) * T128 + t];
            float r3 = sqrtf(cr * cr + cii * cii);
            float gm = glu_mags[(size_t)c * T + t];
            float gp = glu_phases[(size_t)c * T + t];
            float sg = 1.0f / (1.0f + expf(-(r3 + gm)));
            float ux, uy;
            if (r3 > 0.f) { float ir3 = 1.0f / r3; ux = cr * ir3; uy = cii * ir3; }
            else { ux = 1.f; uy = 0.f; }
            float sp, cp;
            sincosf(gp, &sp, &cp);
            float gx = sg * (ux * cp - uy * sp);
            float gy = sg * (ux * sp + uy * cp);
            size_t base = (size_t)(b * 64 + c) * T8cap + wbase;
            Xgr[base] = __float2bfloat16(xr * gx - xi * gy);
            Xgi[base] = __float2bfloat16(xr * gy + xi * gx);
        }
    }
}

// ------- depthwise conv + add (bf16 y, h-major rows, 8-wide, XCD swizzle)
__global__ __launch_bounds__(256) void conv_add_kernel(
    const bf16* __restrict__ y, const float* __restrict__ dw,
    float* __restrict__ out)
{
    const int nb = gridDim.x;
    const int chunk = nb >> 3;
    const int orig = blockIdx.x;
    const int swz = (orig & 7) * chunk + (orig >> 3);   // bijective: nb % 8 == 0
    int g = swz * 256 + threadIdx.x;
    int w8 = g % 90;
    int rem = g / 90;
    int h = rem % Hh;
    int bc = rem / Hh;
    int c = bc & (Cc - 1);
    int w = w8 * 8;
    int walt = (w >= Ww / 2) ? (w - Ww / 2) : (w + Ww / 2);
    float acc[8];
    {
        s16x8 v0 = *(const s16x8*)&y[((size_t)h * BC + bc) * NI + w];
#pragma unroll
        for (int e = 0; e < 8; ++e) acc[e] = bfs2f(v0[e]);
    }
#pragma unroll
    for (int k = 0; k < 11; ++k) {
        int hp = h + k - 5;
        int hh, ww;
        if (hp < 0)        { hh = -1 - hp;         ww = walt; }
        else if (hp >= Hh) { hh = 2 * Hh - 1 - hp; ww = walt; }
        else               { hh = hp;              ww = w; }
        s16x8 v = *(const s16x8*)&y[((size_t)hh * BC + bc) * NI + ww];
        float dwk = dw[c * 11 + k];
#pragma unroll
        for (int e = 0; e < 8; ++e)
            acc[e] = fmaf(dwk, bfs2f(v[e]), acc[e]);
    }
    float* ob = &out[((size_t)bc * Hh + h) * Ww + w];
    *(float4*)&ob[0] = make_float4(acc[0], acc[1], acc[2], acc[3]);
    *(float4*)&ob[4] = make_float4(acc[4], acc[5], acc[6], acc[7]);
}

// ------------------------------------------------------------------ launch
extern "C" void kernel_launch(void* const* d_in, const int* in_sizes, int n_in,
                              void* d_out, int out_size, void* d_ws, size_t ws_size,
                              hipStream_t stream)
{
    const float* x      = (const float*)d_in[0];
    const float* mean_r = (const float*)d_in[1];
    const float* mean_i = (const float*)d_in[2];
    const float* stdv   = (const float*)d_in[3];
    const float* mags_r = (const float*)d_in[4];
    const float* mags_i = (const float*)d_in[5];
    const float* bias_r = (const float*)d_in[6];
    const float* bias_i = (const float*)d_in[7];
    const float* w1_r   = (const float*)d_in[8];
    const float* w1_i   = (const float*)d_in[9];
    const float* brelu  = (const float*)d_in[10];
    const float* w2_r   = (const float*)d_in[11];
    const float* w2_i   = (const float*)d_in[12];
    const float* glu_m  = (const float*)d_in[13];
    const float* glu_p  = (const float*)d_in[14];
    const float* dw     = (const float*)d_in[15];
    const int*   rows   = (const int*)d_in[16];
    const int*   cols   = (const int*)d_in[17];
    const int T = in_sizes[16];
    const int T128 = ((T + 127) / 128) * 128;
    const int T8cap = ((T + 7 * Hh) + 127) & ~127;

    char* ws = (char*)d_ws;
    const size_t SApc  = (size_t)CM * KA * 2;             // 35,389,440
    const size_t XC_SZ = (size_t)BC * T128 * 4;           // ~42.7 MB
    const size_t XG_SZ = (size_t)BC * T8cap * 2;          // ~22.0 MB
    bf16*  Ap  = (bf16*)ws;
    bf16*  Aq  = (bf16*)(ws + SApc);
    float* Xcr = (float*)(ws + 2 * SApc);
    float* Xci = (float*)(ws + 2 * SApc + XC_SZ);
    bf16*  Xgr = (bf16*)ws;
    bf16*  Xgi = (bf16*)(ws + XG_SZ);
    bf16*  y   = (bf16*)(ws + 2 * XG_SZ);
    size_t boff = 2 * SApc + 2 * XC_SZ;                   // ~156.1 MB
    bf16*  Bce = (bf16*)(ws + boff);
    bf16*  Bse = (bf16*)(ws + boff + (size_t)NF * KF3 * 2);
    bf16*  Bti = (bf16*)(ws + boff + 2 * (size_t)NF * KF3 * 2);
    bf16*  W1f = (bf16*)(ws + boff + 2 * (size_t)NF * KF3 * 2 + (size_t)NI * KI * 2);
    bf16*  W2f = W1f + 32768;
    int*   rs  = (int*)(W2f + 32768);
    int*   rs8 = rs + (Hh + 2);

    build_bfwd_kernel<<<(NF * KF3 + 255) / 256, 256, 0, stream>>>(Bce, Bse);
    build_binv_kernel<<<(NI * KI + 255) / 256, 256, 0, stream>>>(Bti);
    build_wf_kernel<<<(2 * 32768 + 255) / 256, 256, 0, stream>>>(
        w1_r, w1_i, w2_r, w2_i, W1f, W2f);
    row_starts_kernel<<<1, 512, 0, stream>>>(rows, T, rs, rs8);

    for (int ch = 0; ch < CHUNKS; ++ch) {
        pack_kernel<<<(CM * 96 + 255) / 256, 256, 0, stream>>>(
            x, Ap, Aq, ch * HPC);
        gemm_fwd_compact_kernel<<<dim3(CM / 128, NF / 128, 2), 256, 0, stream>>>(
            Ap, Aq, Bce, Bse, Xcr, Xci, rs, T128, ch * HPC);
    }

    pad_zero_kernel<<<Hh, 256, 0, stream>>>(Xgr, Xgi, rs, rs8, T8cap);

    const int nT32 = (T + 31) / 32;
    middle_fused_kernel<<<dim3(nT32, Bb), 256, 0, stream>>>(
        Xcr, Xci, Xgr, Xgi, mean_r, mean_i, stdv, mags_r, mags_i,
        bias_r, bias_i, W1f, W2f, brelu, glu_m, glu_p, rows, cols, rs8,
        T, T128, T8cap);

    gemm_inv_kernel<<<dim3(Hh, NI / 128), 256, 0, stream>>>(
        Xgr, Xgi, Bti, rs8, y, T8cap);

    conv_add_kernel<<<(Bb * Cc * Hh * 90) / 256, 256, 0, stream>>>(y, dw, (float*)d_out);
}

// Round 25
// 445.353 us; speedup vs baseline: 1.3052x; 1.0218x over previous
//
#include <hip/hip_runtime.h>
#include <hip/hip_bf16.h>
#include <math.h>

#define Hh 360
#define Ww 720
#define Cc 64
#define Bb 2
#define BC (Bb*Cc)        // 128
#define Mrows (BC*Hh)     // 46080
#define CHUNKS 2
#define CM (Mrows/CHUNKS) // 23040
#define HPC (Hh/CHUNKS)   // 180 latitudes per chunk
#define KA 768            // A row: [hi(384) | lo(384)]
#define KF3 1152          // GEMM K loop: [hi.Bhi | lo.Bhi | hi.Blo]
#define NF 384            // fwd N (361 bins padded)
#define KI 768            // inv K: [Re(384) | Im(384)]
#define NI 768            // inv C row stride (720 used)
#define NSTORE_INV 720
#define SCALE 0.037267799624996496f   // 1/sqrt(720)
#define TWO_PI 6.2831853071795864769f

typedef __attribute__((ext_vector_type(8))) short s16x8;
typedef __attribute__((ext_vector_type(4))) float f32x4;
typedef __hip_bfloat16 bf16;

__device__ __forceinline__ void gload_lds16(const void* g, void* l) {
    __builtin_amdgcn_global_load_lds(
        (const __attribute__((address_space(1))) unsigned int*)g,
        (__attribute__((address_space(3))) unsigned int*)l, 16, 0, 0);
}
__device__ __forceinline__ short f2bfs(float v) {
    bf16 h = __float2bfloat16(v); short s; __builtin_memcpy(&s, &h, 2); return s;
}
__device__ __forceinline__ float bfs2f(short s) {
    bf16 h; __builtin_memcpy(&h, &s, 2); return __bfloat162float(h);
}

// ---------------------------------------------------------- B-matrix builds
// B stays 1152-wide: [Bhi | Bhi | Blo].
__global__ __launch_bounds__(256) void build_bfwd_kernel(bf16* __restrict__ Bc,
                                                         bf16* __restrict__ Bs) {
    int g = blockIdx.x * 256 + threadIdx.x;
    if (g >= NF * KF3) return;
    int wext = g % KF3;
    int j = g / KF3;
    int blk = wext / 384;
    int w = wext - blk * 384;
    float c = 0.f, s = 0.f;
    if (w <= 360 && j <= 360) {
        int idx = (j * w) % Ww;
        float a = (TWO_PI / Ww) * (float)idx;
        float sv, cv;
        sincosf(a, &sv, &cv);
        c = SCALE * cv;
        s = -SCALE * sv;
    }
    bf16 chi = __float2bfloat16(c);
    bf16 shi = __float2bfloat16(s);
    if (blk == 2) {
        Bc[g] = __float2bfloat16(c - __bfloat162float(chi));
        Bs[g] = __float2bfloat16(s - __bfloat162float(shi));
    } else {
        Bc[g] = chi;
        Bs[g] = shi;
    }
}

__global__ __launch_bounds__(256) void build_binv_kernel(bf16* __restrict__ Bi) {
    int g = blockIdx.x * 256 + threadIdx.x;
    if (g >= NI * KI) return;
    int k = g % KI, n = g / KI;
    float v = 0.f;
    if (n < NSTORE_INV) {
        if (k <= 360) {
            int j = k;
            float f = (j == 0 || j == 360) ? 1.f : 2.f;
            int idx = (j * n) % Ww;
            v = SCALE * f * cosf((TWO_PI / Ww) * (float)idx);
        } else if (k >= 384 && k <= 744) {
            int j = k - 384;
            int idx = (j * n) % Ww;
            v = -2.f * SCALE * sinf((TWO_PI / Ww) * (float)idx);
        }
    }
    Bi[g] = __float2bfloat16(v);
}

// W fragment-packed: s16x8 index = fid*64 + lane, fid = ((n16*4 + kb)*2 + kh).
__global__ __launch_bounds__(256) void build_wf_kernel(
    const float* __restrict__ w1_r, const float* __restrict__ w1_i,
    const float* __restrict__ w2_r, const float* __restrict__ w2_i,
    bf16* __restrict__ W1f, bf16* __restrict__ W2f)
{
    int g = blockIdx.x * 256 + threadIdx.x;
    if (g >= 2 * 32768) return;
    int which = g >> 15;
    int gg = g & 32767;
    int e = gg & 7, lane = (gg >> 3) & 63, kh = (gg >> 9) & 1;
    int kb = (gg >> 10) & 3, n16 = (gg >> 12) & 7;
    int frow = lane & 15, fcol = (lane >> 4) * 8;
    int n = n16 * 16 + frow;
    int kfull = kb * 64 + kh * 32 + fcol + e;
    int kk = kfull & 127, islo = kfull >> 7;
    const float* wr = which ? w2_r : w1_r;
    const float* wi = which ? w2_i : w1_i;
    float v;
    if (n < 64) v = (kk < 64) ? wr[n * 64 + kk] : -wi[n * 64 + kk - 64];
    else { int p = n - 64; v = (kk < 64) ? wi[p * 64 + kk] : wr[p * 64 + kk - 64]; }
    bf16 h = __float2bfloat16(v);
    bf16 out = islo ? __float2bfloat16(v - __bfloat162float(h)) : h;
    (which ? W2f : W1f)[gg] = out;
}

// ------------- row starts (compact + 8-padded), parallel prefix scan
__global__ __launch_bounds__(512) void row_starts_kernel(const int* __restrict__ rows,
                                                         int T, int* __restrict__ rs,
                                                         int* __restrict__ rs8) {
    __shared__ int scan[512];
    const int h = threadIdx.x;
    if (h <= Hh) {
        if (h == Hh) rs[Hh] = T;
        else {
            int lo = 0, hi = T;
            while (lo < hi) {
                int mid = (lo + hi) >> 1;
                if (rows[mid] < h) lo = mid + 1; else hi = mid;
            }
            rs[h] = lo;
        }
    }
    __syncthreads();
    int c8 = 0;
    if (h < Hh) c8 = ((rs[h + 1] - rs[h]) + 7) & ~7;
    scan[h] = c8;
    __syncthreads();
    for (int off = 1; off < 512; off <<= 1) {
        int add = (h >= off) ? scan[h - off] : 0;
        __syncthreads();
        scan[h] += add;
        __syncthreads();
    }
    if (h < Hh) rs8[h] = scan[h] - c8;       // exclusive
    if (h == Hh) rs8[Hh] = scan[Hh - 1];     // total
}

// ---------- pack x chunk -> A [hi|lo], h-major rows; one thread per (row,w4)
__global__ __launch_bounds__(256) void pack_kernel(const float* __restrict__ x,
                                                   bf16* __restrict__ Ap,
                                                   bf16* __restrict__ Aq,
                                                   int hbase) {
    int g = blockIdx.x * 256 + threadIdx.x;
    if (g >= CM * 96) return;
    int w4 = g % 96;
    int r = g / 96;
    int hl = r >> 7;
    int bc = r & 127;
    const float* xrow = x + ((size_t)bc * Hh + hbase + hl) * Ww;
    const int wb = w4 * 4;
    float4 fw = *(const float4*)&xrow[wb];
    float fwv[4] = {fw.x, fw.y, fw.z, fw.w};
    short ph[4], qh[4], pl[4], ql[4];
#pragma unroll
    for (int e = 0; e < 4; ++e) {
        int w = wb + e;
        float p = 0.f, q = 0.f;
        if (w == 0 || w == 360) {
            p = fwv[e];
        } else if (w < 360) {
            float a = fwv[e];
            float b = xrow[Ww - w];
            p = a + b;
            q = a - b;
        }
        short phe = f2bfs(p);
        short qhe = f2bfs(q);
        ph[e] = phe; qh[e] = qhe;
        pl[e] = f2bfs(p - bfs2f(phe));
        ql[e] = f2bfs(q - bfs2f(qhe));
    }
    size_t base = (size_t)r * KA + wb;
    *(short4*)&Ap[base]       = make_short4(ph[0], ph[1], ph[2], ph[3]);
    *(short4*)&Aq[base]       = make_short4(qh[0], qh[1], qh[2], qh[3]);
    *(short4*)&Ap[base + 384] = make_short4(pl[0], pl[1], pl[2], pl[3]);
    *(short4*)&Aq[base + 384] = make_short4(ql[0], ql[1], ql[2], ql[3]);
}

// --------- pad-only zero of Xg: rows [cnt, cnt8) per (bc,h) (<= 7 elems)
__global__ __launch_bounds__(256) void pad_zero_kernel(
    bf16* __restrict__ Xgr, bf16* __restrict__ Xgi,
    const int* __restrict__ rs, const int* __restrict__ rs8, int T8cap)
{
    const int h = blockIdx.x;
    const int cnt = rs[h + 1] - rs[h];
    const int t0 = rs8[h];
    const int cnt8 = rs8[h + 1] - t0;
    const int pad = cnt8 - cnt;
    if (pad <= 0) return;
    for (int idx = threadIdx.x; idx < BC * 8; idx += 256) {
        int bc = idx >> 3;
        int e = idx & 7;
        if (e < pad) {
            size_t off = (size_t)bc * T8cap + t0 + cnt + e;
            Xgr[off] = __float2bfloat16(0.f);
            Xgi[off] = __float2bfloat16(0.f);
        }
    }
}

// ------------------- fwd MFMA GEMM, h-uniform tiles + early exit + compact C
__global__ __launch_bounds__(256) void gemm_fwd_compact_kernel(
    const bf16* __restrict__ Ap, const bf16* __restrict__ Aq,
    const bf16* __restrict__ Bc, const bf16* __restrict__ Bsm,
    float* __restrict__ Xcr, float* __restrict__ Xci,
    const int* __restrict__ rs, int T128, int hbase)
{
    __shared__ __align__(128) bf16 As[128][64];
    __shared__ __align__(128) bf16 Bs[128][64];
    const int h = hbase + blockIdx.x;       // one latitude per m-tile
    const int t0 = rs[h];
    const int cnt = rs[h + 1] - t0;
    const int n0 = blockIdx.y * 128;
    if (n0 >= cnt) return;                   // tile stores nothing: dead work
    const bf16* A  = blockIdx.z ? Aq : Ap;
    const bf16* Bt = blockIdx.z ? Bsm : Bc;
    float* Xc      = blockIdx.z ? Xci : Xcr;
    const int tid = threadIdx.x;
    const int lane = tid & 63;
    const int wave = tid >> 6;
    const int m0 = blockIdx.x * 128;
    const int wr = (wave >> 1) * 64;
    const int wc = (wave & 1) * 64;
    const int srow = tid >> 3;
    const int scol = (tid & 7) << 3;
    f32x4 acc[4][4] = {};
    for (int k0 = 0; k0 < KF3; k0 += 64) {
        const int ka0 = (k0 >= 768) ? (k0 - 768) : k0;
#pragma unroll
        for (int i = 0; i < 4; ++i) {
            const bf16* ga = A  + (size_t)(m0 + i * 32 + srow) * KA + ka0 + scol;
            const bf16* gb = Bt + (size_t)(n0 + i * 32 + srow) * KF3 + k0 + scol;
            gload_lds16(ga, ((char*)&As[0][0]) + (size_t)(i * 256 + tid) * 16);
            gload_lds16(gb, ((char*)&Bs[0][0]) + (size_t)(i * 256 + tid) * 16);
        }
        __syncthreads();
#pragma unroll
        for (int kk = 0; kk < 64; kk += 32) {
            s16x8 a[4], b[4];
#pragma unroll
            for (int m = 0; m < 4; ++m)
                a[m] = *(const s16x8*)&As[wr + m * 16 + (lane & 15)][kk + (lane >> 4) * 8];
#pragma unroll
            for (int n = 0; n < 4; ++n)
                b[n] = *(const s16x8*)&Bs[wc + n * 16 + (lane & 15)][kk + (lane >> 4) * 8];
#pragma unroll
            for (int m = 0; m < 4; ++m)
#pragma unroll
                for (int n = 0; n < 4; ++n)
                    acc[m][n] = __builtin_amdgcn_mfma_f32_16x16x32_bf16(a[m], b[n], acc[m][n], 0, 0, 0);
        }
        __syncthreads();
    }
    const int rbase = (lane >> 4) * 4;
    const int cidx = lane & 15;
#pragma unroll
    for (int m = 0; m < 4; ++m) {
#pragma unroll
        for (int r = 0; r < 4; ++r) {
            int bc = wr + m * 16 + rbase + r;   // local row within h-tile
#pragma unroll
            for (int n = 0; n < 4; ++n) {
                int j = n0 + wc + n * 16 + cidx;
                if (j < cnt)
                    Xc[(size_t)bc * T128 + t0 + j] = acc[m][n][r];
            }
        }
    }
}

// -------------- inverse GEMM, h-uniform tiles + K-tile early-skip; y h-major
// Full K-tiles (jb+64 <= cnt8) stage A via global_load_lds (no VGPR
// round-trip; LDS dest (i*256+tid)*16 == &As[i*32+srow][scol], values
// bit-identical). Boundary tile keeps the predicated register path.
__global__ __launch_bounds__(256) void gemm_inv_kernel(
    const bf16* __restrict__ Xgr, const bf16* __restrict__ Xgi,
    const bf16* __restrict__ Bt, const int* __restrict__ rs8,
    bf16* __restrict__ C, int T8cap)
{
    __shared__ __align__(128) bf16 As[128][64];
    __shared__ __align__(128) bf16 Bs[128][64];
    const int h = blockIdx.x;               // one latitude per m-tile
    const int t0v = rs8[h];
    const int cnt8 = rs8[h + 1] - t0v;
    const int n0 = blockIdx.y * 128;
    const int tid = threadIdx.x;
    const int lane = tid & 63;
    const int wave = tid >> 6;
    const int wr = (wave >> 1) * 64;
    const int wc = (wave & 1) * 64;
    const int srow = tid >> 3;
    const int scol = (tid & 7) << 3;
    f32x4 acc[4][4] = {};
    for (int k0 = 0; k0 < KI; k0 += 64) {
        const int jb = (k0 < 384) ? k0 : (k0 - 384);
        if (jb >= cnt8) continue;           // A-tile all zero: acc += 0, skip
        const bf16* base = (k0 < 384) ? Xgr : Xgi;
        const int j0 = jb + scol;
#pragma unroll
        for (int i = 0; i < 4; ++i)
            gload_lds16(Bt + (size_t)(n0 + i * 32 + srow) * KI + k0 + scol,
                        ((char*)&Bs[0][0]) + (size_t)(i * 256 + tid) * 16);
        if (jb + 64 <= cnt8) {
            // full tile: every lane in-range -> direct global->LDS
#pragma unroll
            for (int i = 0; i < 4; ++i)
                gload_lds16(base + (size_t)(i * 32 + srow) * T8cap + t0v + j0,
                            ((char*)&As[0][0]) + (size_t)(i * 256 + tid) * 16);
        } else {
#pragma unroll
            for (int i = 0; i < 4; ++i) {
                int bc = i * 32 + srow;
                s16x8 v = (s16x8){0, 0, 0, 0, 0, 0, 0, 0};
                if (j0 < cnt8)
                    v = *(const s16x8*)(base + (size_t)bc * T8cap + t0v + j0);
                *(s16x8*)&As[bc][scol] = v;
            }
        }
        __syncthreads();
#pragma unroll
        for (int kk = 0; kk < 64; kk += 32) {
            s16x8 a[4], b[4];
#pragma unroll
            for (int m = 0; m < 4; ++m)
                a[m] = *(const s16x8*)&As[wr + m * 16 + (lane & 15)][kk + (lane >> 4) * 8];
#pragma unroll
            for (int n = 0; n < 4; ++n)
                b[n] = *(const s16x8*)&Bs[wc + n * 16 + (lane & 15)][kk + (lane >> 4) * 8];
#pragma unroll
            for (int m = 0; m < 4; ++m)
#pragma unroll
                for (int n = 0; n < 4; ++n)
                    acc[m][n] = __builtin_amdgcn_mfma_f32_16x16x32_bf16(a[m], b[n], acc[m][n], 0, 0, 0);
        }
        __syncthreads();
    }
    const int rbase = (lane >> 4) * 4;
    const int cidx = lane & 15;
#pragma unroll
    for (int m = 0; m < 4; ++m) {
#pragma unroll
        for (int n = 0; n < 4; ++n) {
            int gcol = n0 + wc + n * 16 + cidx;
            if (gcol < NSTORE_INV) {
#pragma unroll
                for (int r = 0; r < 4; ++r) {
                    int bc = wr + m * 16 + rbase + r;
                    C[(size_t)(h * BC + bc) * NI + gcol] = __float2bfloat16(acc[m][n][r]);
                }
            }
        }
    }
}

// ------------------------------------------------ fused middle stage (v3)
// FROZEN: verbatim green r17 middle. Three independent edits (fastmath,
// register-cache, both) each broke correctness (r12/r18/r19) — do not touch.
__device__ __forceinline__ float gelu_exact(float v) {
    return 0.5f * v * (1.0f + erff(v * 0.7071067811865476f));
}

__global__ __launch_bounds__(256, 4) void middle_fused_kernel(
    const float* __restrict__ Xcr, const float* __restrict__ Xci,
    bf16* __restrict__ Xgr, bf16* __restrict__ Xgi,
    const float* __restrict__ mean_r, const float* __restrict__ mean_i,
    const float* __restrict__ stdv,
    const float* __restrict__ mags_r, const float* __restrict__ mags_i,
    const float* __restrict__ bias_r, const float* __restrict__ bias_i,
    const bf16* __restrict__ W1f, const bf16* __restrict__ W2f,
    const float* __restrict__ brelu_p,
    const float* __restrict__ glu_mags, const float* __restrict__ glu_phases,
    const int* __restrict__ rows, const int* __restrict__ cols,
    const int* __restrict__ rs8,
    int T, int T128, int T8cap)
{
    __shared__ __align__(16) char smemA[32 * 264 * 2];   // 16,896 B
    __shared__ __align__(16) char smemB[32 * 264 * 2];
    bf16*  H1 = (bf16*)smemA;    // [32][264] hi/lo split input
    float* aL = (float*)smemA;   // [32][132] GEMM1 result
    float* cL = (float*)smemA;   // [32][132] GEMM2 result
    bf16*  H2 = (bf16*)smemB;    // [32][264] gelu output

    const int tid = threadIdx.x;
    const int b = blockIdx.y;
    const int t0 = blockIdx.x * 32;
    const int tl = tid & 31;
    const int cg = tid >> 5;          // 0..7
    const int t = t0 + tl;
    const bool valid = (t < T);
    const int lane = tid & 63;
    const int wv = tid >> 6;          // 0..3
    const int frow = lane & 15;
    const int fcol = (lane >> 4) * 8;
    const s16x8* W1v = (const s16x8*)W1f;
    const s16x8* W2v = (const s16x8*)W2f;
    constexpr int ASRC[6] = {0, 1, 2, 3, 0, 1};
    constexpr int BSRC[6] = {0, 1, 0, 1, 2, 3};

    // ---- phase 1: normalize -> H1 (lane=t, coalesced global reads)
    {
        float mr = 0.f, mi_ = 0.f, isd = 0.f;
        if (valid) { mr = mean_r[t]; mi_ = mean_i[t]; isd = 1.0f / (1e-12f + stdv[t]); }
        s16x8 vhr, vhi, vlr, vli;
#pragma unroll
        for (int ci = 0; ci < 8; ++ci) {
            int c = cg * 8 + ci;
            float xr = 0.f, xi = 0.f;
            if (valid) {
                xr = Xcr[(size_t)(b * 64 + c) * T128 + t];
                xi = Xci[(size_t)(b * 64 + c) * T128 + t];
            }
            float hr = (xr - mr) * isd;
            float hi = (xi - mi_) * isd;
            float h1r = fmaf(hr, mags_r[c], fmaf(-hi, mags_i[c], bias_r[c]));
            float h1i = fmaf(hr, mags_i[c], fmaf(hi, mags_r[c], bias_i[c]));
            short rh = f2bfs(h1r), ih = f2bfs(h1i);
            vhr[ci] = rh; vhi[ci] = ih;
            vlr[ci] = f2bfs(h1r - bfs2f(rh));
            vli[ci] = f2bfs(h1i - bfs2f(ih));
        }
        *(s16x8*)&H1[tl * 264 + cg * 8]       = vhr;
        *(s16x8*)&H1[tl * 264 + 64 + cg * 8]  = vhi;
        *(s16x8*)&H1[tl * 264 + 128 + cg * 8] = vlr;
        *(s16x8*)&H1[tl * 264 + 192 + cg * 8] = vli;
    }
    __syncthreads();

    // ---- GEMM1: A = H1 [32][264], B frags direct from W1f (L2)
    f32x4 acc[2][2] = {};
#pragma unroll
    for (int lc = 0; lc < 6; ++lc) {
        const int ka = ASRC[lc] * 64;
        const int kb = BSRC[lc];
#pragma unroll
        for (int kh = 0; kh < 2; ++kh) {
            s16x8 a0 = *(const s16x8*)&H1[frow * 264 + ka + kh * 32 + fcol];
            s16x8 a1 = *(const s16x8*)&H1[(16 + frow) * 264 + ka + kh * 32 + fcol];
#pragma unroll
            for (int n = 0; n < 2; ++n) {
                s16x8 bfv = W1v[(size_t)((((wv * 2 + n) * 4 + kb) * 2 + kh) * 64 + lane)];
                acc[0][n] = __builtin_amdgcn_mfma_f32_16x16x32_bf16(a0, bfv, acc[0][n], 0, 0, 0);
                acc[1][n] = __builtin_amdgcn_mfma_f32_16x16x32_bf16(a1, bfv, acc[1][n], 0, 0, 0);
            }
        }
    }
    __syncthreads();

    // ---- phase 3: acc -> aL (overwrites H1)
    const int rbase = (lane >> 4) * 4;
    const int cidx = lane & 15;
#pragma unroll
    for (int m = 0; m < 2; ++m)
#pragma unroll
        for (int n = 0; n < 2; ++n)
#pragma unroll
            for (int r = 0; r < 4; ++r)
                aL[(m * 16 + rbase + r) * 132 + wv * 32 + n * 16 + cidx] = acc[m][n][r];
    __syncthreads();

    // ---- phase 4: gelu (lane=t) -> H2
    {
        const float brelu = brelu_p[0];
        f32x4 ar0 = *(const f32x4*)&aL[tl * 132 + cg * 8];
        f32x4 ar1 = *(const f32x4*)&aL[tl * 132 + cg * 8 + 4];
        f32x4 ai0 = *(const f32x4*)&aL[tl * 132 + 64 + cg * 8];
        f32x4 ai1 = *(const f32x4*)&aL[tl * 132 + 64 + cg * 8 + 4];
        s16x8 vhr, vhi, vlr, vli;
#pragma unroll
        for (int ci = 0; ci < 8; ++ci) {
            float ar = (ci < 4) ? ar0[ci & 3] : ar1[ci & 3];
            float ai = (ci < 4) ? ai0[ci & 3] : ai1[ci & 3];
            float r = sqrtf(ar * ar + ai * ai);
            float g = gelu_exact(r + brelu);
            float h2r, h2i;
            if (r > 0.f) { float f = g / r; h2r = f * ar; h2i = f * ai; }
            else { h2r = g; h2i = 0.f; }
            short rh = f2bfs(h2r), ih = f2bfs(h2i);
            vhr[ci] = rh; vhi[ci] = ih;
            vlr[ci] = f2bfs(h2r - bfs2f(rh));
            vli[ci] = f2bfs(h2i - bfs2f(ih));
        }
        *(s16x8*)&H2[tl * 264 + cg * 8]       = vhr;
        *(s16x8*)&H2[tl * 264 + 64 + cg * 8]  = vhi;
        *(s16x8*)&H2[tl * 264 + 128 + cg * 8] = vlr;
        *(s16x8*)&H2[tl * 264 + 192 + cg * 8] = vli;
    }
    __syncthreads();

    // ---- GEMM2: A = H2, B frags from W2f
    f32x4 acc2[2][2] = {};
#pragma unroll
    for (int lc = 0; lc < 6; ++lc) {
        const int ka = ASRC[lc] * 64;
        const int kb = BSRC[lc];
#pragma unroll
        for (int kh = 0; kh < 2; ++kh) {
            s16x8 a0 = *(const s16x8*)&H2[frow * 264 + ka + kh * 32 + fcol];
            s16x8 a1 = *(const s16x8*)&H2[(16 + frow) * 264 + ka + kh * 32 + fcol];
#pragma unroll
            for (int n = 0; n < 2; ++n) {
                s16x8 bfv = W2v[(size_t)((((wv * 2 + n) * 4 + kb) * 2 + kh) * 64 + lane)];
                acc2[0][n] = __builtin_amdgcn_mfma_f32_16x16x32_bf16(a0, bfv, acc2[0][n], 0, 0, 0);
                acc2[1][n] = __builtin_amdgcn_mfma_f32_16x16x32_bf16(a1, bfv, acc2[1][n], 0, 0, 0);
            }
        }
    }
    // cL aliases aL (smemA): all aL reads completed before the barrier above
    // GEMM2; no thread reads smemA during GEMM2.
#pragma unroll
    for (int m = 0; m < 2; ++m)
#pragma unroll
        for (int n = 0; n < 2; ++n)
#pragma unroll
            for (int r = 0; r < 4; ++r)
                cL[(m * 16 + rbase + r) * 132 + wv * 32 + n * 16 + cidx] = acc2[m][n][r];
    __syncthreads();

    // ---- phase 8: gate + compact coalesced store (lane=t)
    if (valid) {
        int h = rows[t], j = cols[t];
        size_t wbase = (size_t)rs8[h] + j;
        f32x4 cr0 = *(const f32x4*)&cL[tl * 132 + cg * 8];
        f32x4 cr1 = *(const f32x4*)&cL[tl * 132 + cg * 8 + 4];
        f32x4 ci0 = *(const f32x4*)&cL[tl * 132 + 64 + cg * 8];
        f32x4 ci1 = *(const f32x4*)&cL[tl * 132 + 64 + cg * 8 + 4];
#pragma unroll
        for (int ci = 0; ci < 8; ++ci) {
            int c = cg * 8 + ci;
            float cr  = (ci < 4) ? cr0[ci & 3] : cr1[ci & 3];
            float cii = (ci < 4) ? ci0[ci & 3] : ci1[ci & 3];
            float xr = Xcr[(size_t)(b * 64 + c) * T128 + t];
            float xi = Xci[(size_t)(b * 64 + c) * T128 + t];
            float r3 = sqrtf(cr * cr + cii * cii);
            float gm = glu_mags[(size_t)c * T + t];
            float gp = glu_phases[(size_t)c * T + t];
            float sg = 1.0f / (1.0f + expf(-(r3 + gm)));
            float ux, uy;
            if (r3 > 0.f) { float ir3 = 1.0f / r3; ux = cr * ir3; uy = cii * ir3; }
            else { ux = 1.f; uy = 0.f; }
            float sp, cp;
            sincosf(gp, &sp, &cp);
            float gx = sg * (ux * cp - uy * sp);
            float gy = sg * (ux * sp + uy * cp);
            size_t base = (size_t)(b * 64 + c) * T8cap + wbase;
            Xgr[base] = __float2bfloat16(xr * gx - xi * gy);
            Xgi[base] = __float2bfloat16(xr * gy + xi * gx);
        }
    }
}

// ------- depthwise conv + add (bf16 y, h-major rows, 8-wide, XCD swizzle)
__global__ __launch_bounds__(256) void conv_add_kernel(
    const bf16* __restrict__ y, const float* __restrict__ dw,
    float* __restrict__ out)
{
    const int nb = gridDim.x;
    const int chunk = nb >> 3;
    const int orig = blockIdx.x;
    const int swz = (orig & 7) * chunk + (orig >> 3);   // bijective: nb % 8 == 0
    int g = swz * 256 + threadIdx.x;
    int w8 = g % 90;
    int rem = g / 90;
    int h = rem % Hh;
    int bc = rem / Hh;
    int c = bc & (Cc - 1);
    int w = w8 * 8;
    int walt = (w >= Ww / 2) ? (w - Ww / 2) : (w + Ww / 2);
    float acc[8];
    {
        s16x8 v0 = *(const s16x8*)&y[((size_t)h * BC + bc) * NI + w];
#pragma unroll
        for (int e = 0; e < 8; ++e) acc[e] = bfs2f(v0[e]);
    }
#pragma unroll
    for (int k = 0; k < 11; ++k) {
        int hp = h + k - 5;
        int hh, ww;
        if (hp < 0)        { hh = -1 - hp;         ww = walt; }
        else if (hp >= Hh) { hh = 2 * Hh - 1 - hp; ww = walt; }
        else               { hh = hp;              ww = w; }
        s16x8 v = *(const s16x8*)&y[((size_t)hh * BC + bc) * NI + ww];
        float dwk = dw[c * 11 + k];
#pragma unroll
        for (int e = 0; e < 8; ++e)
            acc[e] = fmaf(dwk, bfs2f(v[e]), acc[e]);
    }
    float* ob = &out[((size_t)bc * Hh + h) * Ww + w];
    *(float4*)&ob[0] = make_float4(acc[0], acc[1], acc[2], acc[3]);
    *(float4*)&ob[4] = make_float4(acc[4], acc[5], acc[6], acc[7]);
}

// ------------------------------------------------------------------ launch
extern "C" void kernel_launch(void* const* d_in, const int* in_sizes, int n_in,
                              void* d_out, int out_size, void* d_ws, size_t ws_size,
                              hipStream_t stream)
{
    const float* x      = (const float*)d_in[0];
    const float* mean_r = (const float*)d_in[1];
    const float* mean_i = (const float*)d_in[2];
    const float* stdv   = (const float*)d_in[3];
    const float* mags_r = (const float*)d_in[4];
    const float* mags_i = (const float*)d_in[5];
    const float* bias_r = (const float*)d_in[6];
    const float* bias_i = (const float*)d_in[7];
    const float* w1_r   = (const float*)d_in[8];
    const float* w1_i   = (const float*)d_in[9];
    const float* brelu  = (const float*)d_in[10];
    const float* w2_r   = (const float*)d_in[11];
    const float* w2_i   = (const float*)d_in[12];
    const float* glu_m  = (const float*)d_in[13];
    const float* glu_p  = (const float*)d_in[14];
    const float* dw     = (const float*)d_in[15];
    const int*   rows   = (const int*)d_in[16];
    const int*   cols   = (const int*)d_in[17];
    const int T = in_sizes[16];
    const int T128 = ((T + 127) / 128) * 128;
    const int T8cap = ((T + 7 * Hh) + 127) & ~127;

    char* ws = (char*)d_ws;
    const size_t SApc  = (size_t)CM * KA * 2;             // 35,389,440
    const size_t XC_SZ = (size_t)BC * T128 * 4;           // ~42.7 MB
    const size_t XG_SZ = (size_t)BC * T8cap * 2;          // ~22.0 MB
    bf16*  Ap  = (bf16*)ws;
    bf16*  Aq  = (bf16*)(ws + SApc);
    float* Xcr = (float*)(ws + 2 * SApc);
    float* Xci = (float*)(ws + 2 * SApc + XC_SZ);
    bf16*  Xgr = (bf16*)ws;
    bf16*  Xgi = (bf16*)(ws + XG_SZ);
    bf16*  y   = (bf16*)(ws + 2 * XG_SZ);
    size_t boff = 2 * SApc + 2 * XC_SZ;                   // ~156.1 MB
    bf16*  Bce = (bf16*)(ws + boff);
    bf16*  Bse = (bf16*)(ws + boff + (size_t)NF * KF3 * 2);
    bf16*  Bti = (bf16*)(ws + boff + 2 * (size_t)NF * KF3 * 2);
    bf16*  W1f = (bf16*)(ws + boff + 2 * (size_t)NF * KF3 * 2 + (size_t)NI * KI * 2);
    bf16*  W2f = W1f + 32768;
    int*   rs  = (int*)(W2f + 32768);
    int*   rs8 = rs + (Hh + 2);

    build_bfwd_kernel<<<(NF * KF3 + 255) / 256, 256, 0, stream>>>(Bce, Bse);
    build_binv_kernel<<<(NI * KI + 255) / 256, 256, 0, stream>>>(Bti);
    build_wf_kernel<<<(2 * 32768 + 255) / 256, 256, 0, stream>>>(
        w1_r, w1_i, w2_r, w2_i, W1f, W2f);
    row_starts_kernel<<<1, 512, 0, stream>>>(rows, T, rs, rs8);

    for (int ch = 0; ch < CHUNKS; ++ch) {
        pack_kernel<<<(CM * 96 + 255) / 256, 256, 0, stream>>>(
            x, Ap, Aq, ch * HPC);
        gemm_fwd_compact_kernel<<<dim3(CM / 128, NF / 128, 2), 256, 0, stream>>>(
            Ap, Aq, Bce, Bse, Xcr, Xci, rs, T128, ch * HPC);
    }

    pad_zero_kernel<<<Hh, 256, 0, stream>>>(Xgr, Xgi, rs, rs8, T8cap);

    const int nT32 = (T + 31) / 32;
    middle_fused_kernel<<<dim3(nT32, Bb), 256, 0, stream>>>(
        Xcr, Xci, Xgr, Xgi, mean_r, mean_i, stdv, mags_r, mags_i,
        bias_r, bias_i, W1f, W2f, brelu, glu_m, glu_p, rows, cols, rs8,
        T, T128, T8cap);

    gemm_inv_kernel<<<dim3(Hh, NI / 128), 256, 0, stream>>>(
        Xgr, Xgi, Bti, rs8, y, T8cap);

    conv_add_kernel<<<(Bb * Cc * Hh * 90) / 256, 256, 0, stream>>>(y, dw, (float*)d_out);
}

// Round 26
// 439.656 us; speedup vs baseline: 1.3221x; 1.0130x over previous
//
#include <hip/hip_runtime.h>
#include <hip/hip_bf16.h>
#include <math.h>

#define Hh 360
#define Ww 720
#define Cc 64
#define Bb 2
#define BC (Bb*Cc)        // 128
#define Mrows (BC*Hh)     // 46080
#define CHUNKS 2
#define CM (Mrows/CHUNKS) // 23040
#define HPC (Hh/CHUNKS)   // 180 latitudes per chunk
#define KA 768            // A row: [hi(384) | lo(384)]
#define KF3 1152          // GEMM K loop: [hi.Bhi | lo.Bhi | hi.Blo]
#define NF 384            // fwd N (361 bins padded)
#define KI 768            // inv K: [Re(384) | Im(384)]
#define NI 768            // inv C row stride (720 used)
#define NSTORE_INV 720
#define SCALE 0.037267799624996496f   // 1/sqrt(720)
#define TWO_PI 6.2831853071795864769f

typedef __attribute__((ext_vector_type(8))) short s16x8;
typedef __attribute__((ext_vector_type(4))) float f32x4;
typedef __hip_bfloat16 bf16;

__device__ __forceinline__ void gload_lds16(const void* g, void* l) {
    __builtin_amdgcn_global_load_lds(
        (const __attribute__((address_space(1))) unsigned int*)g,
        (__attribute__((address_space(3))) unsigned int*)l, 16, 0, 0);
}
__device__ __forceinline__ short f2bfs(float v) {
    bf16 h = __float2bfloat16(v); short s; __builtin_memcpy(&s, &h, 2); return s;
}
__device__ __forceinline__ float bfs2f(short s) {
    bf16 h; __builtin_memcpy(&h, &s, 2); return __bfloat162float(h);
}

// ---------------------------------------------------------- B-matrix builds
// B stays 1152-wide: [Bhi | Bhi | Blo].
__global__ __launch_bounds__(256) void build_bfwd_kernel(bf16* __restrict__ Bc,
                                                         bf16* __restrict__ Bs) {
    int g = blockIdx.x * 256 + threadIdx.x;
    if (g >= NF * KF3) return;
    int wext = g % KF3;
    int j = g / KF3;
    int blk = wext / 384;
    int w = wext - blk * 384;
    float c = 0.f, s = 0.f;
    if (w <= 360 && j <= 360) {
        int idx = (j * w) % Ww;
        float a = (TWO_PI / Ww) * (float)idx;
        float sv, cv;
        sincosf(a, &sv, &cv);
        c = SCALE * cv;
        s = -SCALE * sv;
    }
    bf16 chi = __float2bfloat16(c);
    bf16 shi = __float2bfloat16(s);
    if (blk == 2) {
        Bc[g] = __float2bfloat16(c - __bfloat162float(chi));
        Bs[g] = __float2bfloat16(s - __bfloat162float(shi));
    } else {
        Bc[g] = chi;
        Bs[g] = shi;
    }
}

__global__ __launch_bounds__(256) void build_binv_kernel(bf16* __restrict__ Bi) {
    int g = blockIdx.x * 256 + threadIdx.x;
    if (g >= NI * KI) return;
    int k = g % KI, n = g / KI;
    float v = 0.f;
    if (n < NSTORE_INV) {
        if (k <= 360) {
            int j = k;
            float f = (j == 0 || j == 360) ? 1.f : 2.f;
            int idx = (j * n) % Ww;
            v = SCALE * f * cosf((TWO_PI / Ww) * (float)idx);
        } else if (k >= 384 && k <= 744) {
            int j = k - 384;
            int idx = (j * n) % Ww;
            v = -2.f * SCALE * sinf((TWO_PI / Ww) * (float)idx);
        }
    }
    Bi[g] = __float2bfloat16(v);
}

// W fragment-packed: s16x8 index = fid*64 + lane, fid = ((n16*4 + kb)*2 + kh).
__global__ __launch_bounds__(256) void build_wf_kernel(
    const float* __restrict__ w1_r, const float* __restrict__ w1_i,
    const float* __restrict__ w2_r, const float* __restrict__ w2_i,
    bf16* __restrict__ W1f, bf16* __restrict__ W2f)
{
    int g = blockIdx.x * 256 + threadIdx.x;
    if (g >= 2 * 32768) return;
    int which = g >> 15;
    int gg = g & 32767;
    int e = gg & 7, lane = (gg >> 3) & 63, kh = (gg >> 9) & 1;
    int kb = (gg >> 10) & 3, n16 = (gg >> 12) & 7;
    int frow = lane & 15, fcol = (lane >> 4) * 8;
    int n = n16 * 16 + frow;
    int kfull = kb * 64 + kh * 32 + fcol + e;
    int kk = kfull & 127, islo = kfull >> 7;
    const float* wr = which ? w2_r : w1_r;
    const float* wi = which ? w2_i : w1_i;
    float v;
    if (n < 64) v = (kk < 64) ? wr[n * 64 + kk] : -wi[n * 64 + kk - 64];
    else { int p = n - 64; v = (kk < 64) ? wi[p * 64 + kk] : wr[p * 64 + kk - 64]; }
    bf16 h = __float2bfloat16(v);
    bf16 out = islo ? __float2bfloat16(v - __bfloat162float(h)) : h;
    (which ? W2f : W1f)[gg] = out;
}

// ------------- row starts (compact + 8-padded), parallel prefix scan
__global__ __launch_bounds__(512) void row_starts_kernel(const int* __restrict__ rows,
                                                         int T, int* __restrict__ rs,
                                                         int* __restrict__ rs8) {
    __shared__ int scan[512];
    const int h = threadIdx.x;
    if (h <= Hh) {
        if (h == Hh) rs[Hh] = T;
        else {
            int lo = 0, hi = T;
            while (lo < hi) {
                int mid = (lo + hi) >> 1;
                if (rows[mid] < h) lo = mid + 1; else hi = mid;
            }
            rs[h] = lo;
        }
    }
    __syncthreads();
    int c8 = 0;
    if (h < Hh) c8 = ((rs[h + 1] - rs[h]) + 7) & ~7;
    scan[h] = c8;
    __syncthreads();
    for (int off = 1; off < 512; off <<= 1) {
        int add = (h >= off) ? scan[h - off] : 0;
        __syncthreads();
        scan[h] += add;
        __syncthreads();
    }
    if (h < Hh) rs8[h] = scan[h] - c8;       // exclusive
    if (h == Hh) rs8[Hh] = scan[Hh - 1];     // total
}

// ---------- pack x chunk -> A [hi|lo], h-major rows; one thread per (row,w4)
__global__ __launch_bounds__(256) void pack_kernel(const float* __restrict__ x,
                                                   bf16* __restrict__ Ap,
                                                   bf16* __restrict__ Aq,
                                                   int hbase) {
    int g = blockIdx.x * 256 + threadIdx.x;
    if (g >= CM * 96) return;
    int w4 = g % 96;
    int r = g / 96;
    int hl = r >> 7;
    int bc = r & 127;
    const float* xrow = x + ((size_t)bc * Hh + hbase + hl) * Ww;
    const int wb = w4 * 4;
    float4 fw = *(const float4*)&xrow[wb];
    float fwv[4] = {fw.x, fw.y, fw.z, fw.w};
    short ph[4], qh[4], pl[4], ql[4];
#pragma unroll
    for (int e = 0; e < 4; ++e) {
        int w = wb + e;
        float p = 0.f, q = 0.f;
        if (w == 0 || w == 360) {
            p = fwv[e];
        } else if (w < 360) {
            float a = fwv[e];
            float b = xrow[Ww - w];
            p = a + b;
            q = a - b;
        }
        short phe = f2bfs(p);
        short qhe = f2bfs(q);
        ph[e] = phe; qh[e] = qhe;
        pl[e] = f2bfs(p - bfs2f(phe));
        ql[e] = f2bfs(q - bfs2f(qhe));
    }
    size_t base = (size_t)r * KA + wb;
    *(short4*)&Ap[base]       = make_short4(ph[0], ph[1], ph[2], ph[3]);
    *(short4*)&Aq[base]       = make_short4(qh[0], qh[1], qh[2], qh[3]);
    *(short4*)&Ap[base + 384] = make_short4(pl[0], pl[1], pl[2], pl[3]);
    *(short4*)&Aq[base + 384] = make_short4(ql[0], ql[1], ql[2], ql[3]);
}

// --------- pad-only zero of Xg: rows [cnt, cnt8) per (bc,h) (<= 7 elems)
__global__ __launch_bounds__(256) void pad_zero_kernel(
    bf16* __restrict__ Xgr, bf16* __restrict__ Xgi,
    const int* __restrict__ rs, const int* __restrict__ rs8, int T8cap)
{
    const int h = blockIdx.x;
    const int cnt = rs[h + 1] - rs[h];
    const int t0 = rs8[h];
    const int cnt8 = rs8[h + 1] - t0;
    const int pad = cnt8 - cnt;
    if (pad <= 0) return;
    for (int idx = threadIdx.x; idx < BC * 8; idx += 256) {
        int bc = idx >> 3;
        int e = idx & 7;
        if (e < pad) {
            size_t off = (size_t)bc * T8cap + t0 + cnt + e;
            Xgr[off] = __float2bfloat16(0.f);
            Xgi[off] = __float2bfloat16(0.f);
        }
    }
}

// ---- fwd MFMA GEMM, h-uniform 64-row half-tiles (m-split) + early exit
// grid (HPC, 6, 2): y = n*2 + mhalf, z = p/q. Each block computes a 64x128
// output half-tile; per-element dot products identical K-order -> bit-identical.
__global__ __launch_bounds__(256) void gemm_fwd_compact_kernel(
    const bf16* __restrict__ Ap, const bf16* __restrict__ Aq,
    const bf16* __restrict__ Bc, const bf16* __restrict__ Bsm,
    float* __restrict__ Xcr, float* __restrict__ Xci,
    const int* __restrict__ rs, int T128, int hbase)
{
    __shared__ __align__(128) bf16 As[64][64];
    __shared__ __align__(128) bf16 Bs[128][64];
    const int h = hbase + blockIdx.x;       // one latitude per m-tile
    const int t0 = rs[h];
    const int cnt = rs[h + 1] - t0;
    const int n0 = (blockIdx.y >> 1) * 128;
    if (n0 >= cnt) return;                   // tile stores nothing: dead work
    const int mhalf = blockIdx.y & 1;
    const bf16* A  = blockIdx.z ? Aq : Ap;
    const bf16* Bt = blockIdx.z ? Bsm : Bc;
    float* Xc      = blockIdx.z ? Xci : Xcr;
    const int tid = threadIdx.x;
    const int lane = tid & 63;
    const int wave = tid >> 6;
    const int m0 = blockIdx.x * 128 + mhalf * 64;  // global A row base
    const int wr = (wave >> 1) * 32;        // wave covers 32 rows x 64 cols
    const int wc = (wave & 1) * 64;
    const int srow = tid >> 3;
    const int scol = (tid & 7) << 3;
    f32x4 acc[2][4] = {};
    for (int k0 = 0; k0 < KF3; k0 += 64) {
        const int ka0 = (k0 >= 768) ? (k0 - 768) : k0;
#pragma unroll
        for (int i = 0; i < 2; ++i) {
            const bf16* ga = A + (size_t)(m0 + i * 32 + srow) * KA + ka0 + scol;
            gload_lds16(ga, ((char*)&As[0][0]) + (size_t)(i * 256 + tid) * 16);
        }
#pragma unroll
        for (int i = 0; i < 4; ++i) {
            const bf16* gb = Bt + (size_t)(n0 + i * 32 + srow) * KF3 + k0 + scol;
            gload_lds16(gb, ((char*)&Bs[0][0]) + (size_t)(i * 256 + tid) * 16);
        }
        __syncthreads();
#pragma unroll
        for (int kk = 0; kk < 64; kk += 32) {
            s16x8 a[2], b[4];
#pragma unroll
            for (int m = 0; m < 2; ++m)
                a[m] = *(const s16x8*)&As[wr + m * 16 + (lane & 15)][kk + (lane >> 4) * 8];
#pragma unroll
            for (int n = 0; n < 4; ++n)
                b[n] = *(const s16x8*)&Bs[wc + n * 16 + (lane & 15)][kk + (lane >> 4) * 8];
#pragma unroll
            for (int m = 0; m < 2; ++m)
#pragma unroll
                for (int n = 0; n < 4; ++n)
                    acc[m][n] = __builtin_amdgcn_mfma_f32_16x16x32_bf16(a[m], b[n], acc[m][n], 0, 0, 0);
        }
        __syncthreads();
    }
    const int rbase = (lane >> 4) * 4;
    const int cidx = lane & 15;
#pragma unroll
    for (int m = 0; m < 2; ++m) {
#pragma unroll
        for (int r = 0; r < 4; ++r) {
            int bc = mhalf * 64 + wr + m * 16 + rbase + r;  // row within h-tile
#pragma unroll
            for (int n = 0; n < 4; ++n) {
                int j = n0 + wc + n * 16 + cidx;
                if (j < cnt)
                    Xc[(size_t)bc * T128 + t0 + j] = acc[m][n][r];
            }
        }
    }
}

// -------------- inverse GEMM, h-uniform tiles + K-tile early-skip; y h-major
// Full K-tiles (jb+64 <= cnt8) stage A via global_load_lds; boundary tile
// keeps the predicated register path. Bit-identical values.
__global__ __launch_bounds__(256) void gemm_inv_kernel(
    const bf16* __restrict__ Xgr, const bf16* __restrict__ Xgi,
    const bf16* __restrict__ Bt, const int* __restrict__ rs8,
    bf16* __restrict__ C, int T8cap)
{
    __shared__ __align__(128) bf16 As[128][64];
    __shared__ __align__(128) bf16 Bs[128][64];
    const int h = blockIdx.x;               // one latitude per m-tile
    const int t0v = rs8[h];
    const int cnt8 = rs8[h + 1] - t0v;
    const int n0 = blockIdx.y * 128;
    const int tid = threadIdx.x;
    const int lane = tid & 63;
    const int wave = tid >> 6;
    const int wr = (wave >> 1) * 64;
    const int wc = (wave & 1) * 64;
    const int srow = tid >> 3;
    const int scol = (tid & 7) << 3;
    f32x4 acc[4][4] = {};
    for (int k0 = 0; k0 < KI; k0 += 64) {
        const int jb = (k0 < 384) ? k0 : (k0 - 384);
        if (jb >= cnt8) continue;           // A-tile all zero: acc += 0, skip
        const bf16* base = (k0 < 384) ? Xgr : Xgi;
        const int j0 = jb + scol;
#pragma unroll
        for (int i = 0; i < 4; ++i)
            gload_lds16(Bt + (size_t)(n0 + i * 32 + srow) * KI + k0 + scol,
                        ((char*)&Bs[0][0]) + (size_t)(i * 256 + tid) * 16);
        if (jb + 64 <= cnt8) {
#pragma unroll
            for (int i = 0; i < 4; ++i)
                gload_lds16(base + (size_t)(i * 32 + srow) * T8cap + t0v + j0,
                            ((char*)&As[0][0]) + (size_t)(i * 256 + tid) * 16);
        } else {
#pragma unroll
            for (int i = 0; i < 4; ++i) {
                int bc = i * 32 + srow;
                s16x8 v = (s16x8){0, 0, 0, 0, 0, 0, 0, 0};
                if (j0 < cnt8)
                    v = *(const s16x8*)(base + (size_t)bc * T8cap + t0v + j0);
                *(s16x8*)&As[bc][scol] = v;
            }
        }
        __syncthreads();
#pragma unroll
        for (int kk = 0; kk < 64; kk += 32) {
            s16x8 a[4], b[4];
#pragma unroll
            for (int m = 0; m < 4; ++m)
                a[m] = *(const s16x8*)&As[wr + m * 16 + (lane & 15)][kk + (lane >> 4) * 8];
#pragma unroll
            for (int n = 0; n < 4; ++n)
                b[n] = *(const s16x8*)&Bs[wc + n * 16 + (lane & 15)][kk + (lane >> 4) * 8];
#pragma unroll
            for (int m = 0; m < 4; ++m)
#pragma unroll
                for (int n = 0; n < 4; ++n)
                    acc[m][n] = __builtin_amdgcn_mfma_f32_16x16x32_bf16(a[m], b[n], acc[m][n], 0, 0, 0);
        }
        __syncthreads();
    }
    const int rbase = (lane >> 4) * 4;
    const int cidx = lane & 15;
#pragma unroll
    for (int m = 0; m < 4; ++m) {
#pragma unroll
        for (int n = 0; n < 4; ++n) {
            int gcol = n0 + wc + n * 16 + cidx;
            if (gcol < NSTORE_INV) {
#pragma unroll
                for (int r = 0; r < 4; ++r) {
                    int bc = wr + m * 16 + rbase + r;
                    C[(size_t)(h * BC + bc) * NI + gcol] = __float2bfloat16(acc[m][n][r]);
                }
            }
        }
    }
}

// ------------------------------------------------ fused middle stage (v3)
// FROZEN: verbatim green r17 middle. Three independent edits (fastmath,
// register-cache, both) each broke correctness (r12/r18/r19) — do not touch.
__device__ __forceinline__ float gelu_exact(float v) {
    return 0.5f * v * (1.0f + erff(v * 0.7071067811865476f));
}

__global__ __launch_bounds__(256, 4) void middle_fused_kernel(
    const float* __restrict__ Xcr, const float* __restrict__ Xci,
    bf16* __restrict__ Xgr, bf16* __restrict__ Xgi,
    const float* __restrict__ mean_r, const float* __restrict__ mean_i,
    const float* __restrict__ stdv,
    const float* __restrict__ mags_r, const float* __restrict__ mags_i,
    const float* __restrict__ bias_r, const float* __restrict__ bias_i,
    const bf16* __restrict__ W1f, const bf16* __restrict__ W2f,
    const float* __restrict__ brelu_p,
    const float* __restrict__ glu_mags, const float* __restrict__ glu_phases,
    const int* __restrict__ rows, const int* __restrict__ cols,
    const int* __restrict__ rs8,
    int T, int T128, int T8cap)
{
    __shared__ __align__(16) char smemA[32 * 264 * 2];   // 16,896 B
    __shared__ __align__(16) char smemB[32 * 264 * 2];
    bf16*  H1 = (bf16*)smemA;    // [32][264] hi/lo split input
    float* aL = (float*)smemA;   // [32][132] GEMM1 result
    float* cL = (float*)smemA;   // [32][132] GEMM2 result
    bf16*  H2 = (bf16*)smemB;    // [32][264] gelu output

    const int tid = threadIdx.x;
    const int b = blockIdx.y;
    const int t0 = blockIdx.x * 32;
    const int tl = tid & 31;
    const int cg = tid >> 5;          // 0..7
    const int t = t0 + tl;
    const bool valid = (t < T);
    const int lane = tid & 63;
    const int wv = tid >> 6;          // 0..3
    const int frow = lane & 15;
    const int fcol = (lane >> 4) * 8;
    const s16x8* W1v = (const s16x8*)W1f;
    const s16x8* W2v = (const s16x8*)W2f;
    constexpr int ASRC[6] = {0, 1, 2, 3, 0, 1};
    constexpr int BSRC[6] = {0, 1, 0, 1, 2, 3};

    // ---- phase 1: normalize -> H1 (lane=t, coalesced global reads)
    {
        float mr = 0.f, mi_ = 0.f, isd = 0.f;
        if (valid) { mr = mean_r[t]; mi_ = mean_i[t]; isd = 1.0f / (1e-12f + stdv[t]); }
        s16x8 vhr, vhi, vlr, vli;
#pragma unroll
        for (int ci = 0; ci < 8; ++ci) {
            int c = cg * 8 + ci;
            float xr = 0.f, xi = 0.f;
            if (valid) {
                xr = Xcr[(size_t)(b * 64 + c) * T128 + t];
                xi = Xci[(size_t)(b * 64 + c) * T128 + t];
            }
            float hr = (xr - mr) * isd;
            float hi = (xi - mi_) * isd;
            float h1r = fmaf(hr, mags_r[c], fmaf(-hi, mags_i[c], bias_r[c]));
            float h1i = fmaf(hr, mags_i[c], fmaf(hi, mags_r[c], bias_i[c]));
            short rh = f2bfs(h1r), ih = f2bfs(h1i);
            vhr[ci] = rh; vhi[ci] = ih;
            vlr[ci] = f2bfs(h1r - bfs2f(rh));
            vli[ci] = f2bfs(h1i - bfs2f(ih));
        }
        *(s16x8*)&H1[tl * 264 + cg * 8]       = vhr;
        *(s16x8*)&H1[tl * 264 + 64 + cg * 8]  = vhi;
        *(s16x8*)&H1[tl * 264 + 128 + cg * 8] = vlr;
        *(s16x8*)&H1[tl * 264 + 192 + cg * 8] = vli;
    }
    __syncthreads();

    // ---- GEMM1: A = H1 [32][264], B frags direct from W1f (L2)
    f32x4 acc[2][2] = {};
#pragma unroll
    for (int lc = 0; lc < 6; ++lc) {
        const int ka = ASRC[lc] * 64;
        const int kb = BSRC[lc];
#pragma unroll
        for (int kh = 0; kh < 2; ++kh) {
            s16x8 a0 = *(const s16x8*)&H1[frow * 264 + ka + kh * 32 + fcol];
            s16x8 a1 = *(const s16x8*)&H1[(16 + frow) * 264 + ka + kh * 32 + fcol];
#pragma unroll
            for (int n = 0; n < 2; ++n) {
                s16x8 bfv = W1v[(size_t)((((wv * 2 + n) * 4 + kb) * 2 + kh) * 64 + lane)];
                acc[0][n] = __builtin_amdgcn_mfma_f32_16x16x32_bf16(a0, bfv, acc[0][n], 0, 0, 0);
                acc[1][n] = __builtin_amdgcn_mfma_f32_16x16x32_bf16(a1, bfv, acc[1][n], 0, 0, 0);
            }
        }
    }
    __syncthreads();

    // ---- phase 3: acc -> aL (overwrites H1)
    const int rbase = (lane >> 4) * 4;
    const int cidx = lane & 15;
#pragma unroll
    for (int m = 0; m < 2; ++m)
#pragma unroll
        for (int n = 0; n < 2; ++n)
#pragma unroll
            for (int r = 0; r < 4; ++r)
                aL[(m * 16 + rbase + r) * 132 + wv * 32 + n * 16 + cidx] = acc[m][n][r];
    __syncthreads();

    // ---- phase 4: gelu (lane=t) -> H2
    {
        const float brelu = brelu_p[0];
        f32x4 ar0 = *(const f32x4*)&aL[tl * 132 + cg * 8];
        f32x4 ar1 = *(const f32x4*)&aL[tl * 132 + cg * 8 + 4];
        f32x4 ai0 = *(const f32x4*)&aL[tl * 132 + 64 + cg * 8];
        f32x4 ai1 = *(const f32x4*)&aL[tl * 132 + 64 + cg * 8 + 4];
        s16x8 vhr, vhi, vlr, vli;
#pragma unroll
        for (int ci = 0; ci < 8; ++ci) {
            float ar = (ci < 4) ? ar0[ci & 3] : ar1[ci & 3];
            float ai = (ci < 4) ? ai0[ci & 3] : ai1[ci & 3];
            float r = sqrtf(ar * ar + ai * ai);
            float g = gelu_exact(r + brelu);
            float h2r, h2i;
            if (r > 0.f) { float f = g / r; h2r = f * ar; h2i = f * ai; }
            else { h2r = g; h2i = 0.f; }
            short rh = f2bfs(h2r), ih = f2bfs(h2i);
            vhr[ci] = rh; vhi[ci] = ih;
            vlr[ci] = f2bfs(h2r - bfs2f(rh));
            vli[ci] = f2bfs(h2i - bfs2f(ih));
        }
        *(s16x8*)&H2[tl * 264 + cg * 8]       = vhr;
        *(s16x8*)&H2[tl * 264 + 64 + cg * 8]  = vhi;
        *(s16x8*)&H2[tl * 264 + 128 + cg * 8] = vlr;
        *(s16x8*)&H2[tl * 264 + 192 + cg * 8] = vli;
    }
    __syncthreads();

    // ---- GEMM2: A = H2, B frags from W2f
    f32x4 acc2[2][2] = {};
#pragma unroll
    for (int lc = 0; lc < 6; ++lc) {
        const int ka = ASRC[lc] * 64;
        const int kb = BSRC[lc];
#pragma unroll
        for (int kh = 0; kh < 2; ++kh) {
            s16x8 a0 = *(const s16x8*)&H2[frow * 264 + ka + kh * 32 + fcol];
            s16x8 a1 = *(const s16x8*)&H2[(16 + frow) * 264 + ka + kh * 32 + fcol];
#pragma unroll
            for (int n = 0; n < 2; ++n) {
                s16x8 bfv = W2v[(size_t)((((wv * 2 + n) * 4 + kb) * 2 + kh) * 64 + lane)];
                acc2[0][n] = __builtin_amdgcn_mfma_f32_16x16x32_bf16(a0, bfv, acc2[0][n], 0, 0, 0);
                acc2[1][n] = __builtin_amdgcn_mfma_f32_16x16x32_bf16(a1, bfv, acc2[1][n], 0, 0, 0);
            }
        }
    }
    // cL aliases aL (smemA): all aL reads completed before the barrier above
    // GEMM2; no thread reads smemA during GEMM2.
#pragma unroll
    for (int m = 0; m < 2; ++m)
#pragma unroll
        for (int n = 0; n < 2; ++n)
#pragma unroll
            for (int r = 0; r < 4; ++r)
                cL[(m * 16 + rbase + r) * 132 + wv * 32 + n * 16 + cidx] = acc2[m][n][r];
    __syncthreads();

    // ---- phase 8: gate + compact coalesced store (lane=t)
    if (valid) {
        int h = rows[t], j = cols[t];
        size_t wbase = (size_t)rs8[h] + j;
        f32x4 cr0 = *(const f32x4*)&cL[tl * 132 + cg * 8];
        f32x4 cr1 = *(const f32x4*)&cL[tl * 132 + cg * 8 + 4];
        f32x4 ci0 = *(const f32x4*)&cL[tl * 132 + 64 + cg * 8];
        f32x4 ci1 = *(const f32x4*)&cL[tl * 132 + 64 + cg * 8 + 4];
#pragma unroll
        for (int ci = 0; ci < 8; ++ci) {
            int c = cg * 8 + ci;
            float cr  = (ci < 4) ? cr0[ci & 3] : cr1[ci & 3];
            float cii = (ci < 4) ? ci0[ci & 3] : ci1[ci & 3];
            float xr = Xcr[(size_t)(b * 64 + c) * T128 + t];
            float xi = Xci[(size_t)(b * 64 + c) * T128 + t];
            float r3 = sqrtf(cr * cr + cii * cii);
            float gm = glu_mags[(size_t)c * T + t];
            float gp = glu_phases[(size_t)c * T + t];
            float sg = 1.0f / (1.0f + expf(-(r3 + gm)));
            float ux, uy;
            if (r3 > 0.f) { float ir3 = 1.0f / r3; ux = cr * ir3; uy = cii * ir3; }
            else { ux = 1.f; uy = 0.f; }
            float sp, cp;
            sincosf(gp, &sp, &cp);
            float gx = sg * (ux * cp - uy * sp);
            float gy = sg * (ux * sp + uy * cp);
            size_t base = (size_t)(b * 64 + c) * T8cap + wbase;
            Xgr[base] = __float2bfloat16(xr * gx - xi * gy);
            Xgi[base] = __float2bfloat16(xr * gy + xi * gx);
        }
    }
}

// ------- depthwise conv + add (bf16 y, h-major rows, 8-wide, XCD swizzle)
__global__ __launch_bounds__(256) void conv_add_kernel(
    const bf16* __restrict__ y, const float* __restrict__ dw,
    float* __restrict__ out)
{
    const int nb = gridDim.x;
    const int chunk = nb >> 3;
    const int orig = blockIdx.x;
    const int swz = (orig & 7) * chunk + (orig >> 3);   // bijective: nb % 8 == 0
    int g = swz * 256 + threadIdx.x;
    int w8 = g % 90;
    int rem = g / 90;
    int h = rem % Hh;
    int bc = rem / Hh;
    int c = bc & (Cc - 1);
    int w = w8 * 8;
    int walt = (w >= Ww / 2) ? (w - Ww / 2) : (w + Ww / 2);
    float acc[8];
    {
        s16x8 v0 = *(const s16x8*)&y[((size_t)h * BC + bc) * NI + w];
#pragma unroll
        for (int e = 0; e < 8; ++e) acc[e] = bfs2f(v0[e]);
    }
#pragma unroll
    for (int k = 0; k < 11; ++k) {
        int hp = h + k - 5;
        int hh, ww;
        if (hp < 0)        { hh = -1 - hp;         ww = walt; }
        else if (hp >= Hh) { hh = 2 * Hh - 1 - hp; ww = walt; }
        else               { hh = hp;              ww = w; }
        s16x8 v = *(const s16x8*)&y[((size_t)hh * BC + bc) * NI + ww];
        float dwk = dw[c * 11 + k];
#pragma unroll
        for (int e = 0; e < 8; ++e)
            acc[e] = fmaf(dwk, bfs2f(v[e]), acc[e]);
    }
    float* ob = &out[((size_t)bc * Hh + h) * Ww + w];
    *(float4*)&ob[0] = make_float4(acc[0], acc[1], acc[2], acc[3]);
    *(float4*)&ob[4] = make_float4(acc[4], acc[5], acc[6], acc[7]);
}

// ------------------------------------------------------------------ launch
extern "C" void kernel_launch(void* const* d_in, const int* in_sizes, int n_in,
                              void* d_out, int out_size, void* d_ws, size_t ws_size,
                              hipStream_t stream)
{
    const float* x      = (const float*)d_in[0];
    const float* mean_r = (const float*)d_in[1];
    const float* mean_i = (const float*)d_in[2];
    const float* stdv   = (const float*)d_in[3];
    const float* mags_r = (const float*)d_in[4];
    const float* mags_i = (const float*)d_in[5];
    const float* bias_r = (const float*)d_in[6];
    const float* bias_i = (const float*)d_in[7];
    const float* w1_r   = (const float*)d_in[8];
    const float* w1_i   = (const float*)d_in[9];
    const float* brelu  = (const float*)d_in[10];
    const float* w2_r   = (const float*)d_in[11];
    const float* w2_i   = (const float*)d_in[12];
    const float* glu_m  = (const float*)d_in[13];
    const float* glu_p  = (const float*)d_in[14];
    const float* dw     = (const float*)d_in[15];
    const int*   rows   = (const int*)d_in[16];
    const int*   cols   = (const int*)d_in[17];
    const int T = in_sizes[16];
    const int T128 = ((T + 127) / 128) * 128;
    const int T8cap = ((T + 7 * Hh) + 127) & ~127;

    char* ws = (char*)d_ws;
    const size_t SApc  = (size_t)CM * KA * 2;             // 35,389,440
    const size_t XC_SZ = (size_t)BC * T128 * 4;           // ~42.7 MB
    const size_t XG_SZ = (size_t)BC * T8cap * 2;          // ~22.0 MB
    bf16*  Ap  = (bf16*)ws;
    bf16*  Aq  = (bf16*)(ws + SApc);
    float* Xcr = (float*)(ws + 2 * SApc);
    float* Xci = (float*)(ws + 2 * SApc + XC_SZ);
    bf16*  Xgr = (bf16*)ws;
    bf16*  Xgi = (bf16*)(ws + XG_SZ);
    bf16*  y   = (bf16*)(ws + 2 * XG_SZ);
    size_t boff = 2 * SApc + 2 * XC_SZ;                   // ~156.1 MB
    bf16*  Bce = (bf16*)(ws + boff);
    bf16*  Bse = (bf16*)(ws + boff + (size_t)NF * KF3 * 2);
    bf16*  Bti = (bf16*)(ws + boff + 2 * (size_t)NF * KF3 * 2);
    bf16*  W1f = (bf16*)(ws + boff + 2 * (size_t)NF * KF3 * 2 + (size_t)NI * KI * 2);
    bf16*  W2f = W1f + 32768;
    int*   rs  = (int*)(W2f + 32768);
    int*   rs8 = rs + (Hh + 2);

    build_bfwd_kernel<<<(NF * KF3 + 255) / 256, 256, 0, stream>>>(Bce, Bse);
    build_binv_kernel<<<(NI * KI + 255) / 256, 256, 0, stream>>>(Bti);
    build_wf_kernel<<<(2 * 32768 + 255) / 256, 256, 0, stream>>>(
        w1_r, w1_i, w2_r, w2_i, W1f, W2f);
    row_starts_kernel<<<1, 512, 0, stream>>>(rows, T, rs, rs8);

    for (int ch = 0; ch < CHUNKS; ++ch) {
        pack_kernel<<<(CM * 96 + 255) / 256, 256, 0, stream>>>(
            x, Ap, Aq, ch * HPC);
        gemm_fwd_compact_kernel<<<dim3(HPC, 6, 2), 256, 0, stream>>>(
            Ap, Aq, Bce, Bse, Xcr, Xci, rs, T128, ch * HPC);
    }

    pad_zero_kernel<<<Hh, 256, 0, stream>>>(Xgr, Xgi, rs, rs8, T8cap);

    const int nT32 = (T + 31) / 32;
    middle_fused_kernel<<<dim3(nT32, Bb), 256, 0, stream>>>(
        Xcr, Xci, Xgr, Xgi, mean_r, mean_i, stdv, mags_r, mags_i,
        bias_r, bias_i, W1f, W2f, brelu, glu_m, glu_p, rows, cols, rs8,
        T, T128, T8cap);

    gemm_inv_kernel<<<dim3(Hh, NI / 128), 256, 0, stream>>>(
        Xgr, Xgi, Bti, rs8, y, T8cap);

    conv_add_kernel<<<(Bb * Cc * Hh * 90) / 256, 256, 0, stream>>>(y, dw, (float*)d_out);
}